// Round 14
// baseline (71818.030 us; speedup 1.0000x reference)
//
#include <hip/hip_runtime.h>
#include <string.h>
#include <math.h>

#define NE 100000
#define NN 8192
#define NG 512
#define CH 12500
#define NCHUNK 8
#define NNC 2048

#define SQ3F  1.7320508075688772f
#define SQ5F  2.23606797749979f
#define SQ15F 3.872983346207417f

__constant__ int c_amap[10] = {-1,0,-1,-1,-1,-1,1,2,3,4};

typedef __attribute__((ext_vector_type(4))) float f32x4;
typedef __attribute__((ext_vector_type(8))) short bf16x8;
typedef unsigned short u16;

__device__ __forceinline__ float sigf(float x){ return 1.0f/(1.0f+expf(-x)); }
__device__ __forceinline__ float siluf(float x){ return x*sigf(x); }
__device__ __forceinline__ float dsiluf(float x){ float s=sigf(x); return s*(1.0f + x*(1.0f-s)); }

__device__ __forceinline__ float wred64(float v){
  #pragma unroll
  for (int o=32;o>0;o>>=1) v += __shfl_down(v,o,64);
  return v;
}
__device__ __forceinline__ int lbound(const int* a, int n, int v){
  int lo=0, hi=n;
  while (lo<hi){ int m=(lo+hi)>>1; if (a[m]<v) lo=m+1; else hi=m; }
  return lo;
}
__device__ __forceinline__ u16 f2b(float x){
  unsigned u=__float_as_uint(x);
  unsigned r=(u + 0x7fffu + ((u>>16)&1u))>>16;
  return (u16)r;
}
__device__ __forceinline__ float b2f(u16 b){
  return __uint_as_float(((unsigned)b)<<16);
}

// ---------------- edge sort by dst (counting sort) ----------------
__global__ void k_hist(const int* keys, int* hist, int n){
  int i = blockIdx.x*256 + threadIdx.x;
  if (i < n) atomicAdd(&hist[keys[i]], 1);
}
__global__ void k_scan0(const int* hist, int* rows){
  if (threadIdx.x == 0 && blockIdx.x == 0){
    int acc = 0;
    for (int i = 0; i < NN; i++){ rows[i] = acc; acc += hist[i]; }
    rows[NN] = acc;
  }
}
__global__ void k_fillperm(const int* keys, int* cursor, int* perm, int n){
  int i = blockIdx.x*256 + threadIdx.x;
  if (i < n){
    int slot = atomicAdd(&cursor[keys[i]], 1);
    perm[slot] = i;
  }
}
__global__ void k_mkedge(const int* perm, const int* src, const int* dst, int* src2, int* dst2){
  int k = blockIdx.x*256 + threadIdx.x;
  if (k < NE){ int e = perm[k]; src2[k] = src[e]; dst2[k] = dst[e]; }
}

// weight concat: WCATF[i][k][0:352] = [Wv0 | Ws0 | Ws1 | Ws2]
__global__ void k_wcat(const float* Wv0,const float* Ws0,const float* Ws1,const float* Ws2, float* W){
  int t = blockIdx.x*256 + threadIdx.x;
  if (t >= 8*128*352) return;
  int i = t/45056, r = t - i*45056;
  int k = r/352, n = r - k*352;
  float v;
  if (n < 128) v = Wv0[(size_t)i*16384 + k*128 + n];
  else if (n < 256) v = Ws0[(size_t)i*16384 + k*128 + (n-128)];
  else if (n < 320) v = Ws1[(size_t)i*8192 + k*64 + (n-256)];
  else v = Ws2[(size_t)i*4096 + k*32 + (n-320)];
  W[t] = v;
}

// ---------------- weight prep: direct bf16 & transposed bf16 (hi/lo) ----------------
__global__ void k_wpd(const float* __restrict__ W, u16* __restrict__ H, int n){
  int i=blockIdx.x*256+threadIdx.x;
  if (i<n) H[i]=f2b(W[i]);
}
// W: nb blocks of [K][Nd] -> out nb of [Nd][K]; lo part too
__global__ void k_wpt(const float* __restrict__ W, u16* __restrict__ H, u16* __restrict__ L,
                      int nb, int K, int Nd){
  int t=blockIdx.x*256+threadIdx.x;
  int tot=nb*K*Nd;
  if (t>=tot) return;
  int b=t/(K*Nd), r=t-b*(K*Nd);
  int k=r/Nd, n=r-k*Nd;
  float v=W[t];
  u16 h=f2b(v);
  size_t o=(size_t)b*K*Nd + (size_t)n*K + k;
  H[o]=h;
  L[o]=f2b(v-b2f(h));
}

// --------- direct-fragment bf16 MFMA GEMM: no LDS, no barriers; B pre-converted [Nd][K] ---------
template<bool ACC,int ACT,bool GATHER,bool SPLIT,bool ARBF,bool DMUL,bool PREOUT>
__global__ __launch_bounds__(256) void k_dgemm(
    const float* __restrict__ A, const int* __restrict__ idx,
    const u16* __restrict__ Bh, const u16* __restrict__ Bl,
    float* __restrict__ C, int M, int Nd, int K,
    const float* __restrict__ cen, const float* __restrict__ wid,
    const float* __restrict__ dm, float* __restrict__ pre)
{
  const int lane = threadIdx.x & 63, wave = threadIdx.x >> 6;
  const int bm = blockIdx.x*16, bn = blockIdx.y*64;
  int row = bm + (lane & 15);
  int arow = -1;
  if (row < M) arow = GATHER ? idx[row] : row;
  int col = bn + wave*16 + (lane & 15);
  bool bok = (col < Nd);
  const int q8 = (lane >> 4) * 8;
  f32x4 acc = {0.f,0.f,0.f,0.f};
  for (int k0 = 0; k0 < K; k0 += 32){
    int kk = k0 + q8;
    bf16x8 ah, al, bh, bl;
    #pragma unroll
    for (int i=0;i<8;i++){
      float v = 0.f;
      if (arow >= 0){
        if (ARBF){
          float r = A[arow];
          float t = (r - cen[kk+i]) / wid[kk+i];
          v = expf(-0.5f*t*t);
        } else v = A[(size_t)arow*K + kk + i];
      }
      u16 h = f2b(v);
      ah[i] = (short)h;
      if (SPLIT) al[i] = (short)f2b(v - b2f(h));
    }
    if (bok){
      bh = *(const bf16x8*)&Bh[(size_t)col*K + kk];
      if (SPLIT) bl = *(const bf16x8*)&Bl[(size_t)col*K + kk];
    } else {
      #pragma unroll
      for (int i=0;i<8;i++){ bh[i]=0; if (SPLIT) bl[i]=0; }
    }
    acc = __builtin_amdgcn_mfma_f32_16x16x32_bf16(ah, bh, acc, 0,0,0);
    if (SPLIT){
      acc = __builtin_amdgcn_mfma_f32_16x16x32_bf16(ah, bl, acc, 0,0,0);
      acc = __builtin_amdgcn_mfma_f32_16x16x32_bf16(al, bh, acc, 0,0,0);
    }
  }
  if (bok){
    #pragma unroll
    for (int v=0; v<4; v++){
      int r2 = bm + (lane>>4)*4 + v;
      if (r2 >= M) continue;
      size_t o = (size_t)r2*Nd + col;
      float x = acc[v];
      if (ACC) x += C[o];
      if (DMUL) x *= dsiluf(dm[o]);
      if (PREOUT) pre[o] = x;
      if (ACT==1) x=siluf(x); else if (ACT==2) x=tanhf(x); else if (ACT==3) x=sigf(x);
      C[o] = x;
    }
  }
}

// --------- direct-fragment einsum: rows strided by X; B pre-converted [CO][CI] ---------
template<int CI,int CO,int X,bool ACC,bool GATHER,bool SPLIT>
__global__ __launch_bounds__(256) void k_deins(
  const float* __restrict__ A, const int* __restrict__ idx,
  const u16* __restrict__ Bh, const u16* __restrict__ Bl,
  float* __restrict__ C, int M)
{
  const int lane = threadIdx.x & 63, wave = threadIdx.x >> 6;
  const int bm = blockIdx.x*16;
  int grow = bm + (lane & 15);
  long abase = -1;
  if (grow < M*X){
    int ge = grow / X, gx = grow - ge*X;
    int ar = GATHER ? idx[ge] : ge;
    abase = (long)ar*CI*X + gx;
  }
  int col = wave*16 + (lane&15);
  bool bok = (col < CO);
  const int q8 = (lane>>4)*8;
  f32x4 acc = {0.f,0.f,0.f,0.f};
  for (int k0=0;k0<CI;k0+=32){
    int kk=k0+q8;
    bf16x8 ah, al, bh, bl;
    #pragma unroll
    for (int i=0;i<8;i++){
      float v = (abase>=0) ? A[abase + (size_t)(kk+i)*X] : 0.0f;
      u16 h = f2b(v);
      ah[i] = (short)h;
      if (SPLIT) al[i] = (short)f2b(v - b2f(h));
    }
    if (bok){
      bh = *(const bf16x8*)&Bh[(size_t)col*CI + kk];
      if (SPLIT) bl = *(const bf16x8*)&Bl[(size_t)col*CI + kk];
    } else {
      #pragma unroll
      for (int i=0;i<8;i++){ bh[i]=0; if (SPLIT) bl[i]=0; }
    }
    acc = __builtin_amdgcn_mfma_f32_16x16x32_bf16(ah, bh, acc, 0,0,0);
    if (SPLIT){
      acc = __builtin_amdgcn_mfma_f32_16x16x32_bf16(ah, bl, acc, 0,0,0);
      acc = __builtin_amdgcn_mfma_f32_16x16x32_bf16(al, bh, acc, 0,0,0);
    }
  }
  __syncthreads(); // in-place (C==A) safety: all reads done before any write
  if (bok){
    #pragma unroll
    for (int v=0;v<4;v++){
      int r2 = bm + (lane>>4)*4 + v;
      if (r2 >= M*X) continue;
      int ge2 = r2 / X, gx2 = r2 - ge2*X;
      size_t o = (size_t)ge2*CO*X + (size_t)col*X + gx2;
      float x = acc[v];
      if (ACC) x += C[o];
      C[o] = x;
    }
  }
}

// ------------------------- small kernels -------------------------
__global__ void k_sentinel(float* o, int n, float v){
  int i = blockIdx.x*256 + threadIdx.x;
  if (i < n) o[i] = v;
}

__global__ void k_geom(const float* __restrict__ pos, const int* __restrict__ src, const int* __restrict__ dst,
                       float* __restrict__ U, float* __restrict__ Rr, float* __restrict__ SH2b){
  int e = blockIdx.x*256 + threadIdx.x;
  if (e >= NE) return;
  int s = src[e], d = dst[e];
  float vx = pos[s*3+0]-pos[d*3+0];
  float vy = pos[s*3+1]-pos[d*3+1];
  float vz = pos[s*3+2]-pos[d*3+2];
  float r = sqrtf(vx*vx+vy*vy+vz*vz + 1e-12f);
  float ux=vx/r, uy=vy/r, uz=vz/r;
  U[e*3+0]=ux; U[e*3+1]=uy; U[e*3+2]=uz;
  Rr[e]=r;
  SH2b[e*5+0]=SQ15F*ux*uy;
  SH2b[e*5+1]=SQ15F*uy*uz;
  SH2b[e*5+2]=0.5f*SQ5F*(3.0f*uz*uz-1.0f);
  SH2b[e*5+3]=SQ15F*ux*uz;
  SH2b[e*5+4]=0.5f*SQ15F*(ux*ux-uy*uy);
}

__global__ void k_f0init(const int* __restrict__ na, const float* __restrict__ at, float* __restrict__ f0){
  int t = blockIdx.x*256 + threadIdx.x;
  if (t >= NN*128) return;
  int n = t>>7, j = t&127;
  int m = c_amap[na[n]];
  f0[t] = at[m*128+j];
}

// lambda -> p = exp(lambda)
__global__ void k_lambda(const float* __restrict__ Z, const float* __restrict__ wa, float* __restrict__ P_c, int cnt){
  int e = blockIdx.x*256 + threadIdx.x;
  if (e >= cnt) return;
  float s = 0.0f;
  #pragma unroll
  for (int k=0;k<32;k++) s += Z[e*32+k]*wa[k];
  P_c[e] = expf(s);
}

__global__ void k_norm(const float* __restrict__ P, const float* __restrict__ S,
                       const int* __restrict__ dst, float* __restrict__ AB){
  int e = blockIdx.x*256 + threadIdx.x;
  if (e < NE) AB[e] = P[e]/(S[dst[e]]+1e-9f);
}

__global__ void k_finy(const float* __restrict__ x0,const float* __restrict__ x1,const float* __restrict__ x2,
                       float* __restrict__ y0,float* __restrict__ y1,float* __restrict__ y2,
                       const float* __restrict__ S){
  int t = blockIdx.x*256 + threadIdx.x;
  if (t >= NN*480) return;
  if (t < NN*128){ int n=t>>7; y0[t]=x0[t]+y0[t]/(S[n]+1e-9f); }
  else if (t < NN*320){ int q=t-NN*128; int n=q/192; y1[q]=x1[q]+y1[q]/(S[n]+1e-9f); }
  else { int q=t-NN*320; int n=q/160; y2[q]=x2[q]+y2[q]/(S[n]+1e-9f); }
}

// bf16 checkpoint quant/dequant
__global__ void k_q3(const float* __restrict__ f0,const float* __restrict__ f1,const float* __restrict__ f2,
                     u16* __restrict__ ck){
  int t = blockIdx.x*256 + threadIdx.x;
  if (t >= NN*480) return;
  float v;
  if (t < NN*128) v = f0[t];
  else if (t < NN*320) v = f1[t-NN*128];
  else v = f2[t-NN*320];
  ck[t] = f2b(v);
}
__global__ void k_dq3(const u16* __restrict__ ck,
                      float* __restrict__ f0,float* __restrict__ f1,float* __restrict__ f2){
  int t = blockIdx.x*256 + threadIdx.x;
  if (t >= NN*480) return;
  float v = b2f(ck[t]);
  if (t < NN*128) f0[t]=v;
  else if (t < NN*320) f1[t-NN*128]=v;
  else f2[t-NN*320]=v;
}

// per-graph aggregation; SC strided 352 [sv0|sw0|sw1|sw2]; accumulates S in lanes 480..495
template<bool INIT>
__global__ __launch_bounds__(512) void k_agg(
  float* __restrict__ f0o,float* __restrict__ f1o,float* __restrict__ f2o,
  const float* __restrict__ SC,const float* __restrict__ sv1,const float* __restrict__ sv2,
  const float* __restrict__ g,const float* __restrict__ U,const float* __restrict__ SH2b,
  const float* __restrict__ aArr,const int* __restrict__ keys,const int* __restrict__ dst,
  float* __restrict__ SACC, int c0, int c1)
{
  __shared__ float acc[7680];
  int b = blockIdx.x, lo = b<<4;
  int e0 = lbound(keys, NE, lo), e1 = lbound(keys, NE, lo+16);
  if (e0 < c0) e0 = c0;
  if (e1 > c1) e1 = c1;
  if (e0 >= e1) return;
  for (int i=threadIdx.x;i<7680;i+=512) acc[i]=0.0f;
  __syncthreads();
  const int j = threadIdx.x;
  const float inv = 1.0f/sqrtf(15.57f);
  int cat=3, cc_=0, xx_=0;
  if (j<128){ cat=0; }
  else if (j<320){ cat=1; int t=j-128; cc_=t/3; xx_=t-3*cc_; }
  else if (j<480){ cat=2; int t=j-320; cc_=t/5; xx_=t-5*cc_; }
  float sacc=0.0f;
  for (int e=e0; e<e1; ++e){
    int el = e - c0;
    float a = INIT ? inv : aArr[e];
    int nl = dst[e]&15;
    if (cat==0){
      float m = INIT ? g[el*224+j] : (SC[(size_t)el*352+j]*g[el*224+j] + SC[(size_t)el*352+128+j]);
      acc[nl*480+j] += a*m;
    } else if (cat==1){
      int t=j-128;
      float sh = SQ3F*U[e*3+xx_];
      float m = INIT ? g[el*224+128+cc_]*sh : (sv1[el*192+t]*g[el*224+128+cc_] + SC[(size_t)el*352+256+cc_]*sh);
      acc[nl*480+j] += a*m;
    } else if (cat==2){
      int t=j-320;
      float sh = SH2b[e*5+xx_];
      float m = INIT ? g[el*224+192+cc_]*sh : (sv2[el*160+t]*g[el*224+192+cc_] + SC[(size_t)el*352+320+cc_]*sh);
      acc[nl*480+j] += a*m;
    } else if (!INIT && j<496){
      if (nl==(j-480)) sacc += a;
    }
  }
  __syncthreads();
  for (int i=threadIdx.x;i<7680;i+=512){
    int nl=i/480, jj=i-480*nl, n=lo+nl;
    float v=acc[i];
    if (jj<128) f0o[n*128+jj]+=v;
    else if (jj<320) f1o[n*192+jj-128]+=v;
    else f2o[n*160+jj-320]+=v;
  }
  if (!INIT && j>=480 && j<496) SACC[lo+(j-480)] += sacc;
}

// per-graph scatter of edge grads
__global__ __launch_bounds__(640) void k_scat(
  float* __restrict__ df0, float* __restrict__ df1, float* __restrict__ df2,
  const float* __restrict__ DE0, const float* __restrict__ DZD,
  const float* __restrict__ DE1, const float* __restrict__ DE2,
  const int* __restrict__ src, const int* __restrict__ dst, int c0, int c1)
{
  __shared__ float acc[7680];
  int b=blockIdx.x, lo=b<<4;
  int e0=lbound(dst,NE,lo), e1=lbound(dst,NE,lo+16);
  if (e0 < c0) e0 = c0;
  if (e1 > c1) e1 = c1;
  for (int i=threadIdx.x;i<7680;i+=640) acc[i]=0.0f;
  __syncthreads();
  const int j=threadIdx.x;
  for (int e=e0;e<e1;++e){
    int el=e-c0;
    int sl=(src[e]&15)*480, dl=(dst[e]&15)*480;
    if (j<128) acc[sl+j] += DE0[el*128+j];
    else if (j<256){ int q=j-128; acc[dl+q] += DZD[el*128+q]; }
    else if (j<448){ int q=j-256; acc[sl+128+q] += DE1[el*192+q]; }
    else if (j<608){ int q=j-448; acc[sl+320+q] += DE2[el*160+q]; }
    __syncthreads();
  }
  for (int i=threadIdx.x;i<7680;i+=640){
    int nl=i/480, jj=i-480*nl, n=lo+nl;
    float v=acc[i];
    if (jj<128) df0[n*128+jj]+=v;
    else if (jj<320) df1[n*192+jj-128]+=v;
    else df2[n*160+jj-320]+=v;
  }
}

// SSUM[n] = (FB[n]-FA[n]) . DY[n]
__global__ __launch_bounds__(256) void k_ssum(
  const float* __restrict__ FA0,const float* __restrict__ FA1,const float* __restrict__ FA2,
  const float* __restrict__ FB0,const float* __restrict__ FB1,const float* __restrict__ FB2,
  const float* __restrict__ DY0,const float* __restrict__ DY1,const float* __restrict__ DY2,
  float* __restrict__ SSUM)
{
  int n=blockIdx.x*4+(threadIdx.x>>6), lane=threadIdx.x&63;
  if (n>=NN) return;
  float s=0.0f;
  for (int j=lane;j<480;j+=64){
    float d,g;
    if (j<128){ d=FB0[n*128+j]-FA0[n*128+j]; g=DY0[n*128+j]; }
    else if (j<320){ int q=j-128; d=FB1[n*192+q]-FA1[n*192+q]; g=DY1[n*192+q]; }
    else { int q=j-320; d=FB2[n*160+q]-FA2[n*160+q]; g=DY2[n*160+q]; }
    s += d*g;
  }
  s = wred64(s);
  if (lane==0) SSUM[n]=s;
}

// fused backward edge chain: da -> dlam -> dz -> split0/1/2 ; one wave per edge
__global__ __launch_bounds__(256) void k_bedge(
  float* __restrict__ SC, float* __restrict__ SV1, float* __restrict__ SV2,
  const float* __restrict__ g, const float* __restrict__ U, const float* __restrict__ SH2b,
  const float* __restrict__ df0,const float* __restrict__ df1,const float* __restrict__ df2,
  const int* __restrict__ dst, const float* __restrict__ SSUM, const float* __restrict__ wa,
  float* __restrict__ Z, const float* __restrict__ aArr,
  float* __restrict__ DG, float* __restrict__ DSH1, float* __restrict__ DSH2,
  int c0, int cnt)
{
  int w=threadIdx.x>>6, lane=threadIdx.x&63;
  int el=blockIdx.x*4+w;
  if (el>=cnt) return;
  int e=c0+el;
  int d=dst[e];
  float s=0.0f;
  for (int j=lane;j<480;j+=64){
    float m, dfv;
    if (j<128){
      m = SC[(size_t)el*352+j]*g[el*224+j] + SC[(size_t)el*352+128+j];
      dfv = df0[(size_t)d*128+j];
    } else if (j<320){
      int t=j-128, c=t/3, x=t-3*c;
      m = SV1[el*192+t]*g[el*224+128+c] + SC[(size_t)el*352+256+c]*(SQ3F*U[e*3+x]);
      dfv = df1[(size_t)d*192+t];
    } else {
      int t=j-320, c=t/5, x=t-5*c;
      m = SV2[el*160+t]*g[el*224+192+c] + SC[(size_t)el*352+320+c]*SH2b[e*5+x];
      dfv = df2[(size_t)d*160+t];
    }
    s += m*dfv;
  }
  s = wred64(s);
  s = __shfl(s,0,64);
  float a = aArr[e];
  float dlam = a*(s - SSUM[d]);
  if (lane<32){
    float z = Z[(size_t)el*32+lane];
    Z[(size_t)el*32+lane] = dlam*wa[lane]*(1.0f-z*z);
  }
  {
    float* row = SC + (size_t)el*352;
    for (int j=lane;j<128;j+=64){
      float dm = a*df0[(size_t)d*128+j];
      float sv = row[j];
      row[128+j] = dm;
      row[j] = dm*g[el*224+j];
      DG[el*224+j] = dm*sv;
    }
  }
  {
    float dm0=a*df1[(size_t)d*192+lane*3+0];
    float dm1=a*df1[(size_t)d*192+lane*3+1];
    float dm2=a*df1[(size_t)d*192+lane*3+2];
    float sw1o=SC[(size_t)el*352+256+lane];
    float g1=g[el*224+128+lane];
    float c0v=dm0*sw1o, c1v=dm1*sw1o, c2v=dm2*sw1o;
    c0v=wred64(c0v); c1v=wred64(c1v); c2v=wred64(c2v);
    if (lane==0){ DSH1[e*3+0]+=c0v; DSH1[e*3+1]+=c1v; DSH1[e*3+2]+=c2v; }
    float sh0=SQ3F*U[e*3+0], sh1=SQ3F*U[e*3+1], sh2=SQ3F*U[e*3+2];
    SC[(size_t)el*352+256+lane]=dm0*sh0+dm1*sh1+dm2*sh2;
    float sv0o=SV1[el*192+lane*3+0], sv1o=SV1[el*192+lane*3+1], sv2o=SV1[el*192+lane*3+2];
    DG[el*224+128+lane]=dm0*sv0o+dm1*sv1o+dm2*sv2o;
    SV1[el*192+lane*3+0]=dm0*g1; SV1[el*192+lane*3+1]=dm1*g1; SV1[el*192+lane*3+2]=dm2*g1;
  }
  {
    float dm[5]={0,0,0,0,0}, svo[5]={0,0,0,0,0};
    float sw2o=0.0f, g2=0.0f;
    if (lane<32){
      #pragma unroll
      for (int x=0;x<5;x++){ dm[x]=a*df2[(size_t)d*160+lane*5+x]; svo[x]=SV2[el*160+lane*5+x]; }
      sw2o=SC[(size_t)el*352+320+lane]; g2=g[el*224+192+lane];
    }
    float c[5];
    #pragma unroll
    for (int x=0;x<5;x++){ c[x]=dm[x]*sw2o; c[x]=wred64(c[x]); }
    if (lane==0){
      #pragma unroll
      for (int x=0;x<5;x++) DSH2[e*5+x]+=c[x];
    }
    if (lane<32){
      float dsw=0.0f, dg2=0.0f;
      #pragma unroll
      for (int x=0;x<5;x++){ dsw+=dm[x]*SH2b[e*5+x]; dg2+=dm[x]*svo[x]; }
      SC[(size_t)el*352+320+lane]=dsw;
      DG[el*224+192+lane]=dg2;
      #pragma unroll
      for (int x=0;x<5;x++) SV2[el*160+lane*5+x]=dm[x]*g2;
    }
  }
}

template<int CD,int X>
__global__ void k_gatefwd(float* __restrict__ f, const float* __restrict__ V, const float* __restrict__ P){
  int t=blockIdx.x*256+threadIdx.x;
  const int ox=CD*X;
  if (t>=NN*ox) return;
  int n=t/ox, rem=t-n*ox, d=rem/X;
  f[t] += V[t]*P[n*CD+d];
}

template<int CD,int X>
__global__ void k_gateback(const float* __restrict__ dfB, float* __restrict__ V,
                           const float* __restrict__ P, float* __restrict__ DPa){
  int t=blockIdx.x*256+threadIdx.x;
  if (t>=NN*CD) return;
  float p=P[t];
  float dp=0.0f;
  #pragma unroll
  for (int x=0;x<X;x++){ dp += dfB[t*X+x]*V[t*X+x]; }
  #pragma unroll
  for (int x=0;x<X;x++){ V[t*X+x] = dfB[t*X+x]*p; }
  DPa[t] = dp*p*(1.0f-p);
}

__global__ __launch_bounds__(256) void k_dr(const float* __restrict__ DRBF, const float* __restrict__ Rr,
    const float* __restrict__ cen, const float* __restrict__ wid, float* __restrict__ DRa, int c0, int cnt){
  int w=threadIdx.x>>6, lane=threadIdx.x&63;
  int el=blockIdx.x*4+w;
  if (el>=cnt) return;
  int e=c0+el;
  float r=Rr[e], s=0.0f;
  for (int k=lane;k<128;k+=64){
    float c=cen[k], wd=wid[k];
    float t=(r-c)/wd;
    float rb=expf(-0.5f*t*t);
    s += DRBF[el*128+k]*rb*((c-r)/(wd*wd));
  }
  s=wred64(s);
  if (lane==0) DRa[e]+=s;
}

__global__ __launch_bounds__(256) void k_initback(
  const float* __restrict__ df0,const float* __restrict__ df1,const float* __restrict__ df2,
  const int* __restrict__ dst,
  const float* __restrict__ g,const float* __restrict__ U,const float* __restrict__ SH2b,
  float* __restrict__ DG,float* __restrict__ DSH1,float* __restrict__ DSH2, int c0, int cnt)
{
  int w=threadIdx.x>>6, lane=threadIdx.x&63;
  int el=blockIdx.x*4+w;
  if (el>=cnt) return;
  int e=c0+el;
  int d=dst[e];
  const float inv=1.0f/sqrtf(15.57f);
  for (int j=lane;j<128;j+=64) DG[el*224+j]=inv*df0[d*128+j];
  float sh0=SQ3F*U[e*3+0], sh1=SQ3F*U[e*3+1], sh2=SQ3F*U[e*3+2];
  float df10=df1[d*192+lane*3+0], df11=df1[d*192+lane*3+1], df12=df1[d*192+lane*3+2];
  float g1=g[el*224+128+lane];
  DG[el*224+128+lane]=inv*(df10*sh0+df11*sh1+df12*sh2);
  float c0v=g1*df10, c1v=g1*df11, c2v=g1*df12;
  c0v=wred64(c0v); c1v=wred64(c1v); c2v=wred64(c2v);
  if (lane==0){ DSH1[e*3+0]+=inv*c0v; DSH1[e*3+1]+=inv*c1v; DSH1[e*3+2]+=inv*c2v; }
  float cc[5]={0,0,0,0,0};
  if (lane<32){
    float g2=g[el*224+192+lane];
    float dgv=0.0f;
    #pragma unroll
    for (int x=0;x<5;x++){ float dfv=df2[d*160+lane*5+x]; dgv+=dfv*SH2b[e*5+x]; cc[x]=g2*dfv; }
    DG[el*224+192+lane]=inv*dgv;
  }
  #pragma unroll
  for (int x=0;x<5;x++) cc[x]=wred64(cc[x]);
  if (lane==0){
    #pragma unroll
    for (int x=0;x<5;x++) DSH2[e*5+x]+=inv*cc[x];
  }
}

__global__ void k_geoback(const float* __restrict__ DRa, const float* __restrict__ DSH1, const float* __restrict__ DSH2,
                          const float* __restrict__ U, const float* __restrict__ Rr,
                          const int* __restrict__ src, const int* __restrict__ dst,
                          float* __restrict__ DPOS){
  int e=blockIdx.x*256+threadIdx.x;
  if (e>=NE) return;
  float ux=U[e*3+0], uy=U[e*3+1], uz=U[e*3+2];
  float r=Rr[e];
  float dux=SQ3F*DSH1[e*3+0], duy=SQ3F*DSH1[e*3+1], duz=SQ3F*DSH1[e*3+2];
  float d0=DSH2[e*5+0],d1=DSH2[e*5+1],d2=DSH2[e*5+2],d3=DSH2[e*5+3],d4=DSH2[e*5+4];
  dux += SQ15F*(uy*d0+uz*d3+ux*d4);
  duy += SQ15F*(ux*d0+uz*d1-uy*d4);
  duz += SQ15F*(uy*d1+ux*d3)+3.0f*SQ5F*uz*d2;
  float dr=DRa[e];
  float dot=dux*ux+duy*uy+duz*uz;
  float dvx=(dux-dot*ux)/r+dr*ux;
  float dvy=(duy-dot*uy)/r+dr*uy;
  float dvz=(duz-dot*uz)/r+dr*uz;
  int s=src[e], d=dst[e];
  atomicAdd(&DPOS[s*3+0],dvx); atomicAdd(&DPOS[s*3+1],dvy); atomicAdd(&DPOS[s*3+2],dvz);
  atomicAdd(&DPOS[d*3+0],-dvx); atomicAdd(&DPOS[d*3+1],-dvy); atomicAdd(&DPOS[d*3+2],-dvz);
}

__global__ void k_forces(const float* __restrict__ DPOS, float* __restrict__ o){
  int i=blockIdx.x*256+threadIdx.x;
  if (i<NN*3) o[i]=-DPOS[i];
}

// per-node LN + head forward + backward seeds; single wave per node
__global__ __launch_bounds__(64) void k_lnhead(
  const float* __restrict__ f0,const float* __restrict__ f1,const float* __restrict__ f2,
  const float* __restrict__ lng,const float* __restrict__ lnb,
  const float* __restrict__ W0,const float* __restrict__ hout,
  float* __restrict__ EN, float* __restrict__ df0,float* __restrict__ df1,float* __restrict__ df2)
{
  __shared__ float xh[480];
  __shared__ float fl[128];
  __shared__ float dyv[128];
  __shared__ float dxh[128];
  int n=blockIdx.x, lane=threadIdx.x;
  const float c0=1.0f/sqrtf(18.03f);
  for (int i=lane;i<480;i+=64){
    float v=(i<128)? f0[n*128+i] : (i<320)? f1[n*192+(i-128)] : f2[n*160+(i-320)];
    xh[i]=v;
  }
  __syncthreads();
  float s1=0.0f,s2=0.0f;
  for (int i=lane;i<480;i+=64){ float v=xh[i]; s1+=v; s2+=v*v; }
  s1=wred64(s1); s2=wred64(s2);
  float mu=__shfl(s1,0,64)*(1.0f/480.0f);
  float var=__shfl(s2,0,64)*(1.0f/480.0f)-mu*mu;
  float rstd=rsqrtf(var+1e-5f);
  for (int i=lane;i<480;i+=64) xh[i]=(xh[i]-mu)*rstd;
  __syncthreads();
  for (int k=lane;k<128;k+=64) fl[k]=xh[k]*lng[k]+lnb[k];
  __syncthreads();
  float y0=0.0f,y1=0.0f;
  for (int k=0;k<128;k++){ float f=fl[k]; y0+=f*W0[k*128+lane]; y1+=f*W0[k*128+lane+64]; }
  float e = siluf(y0)*hout[lane] + siluf(y1)*hout[lane+64];
  e=wred64(e);
  if (lane==0) EN[n]=e*c0;
  dyv[lane]=c0*hout[lane]*dsiluf(y0);
  dyv[lane+64]=c0*hout[lane+64]*dsiluf(y1);
  __syncthreads();
  float d0=0.0f,d1=0.0f;
  for (int j=0;j<128;j++){ float dv=dyv[j]; d0+=dv*W0[lane*128+j]; d1+=dv*W0[(lane+64)*128+j]; }
  dxh[lane]=d0*lng[lane];
  dxh[lane+64]=d1*lng[lane+64];
  __syncthreads();
  float s3=dxh[lane]+dxh[lane+64];
  float s4=dxh[lane]*xh[lane]+dxh[lane+64]*xh[lane+64];
  s3=wred64(s3); s4=wred64(s4);
  float m1=__shfl(s3,0,64)*(1.0f/480.0f);
  float m2=__shfl(s4,0,64)*(1.0f/480.0f);
  for (int i=lane;i<480;i+=64){
    float dv=rstd*(((i<128)?dxh[i]:0.0f)-m1-xh[i]*m2);
    if (i<128) df0[n*128+i]=dv;
    else if (i<320) df1[n*192+(i-128)]=dv;
    else df2[n*160+(i-320)]=dv;
  }
}

__global__ void k_esum(const float* __restrict__ EN, float* __restrict__ out){
  int b=blockIdx.x*64+threadIdx.x;
  if (b<NG){
    float s=0.0f;
    for (int k=0;k<16;k++) s+=EN[b*16+k];
    out[b]=s;
  }
}

#define DG_(ACC,ACT,GA,SP,AR,DM,PO, A,IDX,BH,BL,C,M,Nd,K, DMp,POp) \
  k_dgemm<ACC,ACT,GA,SP,AR,DM,PO><<<dim3((unsigned)(((M)+15)/16),(unsigned)(((Nd)+63)/64)),dim3(256),0,stream>>>((A),(IDX),(BH),(BL),(C),(M),(Nd),(K),rbfc,rbfw,(DMp),(POp))
#define DE_(CI,CO,X,ACC,GA,SP, A,IDX,BH,BL,C,M) \
  k_deins<CI,CO,X,ACC,GA,SP><<<dim3((unsigned)(((M)*(X)+15)/16)),dim3(256),0,stream>>>((A),(IDX),(BH),(BL),(C),(M))
#define G256(n) dim3((unsigned)(((n)+255)/256)),dim3(256),0,stream
#define GW4(n) dim3((unsigned)(((n)+3)/4)),dim3(256),0,stream

extern "C" void kernel_launch(void* const* d_in, const int* in_sizes, int n_in,
                              void* d_out, int out_size, void* d_ws, size_t ws_size,
                              hipStream_t stream)
{
  const float* pos =(const float*)d_in[0];
  const float* atab=(const float*)d_in[1];
  const float* rbfc=(const float*)d_in[2];
  const float* rbfw=(const float*)d_in[3];
  const float* degW1=(const float*)d_in[4];
  const float* degW2=(const float*)d_in[5];
  const float* degW3=(const float*)d_in[6];
  const float* Wv0=(const float*)d_in[7];
  const float* Wv1=(const float*)d_in[8];
  const float* Wv2=(const float*)d_in[9];
  const float* Ws0=(const float*)d_in[10];
  const float* Ws1=(const float*)d_in[11];
  const float* Ws2=(const float*)d_in[12];
  const float* rW1=(const float*)d_in[13];
  const float* rW2=(const float*)d_in[14];
  const float* rW3=(const float*)d_in[15];
  const float* WaS=(const float*)d_in[16];
  const float* WaD=(const float*)d_in[17];
  const float* WaE=(const float*)d_in[18];
  const float* wab=(const float*)d_in[19];
  const float* ff1=(const float*)d_in[20];
  const float* ff2=(const float*)d_in[21];
  const float* fg1=(const float*)d_in[22];
  const float* fg2=(const float*)d_in[23];
  const float* fW1=(const float*)d_in[24];
  const float* fW2=(const float*)d_in[25];
  const float* lng=(const float*)d_in[26];
  const float* lnb=(const float*)d_in[27];
  const float* W0h=(const float*)d_in[28];
  const float* hout=(const float*)d_in[29];
  const int* natom=(const int*)d_in[30];
  const int* esrc=(const int*)d_in[31];
  const int* edst=(const int*)d_in[32];

  float* Wp=(float*)d_ws;
  size_t off=0;
  auto al=[&](size_t n)->float*{ float* q=Wp+off; off+=n; return q; };
  auto alu=[&](size_t n)->u16*{ off=(off+3)&~(size_t)3; u16* q=(u16*)(Wp+off); off+=(n+1)/2; return q; };

  const size_t SLOT = (size_t)NN*480;
  u16* CKB = alu(9*SLOT);
  float* FA0=al((size_t)NN*128); float* FA1=al((size_t)NN*192); float* FA2=al((size_t)NN*160);
  float* FB0=al((size_t)NN*128); float* FB1=al((size_t)NN*192); float* FB2=al((size_t)NN*160);
  float* F0N=al((size_t)NN*128);
  float* DI0=al((size_t)NN*128); float* DI1=al((size_t)NN*192); float* DI2=al((size_t)NN*160);
  float* DY0=al((size_t)NN*128); float* DY1=al((size_t)NN*192); float* DY2=al((size_t)NN*160);
  float* TBc=al((size_t)NNC*512); float* DTc=al((size_t)NNC*512);
  float* P1=al((size_t)NN*64); float* P2=al((size_t)NN*32);
  float* V1=al((size_t)NN*192); float* V2=al((size_t)NN*160);
  float* DPb=al((size_t)NN*64);
  float* U=al((size_t)NE*3); float* Rr=al(NE); float* SH2b=al((size_t)NE*5);
  float* ABLK=al(8ULL*NE); float* LAM=al(NE);
  float* SSUM=al(NN); float* ENODE=al(NN); float* SACC=al(NN);
  float* DRr=al(NE); float* DSH1=al((size_t)NE*3); float* DSH2=al((size_t)NE*5);
  float* DPOS=al((size_t)NN*3);
  // chunk-local
  float* PRE1=al((size_t)CH*64); float* PRE2=al((size_t)CH*64);
  float* H1=al((size_t)CH*64);  float* H2=al((size_t)CH*64);
  float* Gc=al((size_t)CH*224); float* DGc=al((size_t)CH*224);
  float* SCAT=al((size_t)CH*352);
  float* SV1=al((size_t)CH*192); float* SV2=al((size_t)CH*160);
  float* Zc=al((size_t)CH*32);  float* DE0=al((size_t)CH*128);
  // aliases: DZD -> Gc (after bedge), DRBF -> SCAT (after DE0 GEMM), WCATF -> TBc (prep only)
  float* DZD = Gc;
  float* DRBF = SCAT;
  float* WCATF = TBc;
  // CSR ints
  int* ROWS =(int*)al(NN+1);
  int* CNT  =(int*)al(NN);
  int* POSB =(int*)al(NN);
  int* PERMB=(int*)al(NE);
  int* ESRC2=(int*)al(NE);
  int* EDST2=(int*)al(NE);
  // prepped weights (ushort)
  u16* degW1T_h=alu(8192);  u16* degW1T_l=alu(8192);  u16* degW1D=alu(8192);
  u16* degW2T_h=alu(4096);  u16* degW2T_l=alu(4096);  u16* degW2D=alu(4096);
  u16* degW3T_h=alu(14336); u16* degW3T_l=alu(14336); u16* degW3D=alu(14336);
  u16* rW1T_h=alu(65536);   u16* rW1T_l=alu(65536);   u16* rW1D=alu(65536);
  u16* rW2T_h=alu(32768);   u16* rW2T_l=alu(32768);   u16* rW2D=alu(32768);
  u16* rW3T_h=alu(114688);  u16* rW3T_l=alu(114688);  u16* rW3D=alu(114688);
  u16* WaST_h=alu(32768);   u16* WaST_l=alu(32768);   u16* WaSD=alu(32768);
  u16* WaDT_h=alu(32768);   u16* WaDT_l=alu(32768);   u16* WaDD=alu(32768);
  u16* WaET_h=alu(16384);   u16* WaET_l=alu(16384);   u16* WaED=alu(16384);
  u16* ff1T_h=alu(524288);  u16* ff1T_l=alu(524288);  u16* ff1D=alu(524288);
  u16* ff2T_h=alu(524288);  u16* ff2T_l=alu(524288);  u16* ff2D=alu(524288);
  u16* fg1T_h=alu(65536);   u16* fg1T_l=alu(65536);   u16* fg1D=alu(65536);
  u16* fg2T_h=alu(32768);   u16* fg2T_l=alu(32768);   u16* fg2D=alu(32768);
  u16* fW1T_h=alu(32768);   u16* fW1T_l=alu(32768);   u16* fW1D=alu(32768);
  u16* fW2T_h=alu(8192);    u16* fW2T_l=alu(8192);    u16* fW2D=alu(8192);
  u16* Wv1T_h=alu(32768);   u16* Wv1T_l=alu(32768);   u16* Wv1D=alu(32768);
  u16* Wv2T_h=alu(8192);    u16* Wv2T_l=alu(8192);    u16* Wv2D=alu(8192);
  u16* WCATT_h=alu(360448); u16* WCATT_l=alu(360448); u16* WCATD=alu(360448);

  float* outE=(float*)d_out;
  float* outF=outE+NG;

  if (off*sizeof(float) > ws_size){
    k_sentinel<<<G256(out_size)>>>(outE, out_size, (float)ws_size);
    return;
  }

  // ---------------- weight prep ----------------
  k_wpt<<<G256(8192)>>>(degW1,degW1T_h,degW1T_l,1,128,64);   k_wpd<<<G256(8192)>>>(degW1,degW1D,8192);
  k_wpt<<<G256(4096)>>>(degW2,degW2T_h,degW2T_l,1,64,64);    k_wpd<<<G256(4096)>>>(degW2,degW2D,4096);
  k_wpt<<<G256(14336)>>>(degW3,degW3T_h,degW3T_l,1,64,224);  k_wpd<<<G256(14336)>>>(degW3,degW3D,14336);
  k_wpt<<<G256(65536)>>>(rW1,rW1T_h,rW1T_l,8,128,64);        k_wpd<<<G256(65536)>>>(rW1,rW1D,65536);
  k_wpt<<<G256(32768)>>>(rW2,rW2T_h,rW2T_l,8,64,64);         k_wpd<<<G256(32768)>>>(rW2,rW2D,32768);
  k_wpt<<<G256(114688)>>>(rW3,rW3T_h,rW3T_l,8,64,224);       k_wpd<<<G256(114688)>>>(rW3,rW3D,114688);
  k_wpt<<<G256(32768)>>>(WaS,WaST_h,WaST_l,8,128,32);        k_wpd<<<G256(32768)>>>(WaS,WaSD,32768);
  k_wpt<<<G256(32768)>>>(WaD,WaDT_h,WaDT_l,8,128,32);        k_wpd<<<G256(32768)>>>(WaD,WaDD,32768);
  k_wpt<<<G256(16384)>>>(WaE,WaET_h,WaET_l,8,64,32);         k_wpd<<<G256(16384)>>>(WaE,WaED,16384);
  k_wpt<<<G256(524288)>>>(ff1,ff1T_h,ff1T_l,8,128,512);      k_wpd<<<G256(524288)>>>(ff1,ff1D,524288);
  k_wpt<<<G256(524288)>>>(ff2,ff2T_h,ff2T_l,8,512,128);      k_wpd<<<G256(524288)>>>(ff2,ff2D,524288);
  k_wpt<<<G256(65536)>>>(fg1,fg1T_h,fg1T_l,8,128,64);        k_wpd<<<G256(65536)>>>(fg1,fg1D,65536);
  k_wpt<<<G256(32768)>>>(fg2,fg2T_h,fg2T_l,8,128,32);        k_wpd<<<G256(32768)>>>(fg2,fg2D,32768);
  k_wpt<<<G256(32768)>>>(fW1,fW1T_h,fW1T_l,8,64,64);         k_wpd<<<G256(32768)>>>(fW1,fW1D,32768);
  k_wpt<<<G256(8192)>>>(fW2,fW2T_h,fW2T_l,8,32,32);          k_wpd<<<G256(8192)>>>(fW2,fW2D,8192);
  k_wpt<<<G256(32768)>>>(Wv1,Wv1T_h,Wv1T_l,8,64,64);         k_wpd<<<G256(32768)>>>(Wv1,Wv1D,32768);
  k_wpt<<<G256(8192)>>>(Wv2,Wv2T_h,Wv2T_l,8,32,32);          k_wpd<<<G256(8192)>>>(Wv2,Wv2D,8192);
  k_wcat<<<G256(8*45056)>>>(Wv0,Ws0,Ws1,Ws2,WCATF);
  k_wpt<<<G256(360448)>>>(WCATF,WCATT_h,WCATT_l,8,128,352);  k_wpd<<<G256(360448)>>>(WCATF,WCATD,360448);

  // ---------------- sort edges by dst ----------------
  (void)hipMemsetAsync(CNT,0,NN*sizeof(int),stream);
  k_hist<<<G256(NE)>>>(edst,CNT,NE);
  k_scan0<<<dim3(1),dim3(64),0,stream>>>(CNT,ROWS);
  (void)hipMemcpyAsync(POSB,ROWS,NN*sizeof(int),hipMemcpyDeviceToDevice,stream);
  k_fillperm<<<G256(NE)>>>(edst,POSB,PERMB,NE);
  k_mkedge<<<G256(NE)>>>(PERMB,esrc,edst,ESRC2,EDST2);

  // ---------------- setup ----------------
  k_geom<<<G256(NE)>>>(pos,ESRC2,EDST2,U,Rr,SH2b);
  k_f0init<<<G256(NN*128)>>>(natom,atab,FA0);
  (void)hipMemsetAsync(FA1,0,(size_t)NN*192*4,stream);
  (void)hipMemsetAsync(FA2,0,(size_t)NN*160*4,stream);
  (void)hipMemsetAsync(DRr,0,(size_t)NE*4,stream);
  (void)hipMemsetAsync(DSH1,0,(size_t)NE*3*4,stream);
  (void)hipMemsetAsync(DSH2,0,(size_t)NE*5*4,stream);
  (void)hipMemsetAsync(DPOS,0,(size_t)NN*3*4,stream);

  // degree embedding (chunked) -> FA  [split-bf16 + fused RBF]
  for (int cc=0;cc<NCHUNK;cc++){
    int c0e=cc*CH, cnt=CH;
    DG_(false,1,false,true,true,false,false, Rr+c0e,nullptr,degW1T_h,degW1T_l,H1, cnt,64,128, nullptr,nullptr);
    DG_(false,1,false,true,false,false,false, H1,nullptr,degW2T_h,degW2T_l,H2, cnt,64,64, nullptr,nullptr);
    DG_(false,0,false,true,false,false,false, H2,nullptr,degW3T_h,degW3T_l,Gc, cnt,224,64, nullptr,nullptr);
    k_agg<true><<<dim3(NG),dim3(512),0,stream>>>(FA0,FA1,FA2,
      nullptr,nullptr,nullptr, Gc,U,SH2b, nullptr, EDST2,EDST2, nullptr, c0e,c0e+cnt);
  }
  k_q3<<<G256(NN*480)>>>(FA0,FA1,FA2, CKB);

  float *c0_=FA0,*c1_=FA1,*c2_=FA2, *n0_=FB0,*n1_=FB1,*n2_=FB2;

  // ---------------- forward blocks [split-bf16] ----------------
  for (int i=0;i<8;i++){
    float* AB=ABLK+(size_t)i*NE;
    (void)hipMemsetAsync(SACC,0,(size_t)NN*4,stream);
    (void)hipMemsetAsync(n0_,0,(size_t)NN*128*4,stream);
    (void)hipMemsetAsync(n1_,0,(size_t)NN*192*4,stream);
    (void)hipMemsetAsync(n2_,0,(size_t)NN*160*4,stream);
    for (int cc=0;cc<NCHUNK;cc++){
      int c0e=cc*CH, cnt=CH;
      DG_(false,1,false,true,true,false,false, Rr+c0e,nullptr,rW1T_h+(size_t)i*8192,rW1T_l+(size_t)i*8192,H1, cnt,64,128, nullptr,nullptr);
      DG_(false,1,false,true,false,false,false, H1,nullptr,rW2T_h+(size_t)i*4096,rW2T_l+(size_t)i*4096,H2, cnt,64,64, nullptr,nullptr);
      DG_(false,0,false,true,false,false,false, H2,nullptr,rW3T_h+(size_t)i*14336,rW3T_l+(size_t)i*14336,Gc, cnt,224,64, nullptr,nullptr);
      DG_(false,0,true,true,false,false,false, c0_,ESRC2+c0e,WaST_h+(size_t)i*4096,WaST_l+(size_t)i*4096,Zc, cnt,32,128, nullptr,nullptr);
      DG_(true,0,true,true,false,false,false, c0_,EDST2+c0e,WaDT_h+(size_t)i*4096,WaDT_l+(size_t)i*4096,Zc, cnt,32,128, nullptr,nullptr);
      DG_(true,2,false,true,false,false,false, H2,nullptr,WaET_h+(size_t)i*2048,WaET_l+(size_t)i*2048,Zc, cnt,32,64, nullptr,nullptr);
      k_lambda<<<G256(cnt)>>>(Zc, wab+(size_t)i*32, LAM+c0e, cnt);
      DG_(false,0,true,true,false,false,false, c0_,ESRC2+c0e,WCATT_h+(size_t)i*45056,WCATT_l+(size_t)i*45056,SCAT, cnt,352,128, nullptr,nullptr);
      DE_(64,64,3,false,true,true, c1_,ESRC2+c0e,Wv1T_h+(size_t)i*4096,Wv1T_l+(size_t)i*4096,SV1, cnt);
      DE_(32,32,5,false,true,true, c2_,ESRC2+c0e,Wv2T_h+(size_t)i*1024,Wv2T_l+(size_t)i*1024,SV2, cnt);
      k_agg<false><<<dim3(NG),dim3(512),0,stream>>>(n0_,n1_,n2_,
        SCAT,SV1,SV2, Gc,U,SH2b, LAM, EDST2,EDST2, SACC, c0e,c0e+cnt);
    }
    k_norm<<<G256(NE)>>>(LAM,SACC,EDST2,AB);
    k_finy<<<G256(NN*480)>>>(c0_,c1_,c2_, n0_,n1_,n2_, SACC);
    k_q3<<<G256(NN*480)>>>(n0_,n1_,n2_, CKB+(size_t)(i+1)*SLOT);
    for (int nc=0;nc<NN/NNC;nc++){
      DG_(false,1,false,true,false,false,false, n0_+(size_t)nc*NNC*128,nullptr,ff1T_h+(size_t)i*65536,ff1T_l+(size_t)i*65536,TBc, NNC,512,128, nullptr,nullptr);
      DG_(true,0,false,true,false,false,false, TBc,nullptr,ff2T_h+(size_t)i*65536,ff2T_l+(size_t)i*65536, n0_+(size_t)nc*NNC*128, NNC,128,512, nullptr,nullptr);
    }
    DG_(false,3,false,true,false,false,false, n0_,nullptr,fg1T_h+(size_t)i*8192,fg1T_l+(size_t)i*8192,P1, NN,64,128, nullptr,nullptr);
    DG_(false,3,false,true,false,false,false, n0_,nullptr,fg2T_h+(size_t)i*4096,fg2T_l+(size_t)i*4096,P2, NN,32,128, nullptr,nullptr);
    DE_(64,64,3,false,false,true, n1_,nullptr,fW1T_h+(size_t)i*4096,fW1T_l+(size_t)i*4096,V1, NN);
    DE_(32,32,5,false,false,true, n2_,nullptr,fW2T_h+(size_t)i*1024,fW2T_l+(size_t)i*1024,V2, NN);
    k_gatefwd<64,3><<<G256(NN*192)>>>(n1_,V1,P1);
    k_gatefwd<32,5><<<G256(NN*160)>>>(n2_,V2,P2);
    float* t;
    t=c0_;c0_=n0_;n0_=t; t=c1_;c1_=n1_;n1_=t; t=c2_;c2_=n2_;n2_=t;
  }

  // ---------------- head ----------------
  k_lnhead<<<dim3(NN),dim3(64),0,stream>>>(c0_,c1_,c2_, lng,lnb,W0h,hout, ENODE, DI0,DI1,DI2);
  k_esum<<<dim3(8),dim3(64),0,stream>>>(ENODE,outE);

  // ---------------- backward blocks [plain bf16, direct fragments] ----------------
  for (int i=7;i>=0;--i){
    const float* AB=ABLK+(size_t)i*NE;
    k_dq3<<<G256(NN*480)>>>(CKB+(size_t)i*SLOT, FA0,FA1,FA2);
    if (i>0){
      int p=i-1;
      for (int nc=0;nc<NN/NNC;nc++){
        DG_(false,1,false,false,false,false,false, FA0+(size_t)nc*NNC*128,nullptr,ff1T_h+(size_t)p*65536,nullptr,TBc, NNC,512,128, nullptr,nullptr);
        DG_(true,0,false,false,false,false,false, TBc,nullptr,ff2T_h+(size_t)p*65536,nullptr, FA0+(size_t)nc*NNC*128, NNC,128,512, nullptr,nullptr);
      }
      DG_(false,3,false,false,false,false,false, FA0,nullptr,fg1T_h+(size_t)p*8192,nullptr,P1, NN,64,128, nullptr,nullptr);
      DG_(false,3,false,false,false,false,false, FA0,nullptr,fg2T_h+(size_t)p*4096,nullptr,P2, NN,32,128, nullptr,nullptr);
      DE_(64,64,3,false,false,false, FA1,nullptr,fW1T_h+(size_t)p*4096,nullptr,V1, NN);
      DE_(32,32,5,false,false,false, FA2,nullptr,fW2T_h+(size_t)p*1024,nullptr,V2, NN);
      k_gatefwd<64,3><<<G256(NN*192)>>>(FA1,V1,P1);
      k_gatefwd<32,5><<<G256(NN*160)>>>(FA2,V2,P2);
    }
    k_dq3<<<G256(NN*480)>>>(CKB+(size_t)(i+1)*SLOT, FB0,FB1,FB2);
    (void)hipMemcpyAsync(F0N,FB0,(size_t)NN*128*4,hipMemcpyDeviceToDevice,stream);
    for (int nc=0;nc<NN/NNC;nc++){
      DG_(false,1,false,false,false,false,false, FB0+(size_t)nc*NNC*128,nullptr,ff1T_h+(size_t)i*65536,nullptr,TBc, NNC,512,128, nullptr,nullptr);
      DG_(true,0,false,false,false,false,false, TBc,nullptr,ff2T_h+(size_t)i*65536,nullptr, F0N+(size_t)nc*NNC*128, NNC,128,512, nullptr,nullptr);
    }
    DG_(false,3,false,false,false,false,false, F0N,nullptr,fg1T_h+(size_t)i*8192,nullptr,P1, NN,64,128, nullptr,nullptr);
    DG_(false,3,false,false,false,false,false, F0N,nullptr,fg2T_h+(size_t)i*4096,nullptr,P2, NN,32,128, nullptr,nullptr);
    DE_(64,64,3,false,false,false, FB1,nullptr,fW1T_h+(size_t)i*4096,nullptr,V1, NN);
    DE_(32,32,5,false,false,false, FB2,nullptr,fW2T_h+(size_t)i*1024,nullptr,V2, NN);
    k_gateback<64,3><<<G256(NN*64)>>>(DI1,V1,P1,DPb);
    DG_(true,0,false,false,false,false,false, DPb,nullptr,fg1D+(size_t)i*8192,nullptr,DI0, NN,128,64, nullptr,nullptr);
    (void)hipMemcpyAsync(DY1,DI1,(size_t)NN*192*4,hipMemcpyDeviceToDevice,stream);
    DE_(64,64,3,true,false,false, V1,nullptr,fW1D+(size_t)i*4096,nullptr,DY1, NN);
    k_gateback<32,5><<<G256(NN*32)>>>(DI2,V2,P2,DPb);
    DG_(true,0,false,false,false,false,false, DPb,nullptr,fg2D+(size_t)i*4096,nullptr,DI0, NN,128,32, nullptr,nullptr);
    (void)hipMemcpyAsync(DY2,DI2,(size_t)NN*160*4,hipMemcpyDeviceToDevice,stream);
    DE_(32,32,5,true,false,false, V2,nullptr,fW2D+(size_t)i*1024,nullptr,DY2, NN);
    (void)hipMemcpyAsync(DY0,DI0,(size_t)NN*128*4,hipMemcpyDeviceToDevice,stream);
    for (int nc=0;nc<NN/NNC;nc++){
      DG_(false,0,false,false,false,false,false, FB0+(size_t)nc*NNC*128,nullptr,ff1T_h+(size_t)i*65536,nullptr,TBc, NNC,512,128, nullptr,nullptr);
      DG_(false,0,false,false,false,true,false, DI0+(size_t)nc*NNC*128,nullptr,ff2D+(size_t)i*65536,nullptr,DTc, NNC,512,128, TBc,nullptr);
      DG_(true,0,false,false,false,false,false, DTc,nullptr,ff1D+(size_t)i*65536,nullptr, DY0+(size_t)nc*NNC*128, NNC,128,512, nullptr,nullptr);
    }
    k_ssum<<<dim3(NN/4),dim3(256),0,stream>>>(FA0,FA1,FA2,FB0,FB1,FB2,DY0,DY1,DY2,SSUM);
    (void)hipMemcpyAsync(DI0,DY0,(size_t)NN*128*4,hipMemcpyDeviceToDevice,stream);
    (void)hipMemcpyAsync(DI1,DY1,(size_t)NN*192*4,hipMemcpyDeviceToDevice,stream);
    (void)hipMemcpyAsync(DI2,DY2,(size_t)NN*160*4,hipMemcpyDeviceToDevice,stream);
    for (int cc=0;cc<NCHUNK;cc++){
      int c0e=cc*CH, cnt=CH;
      DG_(false,1,false,false,true,false,true, Rr+c0e,nullptr,rW1T_h+(size_t)i*8192,nullptr,H1, cnt,64,128, nullptr,PRE1);
      DG_(false,1,false,false,false,false,true, H1,nullptr,rW2T_h+(size_t)i*4096,nullptr,H2, cnt,64,64, nullptr,PRE2);
      DG_(false,0,false,false,false,false,false, H2,nullptr,rW3T_h+(size_t)i*14336,nullptr,Gc, cnt,224,64, nullptr,nullptr);
      DG_(false,0,true,false,false,false,false, FA0,ESRC2+c0e,WaST_h+(size_t)i*4096,nullptr,Zc, cnt,32,128, nullptr,nullptr);
      DG_(true,0,true,false,false,false,false, FA0,EDST2+c0e,WaDT_h+(size_t)i*4096,nullptr,Zc, cnt,32,128, nullptr,nullptr);
      DG_(true,2,false,false,false,false,false, H2,nullptr,WaET_h+(size_t)i*2048,nullptr,Zc, cnt,32,64, nullptr,nullptr);
      DG_(false,0,true,false,false,false,false, FA0,ESRC2+c0e,WCATT_h+(size_t)i*45056,nullptr,SCAT, cnt,352,128, nullptr,nullptr);
      DE_(64,64,3,false,true,false, FA1,ESRC2+c0e,Wv1T_h+(size_t)i*4096,nullptr,SV1, cnt);
      DE_(32,32,5,false,true,false, FA2,ESRC2+c0e,Wv2T_h+(size_t)i*1024,nullptr,SV2, cnt);
      k_bedge<<<GW4(cnt)>>>(SCAT,SV1,SV2, Gc,U,SH2b, DY0,DY1,DY2, EDST2, SSUM,
                            wab+(size_t)i*32, Zc, AB, DGc, DSH1, DSH2, c0e, cnt);
      DG_(false,0,false,false,false,false,false, SCAT,nullptr,WCATD+(size_t)i*45056,nullptr,DE0, cnt,128,352, nullptr,nullptr);
      DG_(true,0,false,false,false,false,false, Zc,nullptr,WaSD+(size_t)i*4096,nullptr,DE0, cnt,128,32, nullptr,nullptr);
      DG_(false,0,false,false,false,false,false, Zc,nullptr,WaDD+(size_t)i*4096,nullptr,DZD, cnt,128,32, nullptr,nullptr);
      DE_(64,64,3,false,false,false, SV1,nullptr,Wv1D+(size_t)i*4096,nullptr,SV1, cnt);
      DE_(32,32,5,false,false,false, SV2,nullptr,Wv2D+(size_t)i*1024,nullptr,SV2, cnt);
      DG_(false,0,false,false,false,false,false, Zc,nullptr,WaED+(size_t)i*2048,nullptr,H2, cnt,64,32, nullptr,nullptr);
      DG_(true,0,false,false,false,true,false, DGc,nullptr,rW3D+(size_t)i*14336,nullptr,H2, cnt,64,224, PRE2,nullptr);
      DG_(false,0,false,false,false,true,false, H2,nullptr,rW2D+(size_t)i*4096,nullptr,H1, cnt,64,64, PRE1,nullptr);
      DG_(false,0,false,false,false,false,false, H1,nullptr,rW1D+(size_t)i*8192,nullptr,DRBF, cnt,128,64, nullptr,nullptr);
      k_dr<<<GW4(cnt)>>>(DRBF,Rr,rbfc,rbfw,DRr, c0e,cnt);
      k_scat<<<dim3(NG),dim3(640),0,stream>>>(DI0,DI1,DI2, DE0,DZD,SV1,SV2, ESRC2,EDST2, c0e,c0e+cnt);
    }
  }

  // ---------------- initial embedding backward ----------------
  for (int cc=0;cc<NCHUNK;cc++){
    int c0e=cc*CH, cnt=CH;
    DG_(false,1,false,false,true,false,true, Rr+c0e,nullptr,degW1T_h,nullptr,H1, cnt,64,128, nullptr,PRE1);
    DG_(false,1,false,false,false,false,true, H1,nullptr,degW2T_h,nullptr,H2, cnt,64,64, nullptr,PRE2);
    DG_(false,0,false,false,false,false,false, H2,nullptr,degW3T_h,nullptr,Gc, cnt,224,64, nullptr,nullptr);
    k_initback<<<GW4(cnt)>>>(DI0,DI1,DI2,EDST2,Gc,U,SH2b,DGc,DSH1,DSH2, c0e,cnt);
    DG_(false,0,false,false,false,true,false, DGc,nullptr,degW3D,nullptr,H2, cnt,64,224, PRE2,nullptr);
    DG_(false,0,false,false,false,true,false, H2,nullptr,degW2D,nullptr,H1, cnt,64,64, PRE1,nullptr);
    DG_(false,0,false,false,false,false,false, H1,nullptr,degW1D,nullptr,DRBF, cnt,128,64, nullptr,nullptr);
    k_dr<<<GW4(cnt)>>>(DRBF,Rr,rbfc,rbfw,DRr, c0e,cnt);
  }

  // ---------------- geometry backward + outputs ----------------
  k_geoback<<<G256(NE)>>>(DRr,DSH1,DSH2,U,Rr,ESRC2,EDST2,DPOS);
  k_forces<<<G256(NN*3)>>>(DPOS,outF);
  (void)in_sizes; (void)n_in; (void)out_size;
}

// Round 17
// 48680.692 us; speedup vs baseline: 1.4753x; 1.4753x over previous
//
#include <hip/hip_runtime.h>
#include <string.h>
#include <math.h>

#define NE 100000
#define NN 8192
#define NG 512
#define CH 12500
#define NCHUNK 8
#define NNC 2048

#define SQ3F  1.7320508075688772f
#define SQ5F  2.23606797749979f
#define SQ15F 3.872983346207417f

__constant__ int c_amap[10] = {-1,0,-1,-1,-1,-1,1,2,3,4};

typedef __attribute__((ext_vector_type(4))) float f32x4;
typedef __attribute__((ext_vector_type(8))) short bf16x8;

__device__ __forceinline__ float sigf(float x){ return 1.0f/(1.0f+expf(-x)); }
__device__ __forceinline__ float siluf(float x){ return x*sigf(x); }
__device__ __forceinline__ float dsiluf(float x){ float s=sigf(x); return s*(1.0f + x*(1.0f-s)); }

__device__ __forceinline__ float wred64(float v){
  #pragma unroll
  for (int o=32;o>0;o>>=1) v += __shfl_down(v,o,64);
  return v;
}
__device__ __forceinline__ int lbound(const int* a, int n, int v){
  int lo=0, hi=n;
  while (lo<hi){ int m=(lo+hi)>>1; if (a[m]<v) lo=m+1; else hi=m; }
  return lo;
}
__device__ __forceinline__ unsigned short f2b(float x){
  unsigned u=__float_as_uint(x);
  unsigned r=(u + 0x7fffu + ((u>>16)&1u))>>16;
  return (unsigned short)r;
}
__device__ __forceinline__ float b2f(unsigned short b){
  return __uint_as_float(((unsigned)b)<<16);
}

// ---------------- edge sort by dst (counting sort) ----------------
__global__ void k_hist(const int* keys, int* hist, int n){
  int i = blockIdx.x*256 + threadIdx.x;
  if (i < n) atomicAdd(&hist[keys[i]], 1);
}
__global__ void k_scan0(const int* hist, int* rows){
  if (threadIdx.x == 0 && blockIdx.x == 0){
    int acc = 0;
    for (int i = 0; i < NN; i++){ rows[i] = acc; acc += hist[i]; }
    rows[NN] = acc;
  }
}
__global__ void k_fillperm(const int* keys, int* cursor, int* perm, int n){
  int i = blockIdx.x*256 + threadIdx.x;
  if (i < n){
    int slot = atomicAdd(&cursor[keys[i]], 1);
    perm[slot] = i;
  }
}
__global__ void k_mkedge(const int* perm, const int* src, const int* dst, int* src2, int* dst2){
  int k = blockIdx.x*256 + threadIdx.x;
  if (k < NE){ int e = perm[k]; src2[k] = src[e]; dst2[k] = dst[e]; }
}

// weight concat: WCATF[i][k][0:352] = [Wv0 | Ws0 | Ws1 | Ws2]
__global__ void k_wcat(const float* Wv0,const float* Ws0,const float* Ws1,const float* Ws2, float* W){
  int t = blockIdx.x*256 + threadIdx.x;
  if (t >= 8*128*352) return;
  int i = t/45056, r = t - i*45056;
  int k = r/352, n = r - k*352;
  float v;
  if (n < 128) v = Wv0[(size_t)i*16384 + k*128 + n];
  else if (n < 256) v = Ws0[(size_t)i*16384 + k*128 + (n-128)];
  else if (n < 320) v = Ws1[(size_t)i*8192 + k*64 + (n-256)];
  else v = Ws2[(size_t)i*4096 + k*32 + (n-320)];
  W[t] = v;
}

// --- bf16 MFMA GEMM; MT = M-tile (64 or 16); SPLIT=3-term split-bf16; ARBF=A computed as RBF(Rr row);
//     DMUL=epilogue *dsilu(dm); PREOUT=write pre-activation to pre[] ---
template<int MT, bool TB, bool ACC, int ACT, bool GATHER, bool SPLIT, bool ARBF, bool DMUL, bool PREOUT>
__global__ __launch_bounds__(256) void k_mgemm(
    const float* __restrict__ A, const int* __restrict__ idx,
    const float* __restrict__ B, float* __restrict__ C,
    int M, int Nd, int K,
    const float* __restrict__ cen, const float* __restrict__ wid,
    const float* __restrict__ dm, float* __restrict__ pre)
{
  constexpr int TPR = 256/MT;     // threads per A-row
  constexpr int EPT = 32/TPR;     // elems per thread (A staging)
  constexpr int RT  = MT/16;      // MFMA row-tiles
  __shared__ unsigned short Asb[(SPLIT?2:1)*MT*40];
  __shared__ unsigned short Btb[(SPLIT?2:1)*2560];
  const int bm = blockIdx.x*MT, bn = blockIdx.y*64;
  const int tid = threadIdx.x;
  const int wave = tid>>6, lane = tid&63;
  const int arow_s = tid / TPR, aoff = (tid % TPR) * EPT;
  const int bsrow = tid>>2, bsoff = (tid&3)*8;
  f32x4 acc[RT];
  #pragma unroll
  for (int r=0;r<RT;r++) acc[r] = (f32x4){0.f,0.f,0.f,0.f};
  int arow = -1;
  {
    int gr = bm + arow_s;
    if (gr < M) arow = GATHER ? idx[gr] : gr;
  }
  int bcol = bn + bsrow;
  for (int k0=0;k0<K;k0+=32){
    #pragma unroll
    for (int i=0;i<EPT;i++){
      float v = 0.0f;
      if (arow>=0){
        if (ARBF){
          float r = A[arow];
          int kk = k0 + aoff + i;
          float t = (r - cen[kk]) / wid[kk];
          v = expf(-0.5f*t*t);
        } else {
          v = A[(size_t)arow*K + k0 + aoff + i];
        }
      }
      unsigned short h = f2b(v);
      Asb[arow_s*40 + aoff + i] = h;
      if (SPLIT) Asb[MT*40 + arow_s*40 + aoff + i] = f2b(v - b2f(h));
    }
    #pragma unroll
    for (int i=0;i<8;i++){
      float v = 0.0f;
      if (bcol < Nd) v = TB ? B[(size_t)bcol*K + k0 + bsoff + i] : B[(size_t)(k0+bsoff+i)*Nd + bcol];
      unsigned short h = f2b(v);
      Btb[bsrow*40 + bsoff + i] = h;
      if (SPLIT) Btb[2560 + bsrow*40 + bsoff + i] = f2b(v - b2f(h));
    }
    __syncthreads();
    int boff = (wave*16 + (lane&15))*40 + (lane>>4)*8;
    bf16x8 bh = *(const bf16x8*)&Btb[boff];
    #pragma unroll
    for (int r=0;r<RT;r++){
      int aoff2 = (r*16 + (lane&15))*40 + (lane>>4)*8;
      bf16x8 ah = *(const bf16x8*)&Asb[aoff2];
      acc[r] = __builtin_amdgcn_mfma_f32_16x16x32_bf16(ah, bh, acc[r], 0,0,0);
      if (SPLIT){
        bf16x8 bl = *(const bf16x8*)&Btb[2560 + boff];
        bf16x8 al = *(const bf16x8*)&Asb[MT*40 + aoff2];
        acc[r] = __builtin_amdgcn_mfma_f32_16x16x32_bf16(ah, bl, acc[r], 0,0,0);
        acc[r] = __builtin_amdgcn_mfma_f32_16x16x32_bf16(al, bh, acc[r], 0,0,0);
      }
    }
    __syncthreads();
  }
  int col = bn + wave*16 + (lane&15);
  if (col < Nd){
    #pragma unroll
    for (int r=0;r<RT;r++){
      #pragma unroll
      for (int v=0;v<4;v++){
        int row = bm + r*16 + (lane>>4)*4 + v;
        if (row >= M) continue;
        size_t o = (size_t)row*Nd + col;
        float x = acc[r][v];
        if (ACC) x += C[o];
        if (DMUL) x *= dsiluf(dm[o]);
        if (PREOUT) pre[o] = x;
        if (ACT == 1) x = siluf(x);
        else if (ACT == 2) x = tanhf(x);
        else if (ACT == 3) x = sigf(x);
        C[o] = x;
      }
    }
  }
}

// ---------- bf16 MFMA einsum (X-strided rows); SPLIT => split-bf16 ----------
template<int CI, int CO, int X, bool TB, bool ACC, bool GATHER, bool SPLIT>
__global__ __launch_bounds__(256) void k_meinsum(
    const float* __restrict__ A, const int* __restrict__ idx,
    const float* __restrict__ W, float* __restrict__ C, int M)
{
  __shared__ unsigned short Asb[(SPLIT?2:1)*2560];
  __shared__ unsigned short Btb[(SPLIT?2:1)*2560];
  const int bm = blockIdx.x*64;
  const int tid = threadIdx.x, wave = tid>>6, lane = tid&63;
  const int srow = tid>>2, soff = (tid&3)*8;
  f32x4 acc[4];
  #pragma unroll
  for (int r=0;r<4;r++) acc[r] = (f32x4){0.f,0.f,0.f,0.f};
  long abase = -1;
  {
    int grow = bm + srow;
    if (grow < M*X){
      int ge = grow / X, gx = grow - ge*X;
      int ar = GATHER ? idx[ge] : ge;
      abase = (long)ar*CI*X + gx;
    }
  }
  for (int k0=0;k0<CI;k0+=32){
    #pragma unroll
    for (int i=0;i<8;i++){
      float v = (abase>=0) ? A[abase + (size_t)(k0+soff+i)*X] : 0.0f;
      unsigned short h = f2b(v);
      Asb[srow*40 + soff + i] = h;
      if (SPLIT) Asb[2560 + srow*40 + soff + i] = f2b(v - b2f(h));
    }
    #pragma unroll
    for (int i=0;i<8;i++){
      int kk = k0 + soff + i;
      float v = 0.0f;
      if (srow < CO) v = TB ? W[srow*CI + kk] : W[kk*CO + srow];
      unsigned short h = f2b(v);
      Btb[srow*40 + soff + i] = h;
      if (SPLIT) Btb[2560 + srow*40 + soff + i] = f2b(v - b2f(h));
    }
    __syncthreads();
    int boff = (wave*16 + (lane&15))*40 + (lane>>4)*8;
    bf16x8 bh = *(const bf16x8*)&Btb[boff];
    #pragma unroll
    for (int r=0;r<4;r++){
      int aoff = (r*16 + (lane&15))*40 + (lane>>4)*8;
      bf16x8 ah = *(const bf16x8*)&Asb[aoff];
      acc[r] = __builtin_amdgcn_mfma_f32_16x16x32_bf16(ah, bh, acc[r], 0,0,0);
      if (SPLIT){
        bf16x8 bl = *(const bf16x8*)&Btb[2560 + boff];
        bf16x8 al = *(const bf16x8*)&Asb[2560 + aoff];
        acc[r] = __builtin_amdgcn_mfma_f32_16x16x32_bf16(ah, bl, acc[r], 0,0,0);
        acc[r] = __builtin_amdgcn_mfma_f32_16x16x32_bf16(al, bh, acc[r], 0,0,0);
      }
    }
    __syncthreads();
  }
  int col = wave*16 + (lane&15);
  if (col < CO){
    #pragma unroll
    for (int r=0;r<4;r++){
      #pragma unroll
      for (int v=0;v<4;v++){
        int row = bm + r*16 + (lane>>4)*4 + v;
        if (row >= M*X) continue;
        int ge = row / X, gx = row - ge*X;
        size_t o = (size_t)ge*CO*X + (size_t)col*X + gx;
        float xx = acc[r][v];
        if (ACC) xx += C[o];
        C[o] = xx;
      }
    }
  }
}

// ------------------------- small kernels -------------------------
__global__ void k_sentinel(float* o, int n, float v){
  int i = blockIdx.x*256 + threadIdx.x;
  if (i < n) o[i] = v;
}

__global__ void k_geom(const float* __restrict__ pos, const int* __restrict__ src, const int* __restrict__ dst,
                       float* __restrict__ U, float* __restrict__ Rr, float* __restrict__ SH2b){
  int e = blockIdx.x*256 + threadIdx.x;
  if (e >= NE) return;
  int s = src[e], d = dst[e];
  float vx = pos[s*3+0]-pos[d*3+0];
  float vy = pos[s*3+1]-pos[d*3+1];
  float vz = pos[s*3+2]-pos[d*3+2];
  float r = sqrtf(vx*vx+vy*vy+vz*vz + 1e-12f);
  float ux=vx/r, uy=vy/r, uz=vz/r;
  U[e*3+0]=ux; U[e*3+1]=uy; U[e*3+2]=uz;
  Rr[e]=r;
  SH2b[e*5+0]=SQ15F*ux*uy;
  SH2b[e*5+1]=SQ15F*uy*uz;
  SH2b[e*5+2]=0.5f*SQ5F*(3.0f*uz*uz-1.0f);
  SH2b[e*5+3]=SQ15F*ux*uz;
  SH2b[e*5+4]=0.5f*SQ15F*(ux*ux-uy*uy);
}

__global__ void k_f0init(const int* __restrict__ na, const float* __restrict__ at, float* __restrict__ f0){
  int t = blockIdx.x*256 + threadIdx.x;
  if (t >= NN*128) return;
  int n = t>>7, j = t&127;
  int m = c_amap[na[n]];
  f0[t] = at[m*128+j];
}

// lambda -> p = exp(lambda)
__global__ void k_lambda(const float* __restrict__ Z, const float* __restrict__ wa, float* __restrict__ P_c, int cnt){
  int e = blockIdx.x*256 + threadIdx.x;
  if (e >= cnt) return;
  float s = 0.0f;
  #pragma unroll
  for (int k=0;k<32;k++) s += Z[e*32+k]*wa[k];
  P_c[e] = expf(s);
}

__global__ void k_norm(const float* __restrict__ P, const float* __restrict__ S,
                       const int* __restrict__ dst, float* __restrict__ AB){
  int e = blockIdx.x*256 + threadIdx.x;
  if (e < NE) AB[e] = P[e]/(S[dst[e]]+1e-9f);
}

__global__ void k_finy(const float* __restrict__ x0,const float* __restrict__ x1,const float* __restrict__ x2,
                       float* __restrict__ y0,float* __restrict__ y1,float* __restrict__ y2,
                       const float* __restrict__ S){
  int t = blockIdx.x*256 + threadIdx.x;
  if (t >= NN*480) return;
  if (t < NN*128){ int n=t>>7; y0[t]=x0[t]+y0[t]/(S[n]+1e-9f); }
  else if (t < NN*320){ int q=t-NN*128; int n=q/192; y1[q]=x1[q]+y1[q]/(S[n]+1e-9f); }
  else { int q=t-NN*320; int n=q/160; y2[q]=x2[q]+y2[q]/(S[n]+1e-9f); }
}

// bf16 checkpoint quant/dequant
__global__ void k_q3(const float* __restrict__ f0,const float* __restrict__ f1,const float* __restrict__ f2,
                     unsigned short* __restrict__ ck){
  int t = blockIdx.x*256 + threadIdx.x;
  if (t >= NN*480) return;
  float v;
  if (t < NN*128) v = f0[t];
  else if (t < NN*320) v = f1[t-NN*128];
  else v = f2[t-NN*320];
  ck[t] = f2b(v);
}
__global__ void k_dq3(const unsigned short* __restrict__ ck,
                      float* __restrict__ f0,float* __restrict__ f1,float* __restrict__ f2){
  int t = blockIdx.x*256 + threadIdx.x;
  if (t >= NN*480) return;
  float v = b2f(ck[t]);
  if (t < NN*128) f0[t]=v;
  else if (t < NN*320) f1[t-NN*128]=v;
  else f2[t-NN*320]=v;
}

// per-graph aggregation; SC strided 352 [sv0|sw0|sw1|sw2]; accumulates S in lanes 480..495
template<bool INIT>
__global__ __launch_bounds__(512) void k_agg(
  float* __restrict__ f0o,float* __restrict__ f1o,float* __restrict__ f2o,
  const float* __restrict__ SC,const float* __restrict__ sv1,const float* __restrict__ sv2,
  const float* __restrict__ g,const float* __restrict__ U,const float* __restrict__ SH2b,
  const float* __restrict__ aArr,const int* __restrict__ keys,const int* __restrict__ dst,
  float* __restrict__ SACC, int c0, int c1)
{
  __shared__ float acc[7680];
  int b = blockIdx.x, lo = b<<4;
  int e0 = lbound(keys, NE, lo), e1 = lbound(keys, NE, lo+16);
  if (e0 < c0) e0 = c0;
  if (e1 > c1) e1 = c1;
  if (e0 >= e1) return;
  for (int i=threadIdx.x;i<7680;i+=512) acc[i]=0.0f;
  __syncthreads();
  const int j = threadIdx.x;
  const float inv = 1.0f/sqrtf(15.57f);
  int cat=3, cc_=0, xx_=0;
  if (j<128){ cat=0; }
  else if (j<320){ cat=1; int t=j-128; cc_=t/3; xx_=t-3*cc_; }
  else if (j<480){ cat=2; int t=j-320; cc_=t/5; xx_=t-5*cc_; }
  float sacc=0.0f;
  for (int e=e0; e<e1; ++e){
    int el = e - c0;
    float a = INIT ? inv : aArr[e];
    int nl = dst[e]&15;
    if (cat==0){
      float m = INIT ? g[el*224+j] : (SC[(size_t)el*352+j]*g[el*224+j] + SC[(size_t)el*352+128+j]);
      acc[nl*480+j] += a*m;
    } else if (cat==1){
      int t=j-128;
      float sh = SQ3F*U[e*3+xx_];
      float m = INIT ? g[el*224+128+cc_]*sh : (sv1[el*192+t]*g[el*224+128+cc_] + SC[(size_t)el*352+256+cc_]*sh);
      acc[nl*480+j] += a*m;
    } else if (cat==2){
      int t=j-320;
      float sh = SH2b[e*5+xx_];
      float m = INIT ? g[el*224+192+cc_]*sh : (sv2[el*160+t]*g[el*224+192+cc_] + SC[(size_t)el*352+320+cc_]*sh);
      acc[nl*480+j] += a*m;
    } else if (!INIT && j<496){
      if (nl==(j-480)) sacc += a;
    }
  }
  __syncthreads();
  for (int i=threadIdx.x;i<7680;i+=512){
    int nl=i/480, jj=i-480*nl, n=lo+nl;
    float v=acc[i];
    if (jj<128) f0o[n*128+jj]+=v;
    else if (jj<320) f1o[n*192+jj-128]+=v;
    else f2o[n*160+jj-320]+=v;
  }
  if (!INIT && j>=480 && j<496) SACC[lo+(j-480)] += sacc;
}

// per-graph scatter of edge grads
__global__ __launch_bounds__(640) void k_scat(
  float* __restrict__ df0, float* __restrict__ df1, float* __restrict__ df2,
  const float* __restrict__ DE0, const float* __restrict__ DZD,
  const float* __restrict__ DE1, const float* __restrict__ DE2,
  const int* __restrict__ src, const int* __restrict__ dst, int c0, int c1)
{
  __shared__ float acc[7680];
  int b=blockIdx.x, lo=b<<4;
  int e0=lbound(dst,NE,lo), e1=lbound(dst,NE,lo+16);
  if (e0 < c0) e0 = c0;
  if (e1 > c1) e1 = c1;
  for (int i=threadIdx.x;i<7680;i+=640) acc[i]=0.0f;
  __syncthreads();
  const int j=threadIdx.x;
  for (int e=e0;e<e1;++e){
    int el=e-c0;
    int sl=(src[e]&15)*480, dl=(dst[e]&15)*480;
    if (j<128) acc[sl+j] += DE0[el*128+j];
    else if (j<256){ int q=j-128; acc[dl+q] += DZD[el*128+q]; }
    else if (j<448){ int q=j-256; acc[sl+128+q] += DE1[el*192+q]; }
    else if (j<608){ int q=j-448; acc[sl+320+q] += DE2[el*160+q]; }
    __syncthreads();
  }
  for (int i=threadIdx.x;i<7680;i+=640){
    int nl=i/480, jj=i-480*nl, n=lo+nl;
    float v=acc[i];
    if (jj<128) df0[n*128+jj]+=v;
    else if (jj<320) df1[n*192+jj-128]+=v;
    else df2[n*160+jj-320]+=v;
  }
}

// SSUM[n] = (FB[n]-FA[n]) . DY[n]
__global__ __launch_bounds__(256) void k_ssum(
  const float* __restrict__ FA0,const float* __restrict__ FA1,const float* __restrict__ FA2,
  const float* __restrict__ FB0,const float* __restrict__ FB1,const float* __restrict__ FB2,
  const float* __restrict__ DY0,const float* __restrict__ DY1,const float* __restrict__ DY2,
  float* __restrict__ SSUM)
{
  int n=blockIdx.x*4+(threadIdx.x>>6), lane=threadIdx.x&63;
  if (n>=NN) return;
  float s=0.0f;
  for (int j=lane;j<480;j+=64){
    float d,g;
    if (j<128){ d=FB0[n*128+j]-FA0[n*128+j]; g=DY0[n*128+j]; }
    else if (j<320){ int q=j-128; d=FB1[n*192+q]-FA1[n*192+q]; g=DY1[n*192+q]; }
    else { int q=j-320; d=FB2[n*160+q]-FA2[n*160+q]; g=DY2[n*160+q]; }
    s += d*g;
  }
  s = wred64(s);
  if (lane==0) SSUM[n]=s;
}

// fused backward edge chain: da -> dlam -> dz -> split0/1/2 ; one wave per edge
__global__ __launch_bounds__(256) void k_bedge(
  float* __restrict__ SC, float* __restrict__ SV1, float* __restrict__ SV2,
  const float* __restrict__ g, const float* __restrict__ U, const float* __restrict__ SH2b,
  const float* __restrict__ df0,const float* __restrict__ df1,const float* __restrict__ df2,
  const int* __restrict__ dst, const float* __restrict__ SSUM, const float* __restrict__ wa,
  float* __restrict__ Z, const float* __restrict__ aArr,
  float* __restrict__ DG, float* __restrict__ DSH1, float* __restrict__ DSH2,
  int c0, int cnt)
{
  int w=threadIdx.x>>6, lane=threadIdx.x&63;
  int el=blockIdx.x*4+w;
  if (el>=cnt) return;
  int e=c0+el;
  int d=dst[e];
  float s=0.0f;
  for (int j=lane;j<480;j+=64){
    float m, dfv;
    if (j<128){
      m = SC[(size_t)el*352+j]*g[el*224+j] + SC[(size_t)el*352+128+j];
      dfv = df0[(size_t)d*128+j];
    } else if (j<320){
      int t=j-128, c=t/3, x=t-3*c;
      m = SV1[el*192+t]*g[el*224+128+c] + SC[(size_t)el*352+256+c]*(SQ3F*U[e*3+x]);
      dfv = df1[(size_t)d*192+t];
    } else {
      int t=j-320, c=t/5, x=t-5*c;
      m = SV2[el*160+t]*g[el*224+192+c] + SC[(size_t)el*352+320+c]*SH2b[e*5+x];
      dfv = df2[(size_t)d*160+t];
    }
    s += m*dfv;
  }
  s = wred64(s);
  s = __shfl(s,0,64);
  float a = aArr[e];
  float dlam = a*(s - SSUM[d]);
  if (lane<32){
    float z = Z[(size_t)el*32+lane];
    Z[(size_t)el*32+lane] = dlam*wa[lane]*(1.0f-z*z);
  }
  {
    float* row = SC + (size_t)el*352;
    for (int j=lane;j<128;j+=64){
      float dm = a*df0[(size_t)d*128+j];
      float sv = row[j];
      row[128+j] = dm;
      row[j] = dm*g[el*224+j];
      DG[el*224+j] = dm*sv;
    }
  }
  {
    float dm0=a*df1[(size_t)d*192+lane*3+0];
    float dm1=a*df1[(size_t)d*192+lane*3+1];
    float dm2=a*df1[(size_t)d*192+lane*3+2];
    float sw1o=SC[(size_t)el*352+256+lane];
    float g1=g[el*224+128+lane];
    float c0v=dm0*sw1o, c1v=dm1*sw1o, c2v=dm2*sw1o;
    c0v=wred64(c0v); c1v=wred64(c1v); c2v=wred64(c2v);
    if (lane==0){ DSH1[e*3+0]+=c0v; DSH1[e*3+1]+=c1v; DSH1[e*3+2]+=c2v; }
    float sh0=SQ3F*U[e*3+0], sh1=SQ3F*U[e*3+1], sh2=SQ3F*U[e*3+2];
    SC[(size_t)el*352+256+lane]=dm0*sh0+dm1*sh1+dm2*sh2;
    float sv0o=SV1[el*192+lane*3+0], sv1o=SV1[el*192+lane*3+1], sv2o=SV1[el*192+lane*3+2];
    DG[el*224+128+lane]=dm0*sv0o+dm1*sv1o+dm2*sv2o;
    SV1[el*192+lane*3+0]=dm0*g1; SV1[el*192+lane*3+1]=dm1*g1; SV1[el*192+lane*3+2]=dm2*g1;
  }
  {
    float dm[5]={0,0,0,0,0}, svo[5]={0,0,0,0,0};
    float sw2o=0.0f, g2=0.0f;
    if (lane<32){
      #pragma unroll
      for (int x=0;x<5;x++){ dm[x]=a*df2[(size_t)d*160+lane*5+x]; svo[x]=SV2[el*160+lane*5+x]; }
      sw2o=SC[(size_t)el*352+320+lane]; g2=g[el*224+192+lane];
    }
    float c[5];
    #pragma unroll
    for (int x=0;x<5;x++){ c[x]=dm[x]*sw2o; c[x]=wred64(c[x]); }
    if (lane==0){
      #pragma unroll
      for (int x=0;x<5;x++) DSH2[e*5+x]+=c[x];
    }
    if (lane<32){
      float dsw=0.0f, dg2=0.0f;
      #pragma unroll
      for (int x=0;x<5;x++){ dsw+=dm[x]*SH2b[e*5+x]; dg2+=dm[x]*svo[x]; }
      SC[(size_t)el*352+320+lane]=dsw;
      DG[el*224+192+lane]=dg2;
      #pragma unroll
      for (int x=0;x<5;x++) SV2[el*160+lane*5+x]=dm[x]*g2;
    }
  }
}

template<int CD,int X>
__global__ void k_gatefwd(float* __restrict__ f, const float* __restrict__ V, const float* __restrict__ P){
  int t=blockIdx.x*256+threadIdx.x;
  const int ox=CD*X;
  if (t>=NN*ox) return;
  int n=t/ox, rem=t-n*ox, d=rem/X;
  f[t] += V[t]*P[n*CD+d];
}

template<int CD,int X>
__global__ void k_gateback(const float* __restrict__ dfB, float* __restrict__ V,
                           const float* __restrict__ P, float* __restrict__ DPa){
  int t=blockIdx.x*256+threadIdx.x;
  if (t>=NN*CD) return;
  float p=P[t];
  float dp=0.0f;
  #pragma unroll
  for (int x=0;x<X;x++){ dp += dfB[t*X+x]*V[t*X+x]; }
  #pragma unroll
  for (int x=0;x<X;x++){ V[t*X+x] = dfB[t*X+x]*p; }
  DPa[t] = dp*p*(1.0f-p);
}

__global__ __launch_bounds__(256) void k_dr(const float* __restrict__ DRBF, const float* __restrict__ Rr,
    const float* __restrict__ cen, const float* __restrict__ wid, float* __restrict__ DRa, int c0, int cnt){
  int w=threadIdx.x>>6, lane=threadIdx.x&63;
  int el=blockIdx.x*4+w;
  if (el>=cnt) return;
  int e=c0+el;
  float r=Rr[e], s=0.0f;
  for (int k=lane;k<128;k+=64){
    float c=cen[k], wd=wid[k];
    float t=(r-c)/wd;
    float rb=expf(-0.5f*t*t);
    s += DRBF[el*128+k]*rb*((c-r)/(wd*wd));
  }
  s=wred64(s);
  if (lane==0) DRa[e]+=s;
}

__global__ __launch_bounds__(256) void k_initback(
  const float* __restrict__ df0,const float* __restrict__ df1,const float* __restrict__ df2,
  const int* __restrict__ dst,
  const float* __restrict__ g,const float* __restrict__ U,const float* __restrict__ SH2b,
  float* __restrict__ DG,float* __restrict__ DSH1,float* __restrict__ DSH2, int c0, int cnt)
{
  int w=threadIdx.x>>6, lane=threadIdx.x&63;
  int el=blockIdx.x*4+w;
  if (el>=cnt) return;
  int e=c0+el;
  int d=dst[e];
  const float inv=1.0f/sqrtf(15.57f);
  for (int j=lane;j<128;j+=64) DG[el*224+j]=inv*df0[d*128+j];
  float sh0=SQ3F*U[e*3+0], sh1=SQ3F*U[e*3+1], sh2=SQ3F*U[e*3+2];
  float df10=df1[d*192+lane*3+0], df11=df1[d*192+lane*3+1], df12=df1[d*192+lane*3+2];
  float g1=g[el*224+128+lane];
  DG[el*224+128+lane]=inv*(df10*sh0+df11*sh1+df12*sh2);
  float c0v=g1*df10, c1v=g1*df11, c2v=g1*df12;
  c0v=wred64(c0v); c1v=wred64(c1v); c2v=wred64(c2v);
  if (lane==0){ DSH1[e*3+0]+=inv*c0v; DSH1[e*3+1]+=inv*c1v; DSH1[e*3+2]+=inv*c2v; }
  float cc[5]={0,0,0,0,0};
  if (lane<32){
    float g2=g[el*224+192+lane];
    float dgv=0.0f;
    #pragma unroll
    for (int x=0;x<5;x++){ float dfv=df2[d*160+lane*5+x]; dgv+=dfv*SH2b[e*5+x]; cc[x]=g2*dfv; }
    DG[el*224+192+lane]=inv*dgv;
  }
  #pragma unroll
  for (int x=0;x<5;x++) cc[x]=wred64(cc[x]);
  if (lane==0){
    #pragma unroll
    for (int x=0;x<5;x++) DSH2[e*5+x]+=inv*cc[x];
  }
}

__global__ void k_geoback(const float* __restrict__ DRa, const float* __restrict__ DSH1, const float* __restrict__ DSH2,
                          const float* __restrict__ U, const float* __restrict__ Rr,
                          const int* __restrict__ src, const int* __restrict__ dst,
                          float* __restrict__ DPOS){
  int e=blockIdx.x*256+threadIdx.x;
  if (e>=NE) return;
  float ux=U[e*3+0], uy=U[e*3+1], uz=U[e*3+2];
  float r=Rr[e];
  float dux=SQ3F*DSH1[e*3+0], duy=SQ3F*DSH1[e*3+1], duz=SQ3F*DSH1[e*3+2];
  float d0=DSH2[e*5+0],d1=DSH2[e*5+1],d2=DSH2[e*5+2],d3=DSH2[e*5+3],d4=DSH2[e*5+4];
  dux += SQ15F*(uy*d0+uz*d3+ux*d4);
  duy += SQ15F*(ux*d0+uz*d1-uy*d4);
  duz += SQ15F*(uy*d1+ux*d3)+3.0f*SQ5F*uz*d2;
  float dr=DRa[e];
  float dot=dux*ux+duy*uy+duz*uz;
  float dvx=(dux-dot*ux)/r+dr*ux;
  float dvy=(duy-dot*uy)/r+dr*uy;
  float dvz=(duz-dot*uz)/r+dr*uz;
  int s=src[e], d=dst[e];
  atomicAdd(&DPOS[s*3+0],dvx); atomicAdd(&DPOS[s*3+1],dvy); atomicAdd(&DPOS[s*3+2],dvz);
  atomicAdd(&DPOS[d*3+0],-dvx); atomicAdd(&DPOS[d*3+1],-dvy); atomicAdd(&DPOS[d*3+2],-dvz);
}

__global__ void k_forces(const float* __restrict__ DPOS, float* __restrict__ o){
  int i=blockIdx.x*256+threadIdx.x;
  if (i<NN*3) o[i]=-DPOS[i];
}

// per-node LN + head forward + backward seeds; single wave per node
__global__ __launch_bounds__(64) void k_lnhead(
  const float* __restrict__ f0,const float* __restrict__ f1,const float* __restrict__ f2,
  const float* __restrict__ lng,const float* __restrict__ lnb,
  const float* __restrict__ W0,const float* __restrict__ hout,
  float* __restrict__ EN, float* __restrict__ df0,float* __restrict__ df1,float* __restrict__ df2)
{
  __shared__ float xh[480];
  __shared__ float fl[128];
  __shared__ float dyv[128];
  __shared__ float dxh[128];
  int n=blockIdx.x, lane=threadIdx.x;
  const float c0=1.0f/sqrtf(18.03f);
  for (int i=lane;i<480;i+=64){
    float v=(i<128)? f0[n*128+i] : (i<320)? f1[n*192+(i-128)] : f2[n*160+(i-320)];
    xh[i]=v;
  }
  __syncthreads();
  float s1=0.0f,s2=0.0f;
  for (int i=lane;i<480;i+=64){ float v=xh[i]; s1+=v; s2+=v*v; }
  s1=wred64(s1); s2=wred64(s2);
  float mu=__shfl(s1,0,64)*(1.0f/480.0f);
  float var=__shfl(s2,0,64)*(1.0f/480.0f)-mu*mu;
  float rstd=rsqrtf(var+1e-5f);
  for (int i=lane;i<480;i+=64) xh[i]=(xh[i]-mu)*rstd;
  __syncthreads();
  for (int k=lane;k<128;k+=64) fl[k]=xh[k]*lng[k]+lnb[k];
  __syncthreads();
  float y0=0.0f,y1=0.0f;
  for (int k=0;k<128;k++){ float f=fl[k]; y0+=f*W0[k*128+lane]; y1+=f*W0[k*128+lane+64]; }
  float e = siluf(y0)*hout[lane] + siluf(y1)*hout[lane+64];
  e=wred64(e);
  if (lane==0) EN[n]=e*c0;
  dyv[lane]=c0*hout[lane]*dsiluf(y0);
  dyv[lane+64]=c0*hout[lane+64]*dsiluf(y1);
  __syncthreads();
  float d0=0.0f,d1=0.0f;
  for (int j=0;j<128;j++){ float dv=dyv[j]; d0+=dv*W0[lane*128+j]; d1+=dv*W0[(lane+64)*128+j]; }
  dxh[lane]=d0*lng[lane];
  dxh[lane+64]=d1*lng[lane+64];
  __syncthreads();
  float s3=dxh[lane]+dxh[lane+64];
  float s4=dxh[lane]*xh[lane]+dxh[lane+64]*xh[lane+64];
  s3=wred64(s3); s4=wred64(s4);
  float m1=__shfl(s3,0,64)*(1.0f/480.0f);
  float m2=__shfl(s4,0,64)*(1.0f/480.0f);
  for (int i=lane;i<480;i+=64){
    float dv=rstd*(((i<128)?dxh[i]:0.0f)-m1-xh[i]*m2);
    if (i<128) df0[n*128+i]=dv;
    else if (i<320) df1[n*192+(i-128)]=dv;
    else df2[n*160+(i-320)]=dv;
  }
}

__global__ void k_esum(const float* __restrict__ EN, float* __restrict__ out){
  int b=blockIdx.x*64+threadIdx.x;
  if (b<NG){
    float s=0.0f;
    for (int k=0;k<16;k++) s+=EN[b*16+k];
    out[b]=s;
  }
}

#define MG(MT,TB,ACC,ACT,GA,SP,AR,DM,PO, A,IDX,B,C,M,Nd,K, CEN,WID,DMp,POp) \
  k_mgemm<MT,TB,ACC,ACT,GA,SP,AR,DM,PO><<<dim3((unsigned)(((M)+(MT)-1)/(MT)),(unsigned)(((Nd)+63)/64)),dim3(256),0,stream>>>((A),(IDX),(B),(C),(M),(Nd),(K),(CEN),(WID),(DMp),(POp))
#define MGEMM(TB,ACC,ACT,GA, A,IDX,B,C,M,Nd,K) MG(16,TB,ACC,ACT,GA,false,false,false,false, A,IDX,B,C,M,Nd,K, nullptr,nullptr,nullptr,nullptr)
#define MGEMM3(TB,ACC,ACT,GA, A,IDX,B,C,M,Nd,K) MG(16,TB,ACC,ACT,GA,true,false,false,false, A,IDX,B,C,M,Nd,K, nullptr,nullptr,nullptr,nullptr)
#define MEINS(CI,CO,X,TB,ACC,GA, A,IDX,Wt,C,M) \
  k_meinsum<CI,CO,X,TB,ACC,GA,false><<<dim3((unsigned)(((M)*(X)+63)/64)),dim3(256),0,stream>>>((A),(IDX),(Wt),(C),(M))
#define MEINS3(CI,CO,X,TB,ACC,GA, A,IDX,Wt,C,M) \
  k_meinsum<CI,CO,X,TB,ACC,GA,true><<<dim3((unsigned)(((M)*(X)+63)/64)),dim3(256),0,stream>>>((A),(IDX),(Wt),(C),(M))
#define G256(n) dim3((unsigned)(((n)+255)/256)),dim3(256),0,stream
#define GW4(n) dim3((unsigned)(((n)+3)/4)),dim3(256),0,stream

extern "C" void kernel_launch(void* const* d_in, const int* in_sizes, int n_in,
                              void* d_out, int out_size, void* d_ws, size_t ws_size,
                              hipStream_t stream)
{
  const float* pos =(const float*)d_in[0];
  const float* atab=(const float*)d_in[1];
  const float* rbfc=(const float*)d_in[2];
  const float* rbfw=(const float*)d_in[3];
  const float* degW1=(const float*)d_in[4];
  const float* degW2=(const float*)d_in[5];
  const float* degW3=(const float*)d_in[6];
  const float* Wv0=(const float*)d_in[7];
  const float* Wv1=(const float*)d_in[8];
  const float* Wv2=(const float*)d_in[9];
  const float* Ws0=(const float*)d_in[10];
  const float* Ws1=(const float*)d_in[11];
  const float* Ws2=(const float*)d_in[12];
  const float* rW1=(const float*)d_in[13];
  const float* rW2=(const float*)d_in[14];
  const float* rW3=(const float*)d_in[15];
  const float* WaS=(const float*)d_in[16];
  const float* WaD=(const float*)d_in[17];
  const float* WaE=(const float*)d_in[18];
  const float* wab=(const float*)d_in[19];
  const float* ff1=(const float*)d_in[20];
  const float* ff2=(const float*)d_in[21];
  const float* fg1=(const float*)d_in[22];
  const float* fg2=(const float*)d_in[23];
  const float* fW1=(const float*)d_in[24];
  const float* fW2=(const float*)d_in[25];
  const float* lng=(const float*)d_in[26];
  const float* lnb=(const float*)d_in[27];
  const float* W0h=(const float*)d_in[28];
  const float* hout=(const float*)d_in[29];
  const int* natom=(const int*)d_in[30];
  const int* esrc=(const int*)d_in[31];
  const int* edst=(const int*)d_in[32];

  float* Wp=(float*)d_ws;
  size_t off=0;
  auto al=[&](size_t n)->float*{ float* q=Wp+off; off+=n; return q; };

  const size_t SLOT = (size_t)NN*480;
  unsigned short* CKB = (unsigned short*)al((9*SLOT+1)/2);
  float* FA0=al((size_t)NN*128); float* FA1=al((size_t)NN*192); float* FA2=al((size_t)NN*160);
  float* FB0=al((size_t)NN*128); float* FB1=al((size_t)NN*192); float* FB2=al((size_t)NN*160);
  float* F0N=al((size_t)NN*128);
  float* DI0=al((size_t)NN*128); float* DI1=al((size_t)NN*192); float* DI2=al((size_t)NN*160);
  float* DY0=al((size_t)NN*128); float* DY1=al((size_t)NN*192); float* DY2=al((size_t)NN*160);
  float* TBc=al((size_t)NNC*512); float* DTc=al((size_t)NNC*512);
  float* P1=al((size_t)NN*64); float* P2=al((size_t)NN*32);
  float* V1=al((size_t)NN*192); float* V2=al((size_t)NN*160);
  float* DPb=al((size_t)NN*64);
  float* U=al((size_t)NE*3); float* Rr=al(NE); float* SH2b=al((size_t)NE*5);
  float* ABLK=al(8ULL*NE); float* LAM=al(NE);
  float* SSUM=al(NN); float* ENODE=al(NN); float* SACC=al(NN);
  float* DRr=al(NE); float* DSH1=al((size_t)NE*3); float* DSH2=al((size_t)NE*5);
  float* DPOS=al((size_t)NN*3);
  float* WCATF=al(8ULL*128*352);
  float* RBFc=al((size_t)CH*128);
  float* PRE1=al((size_t)CH*64); float* PRE2=al((size_t)CH*64);
  float* H1=al((size_t)CH*64);  float* H2=al((size_t)CH*64);
  float* Gc=al((size_t)CH*224); float* DGc=al((size_t)CH*224);
  float* SCAT=al((size_t)CH*352);
  float* SV1=al((size_t)CH*192); float* SV2=al((size_t)CH*160);
  float* Zc=al((size_t)CH*32);  float* DE0=al((size_t)CH*128);
  float* DZD=al((size_t)CH*128);
  int* ROWS =(int*)al(NN+1);
  int* CNT  =(int*)al(NN);
  int* POSB =(int*)al(NN);
  int* PERMB=(int*)al(NE);
  int* ESRC2=(int*)al(NE);
  int* EDST2=(int*)al(NE);

  float* outE=(float*)d_out;
  float* outF=outE+NG;

  if (off*sizeof(float) > ws_size){
    k_sentinel<<<G256(out_size)>>>(outE, out_size, (float)ws_size);
    return;
  }

  // ---------------- sort edges by dst ----------------
  (void)hipMemsetAsync(CNT,0,NN*sizeof(int),stream);
  k_hist<<<G256(NE)>>>(edst,CNT,NE);
  k_scan0<<<dim3(1),dim3(64),0,stream>>>(CNT,ROWS);
  (void)hipMemcpyAsync(POSB,ROWS,NN*sizeof(int),hipMemcpyDeviceToDevice,stream);
  k_fillperm<<<G256(NE)>>>(edst,POSB,PERMB,NE);
  k_mkedge<<<G256(NE)>>>(PERMB,esrc,edst,ESRC2,EDST2);
  k_wcat<<<G256(8*128*352)>>>(Wv0,Ws0,Ws1,Ws2,WCATF);

  // ---------------- setup ----------------
  k_geom<<<G256(NE)>>>(pos,ESRC2,EDST2,U,Rr,SH2b);
  k_f0init<<<G256(NN*128)>>>(natom,atab,FA0);
  (void)hipMemsetAsync(FA1,0,(size_t)NN*192*4,stream);
  (void)hipMemsetAsync(FA2,0,(size_t)NN*160*4,stream);
  (void)hipMemsetAsync(DRr,0,(size_t)NE*4,stream);
  (void)hipMemsetAsync(DSH1,0,(size_t)NE*3*4,stream);
  (void)hipMemsetAsync(DSH2,0,(size_t)NE*5*4,stream);
  (void)hipMemsetAsync(DPOS,0,(size_t)NN*3*4,stream);

  // degree embedding (chunked) -> FA  [split-bf16 + fused RBF]
  for (int cc=0;cc<NCHUNK;cc++){
    int c0e=cc*CH, cnt=CH;
    MG(16,false,false,1,false, true,true,false,false, Rr+c0e,nullptr,degW1,H1, cnt,64,128, rbfc,rbfw,nullptr,nullptr);
    MGEMM3(false,false,1,false, H1,nullptr,degW2,H2, cnt,64,64);
    MGEMM3(false,false,0,false, H2,nullptr,degW3,Gc, cnt,224,64);
    k_agg<true><<<dim3(NG),dim3(512),0,stream>>>(FA0,FA1,FA2,
      nullptr,nullptr,nullptr, Gc,U,SH2b, nullptr, EDST2,EDST2, nullptr, c0e,c0e+cnt);
  }
  k_q3<<<G256(NN*480)>>>(FA0,FA1,FA2, CKB);

  float *c0_=FA0,*c1_=FA1,*c2_=FA2, *n0_=FB0,*n1_=FB1,*n2_=FB2;

  // ---------------- forward blocks [split-bf16] ----------------
  for (int i=0;i<8;i++){
    const float* Wv1i=Wv1+(size_t)i*4096; const float* Wv2i=Wv2+(size_t)i*1024;
    const float* rW1i=rW1+(size_t)i*8192; const float* rW2i=rW2+(size_t)i*4096; const float* rW3i=rW3+(size_t)i*14336;
    const float* WaSi=WaS+(size_t)i*4096; const float* WaDi=WaD+(size_t)i*4096; const float* WaEi=WaE+(size_t)i*2048;
    const float* ff1i=ff1+(size_t)i*65536; const float* ff2i=ff2+(size_t)i*65536;
    const float* fg1i=fg1+(size_t)i*8192; const float* fg2i=fg2+(size_t)i*4096;
    const float* fW1i=fW1+(size_t)i*4096; const float* fW2i=fW2+(size_t)i*1024;
    const float* WCi=WCATF+(size_t)i*45056;
    float* AB=ABLK+(size_t)i*NE;

    (void)hipMemsetAsync(SACC,0,(size_t)NN*4,stream);
    (void)hipMemsetAsync(n0_,0,(size_t)NN*128*4,stream);
    (void)hipMemsetAsync(n1_,0,(size_t)NN*192*4,stream);
    (void)hipMemsetAsync(n2_,0,(size_t)NN*160*4,stream);
    for (int cc=0;cc<NCHUNK;cc++){
      int c0e=cc*CH, cnt=CH;
      MG(16,false,false,1,false, true,true,false,false, Rr+c0e,nullptr,rW1i,H1, cnt,64,128, rbfc,rbfw,nullptr,nullptr);
      MGEMM3(false,false,1,false, H1,nullptr,rW2i,H2, cnt,64,64);
      MGEMM3(false,false,0,false, H2,nullptr,rW3i,Gc, cnt,224,64);
      MGEMM3(false,false,0,true,  c0_,ESRC2+c0e,WaSi,Zc, cnt,32,128);
      MGEMM3(false,true, 0,true,  c0_,EDST2+c0e,WaDi,Zc, cnt,32,128);
      MGEMM3(false,true, 2,false, H2,nullptr,WaEi,Zc, cnt,32,64);
      k_lambda<<<G256(cnt)>>>(Zc, wab+(size_t)i*32, LAM+c0e, cnt);
      MGEMM3(false,false,0,true, c0_,ESRC2+c0e,WCi,SCAT, cnt,352,128);
      MEINS3(64,64,3,false,false,true, c1_,ESRC2+c0e,Wv1i,SV1, cnt);
      MEINS3(32,32,5,false,false,true, c2_,ESRC2+c0e,Wv2i,SV2, cnt);
      k_agg<false><<<dim3(NG),dim3(512),0,stream>>>(n0_,n1_,n2_,
        SCAT,SV1,SV2, Gc,U,SH2b, LAM, EDST2,EDST2, SACC, c0e,c0e+cnt);
    }
    k_norm<<<G256(NE)>>>(LAM,SACC,EDST2,AB);
    k_finy<<<G256(NN*480)>>>(c0_,c1_,c2_, n0_,n1_,n2_, SACC);
    k_q3<<<G256(NN*480)>>>(n0_,n1_,n2_, CKB+(size_t)(i+1)*SLOT);
    for (int nc=0;nc<NN/NNC;nc++){
      MGEMM3(false,false,1,false, n0_+(size_t)nc*NNC*128,nullptr,ff1i,TBc, NNC,512,128);
      MGEMM3(false,true, 0,false, TBc,nullptr,ff2i, n0_+(size_t)nc*NNC*128, NNC,128,512);
    }
    MGEMM3(false,false,3,false, n0_,nullptr,fg1i,P1, NN,64,128);
    MGEMM3(false,false,3,false, n0_,nullptr,fg2i,P2, NN,32,128);
    MEINS3(64,64,3,false,false,false, n1_,nullptr,fW1i,V1, NN);
    MEINS3(32,32,5,false,false,false, n2_,nullptr,fW2i,V2, NN);
    k_gatefwd<64,3><<<G256(NN*192)>>>(n1_,V1,P1);
    k_gatefwd<32,5><<<G256(NN*160)>>>(n2_,V2,P2);
    float* t;
    t=c0_;c0_=n0_;n0_=t; t=c1_;c1_=n1_;n1_=t; t=c2_;c2_=n2_;n2_=t;
  }

  // ---------------- head ----------------
  k_lnhead<<<dim3(NN),dim3(64),0,stream>>>(c0_,c1_,c2_, lng,lnb,W0h,hout, ENODE, DI0,DI1,DI2);
  k_esum<<<dim3(8),dim3(64),0,stream>>>(ENODE,outE);

  // ---------------- backward blocks [plain bf16 MFMA, fused epilogues] ----------------
  for (int i=7;i>=0;--i){
    const float* Wv1i=Wv1+(size_t)i*4096; const float* Wv2i=Wv2+(size_t)i*1024;
    const float* rW1i=rW1+(size_t)i*8192; const float* rW2i=rW2+(size_t)i*4096; const float* rW3i=rW3+(size_t)i*14336;
    const float* WaSi=WaS+(size_t)i*4096; const float* WaDi=WaD+(size_t)i*4096; const float* WaEi=WaE+(size_t)i*2048;
    const float* ff1i=ff1+(size_t)i*65536; const float* ff2i=ff2+(size_t)i*65536;
    const float* fg1i=fg1+(size_t)i*8192; const float* fg2i=fg2+(size_t)i*4096;
    const float* fW1i=fW1+(size_t)i*4096; const float* fW2i=fW2+(size_t)i*1024;
    const float* WCi=WCATF+(size_t)i*45056;
    const float* AB=ABLK+(size_t)i*NE;

    k_dq3<<<G256(NN*480)>>>(CKB+(size_t)i*SLOT, FA0,FA1,FA2);
    if (i>0){
      const float* pf1=ff1+(size_t)(i-1)*65536; const float* pf2=ff2+(size_t)(i-1)*65536;
      const float* pg1=fg1+(size_t)(i-1)*8192; const float* pg2=fg2+(size_t)(i-1)*4096;
      const float* pW1=fW1+(size_t)(i-1)*4096; const float* pW2=fW2+(size_t)(i-1)*1024;
      for (int nc=0;nc<NN/NNC;nc++){
        MGEMM(false,false,1,false, FA0+(size_t)nc*NNC*128,nullptr,pf1,TBc, NNC,512,128);
        MGEMM(false,true, 0,false, TBc,nullptr,pf2, FA0+(size_t)nc*NNC*128, NNC,128,512);
      }
      MGEMM(false,false,3,false, FA0,nullptr,pg1,P1, NN,64,128);
      MGEMM(false,false,3,false, FA0,nullptr,pg2,P2, NN,32,128);
      MEINS(64,64,3,false,false,false, FA1,nullptr,pW1,V1, NN);
      MEINS(32,32,5,false,false,false, FA2,nullptr,pW2,V2, NN);
      k_gatefwd<64,3><<<G256(NN*192)>>>(FA1,V1,P1);
      k_gatefwd<32,5><<<G256(NN*160)>>>(FA2,V2,P2);
    }
    k_dq3<<<G256(NN*480)>>>(CKB+(size_t)(i+1)*SLOT, FB0,FB1,FB2);
    (void)hipMemcpyAsync(F0N,FB0,(size_t)NN*128*4,hipMemcpyDeviceToDevice,stream);
    for (int nc=0;nc<NN/NNC;nc++){
      MGEMM(false,false,1,false, FB0+(size_t)nc*NNC*128,nullptr,ff1i,TBc, NNC,512,128);
      MGEMM(false,true, 0,false, TBc,nullptr,ff2i, F0N+(size_t)nc*NNC*128, NNC,128,512);
    }
    MGEMM(false,false,3,false, F0N,nullptr,fg1i,P1, NN,64,128);
    MGEMM(false,false,3,false, F0N,nullptr,fg2i,P2, NN,32,128);
    MEINS(64,64,3,false,false,false, FB1,nullptr,fW1i,V1, NN);
    MEINS(32,32,5,false,false,false, FB2,nullptr,fW2i,V2, NN);
    k_gateback<64,3><<<G256(NN*64)>>>(DI1,V1,P1,DPb);
    MGEMM(true,true,0,false, DPb,nullptr,fg1i,DI0, NN,128,64);
    (void)hipMemcpyAsync(DY1,DI1,(size_t)NN*192*4,hipMemcpyDeviceToDevice,stream);
    MEINS(64,64,3,true,true,false, V1,nullptr,fW1i,DY1, NN);
    k_gateback<32,5><<<G256(NN*32)>>>(DI2,V2,P2,DPb);
    MGEMM(true,true,0,false, DPb,nullptr,fg2i,DI0, NN,128,32);
    (void)hipMemcpyAsync(DY2,DI2,(size_t)NN*160*4,hipMemcpyDeviceToDevice,stream);
    MEINS(32,32,5,true,true,false, V2,nullptr,fW2i,DY2, NN);
    (void)hipMemcpyAsync(DY0,DI0,(size_t)NN*128*4,hipMemcpyDeviceToDevice,stream);
    for (int nc=0;nc<NN/NNC;nc++){
      MGEMM(false,false,0,false, FB0+(size_t)nc*NNC*128,nullptr,ff1i,TBc, NNC,512,128);
      MG(16,true,false,0,false, false,false,true,false, DI0+(size_t)nc*NNC*128,nullptr,ff2i,DTc, NNC,512,128, nullptr,nullptr,TBc,nullptr);
      MGEMM(true,true,0,false, DTc,nullptr,ff1i, DY0+(size_t)nc*NNC*128, NNC,128,512);
    }
    k_ssum<<<dim3(NN/4),dim3(256),0,stream>>>(FA0,FA1,FA2,FB0,FB1,FB2,DY0,DY1,DY2,SSUM);
    (void)hipMemcpyAsync(DI0,DY0,(size_t)NN*128*4,hipMemcpyDeviceToDevice,stream);
    (void)hipMemcpyAsync(DI1,DY1,(size_t)NN*192*4,hipMemcpyDeviceToDevice,stream);
    (void)hipMemcpyAsync(DI2,DY2,(size_t)NN*160*4,hipMemcpyDeviceToDevice,stream);
    for (int cc=0;cc<NCHUNK;cc++){
      int c0e=cc*CH, cnt=CH;
      MG(16,false,false,1,false, false,true,false,true, Rr+c0e,nullptr,rW1i,H1, cnt,64,128, rbfc,rbfw,nullptr,PRE1);
      MG(16,false,false,1,false, false,false,false,true, H1,nullptr,rW2i,H2, cnt,64,64, nullptr,nullptr,nullptr,PRE2);
      MGEMM(false,false,0,false, H2,nullptr,rW3i,Gc, cnt,224,64);
      MGEMM(false,false,0,true,  FA0,ESRC2+c0e,WaSi,Zc, cnt,32,128);
      MGEMM(false,true, 0,true,  FA0,EDST2+c0e,WaDi,Zc, cnt,32,128);
      MGEMM(false,true, 2,false, H2,nullptr,WaEi,Zc, cnt,32,64);
      MGEMM(false,false,0,true, FA0,ESRC2+c0e,WCi,SCAT, cnt,352,128);
      MEINS(64,64,3,false,false,true, FA1,ESRC2+c0e,Wv1i,SV1, cnt);
      MEINS(32,32,5,false,false,true, FA2,ESRC2+c0e,Wv2i,SV2, cnt);
      k_bedge<<<GW4(cnt)>>>(SCAT,SV1,SV2, Gc,U,SH2b, DY0,DY1,DY2, EDST2, SSUM,
                            wab+(size_t)i*32, Zc, AB, DGc, DSH1, DSH2, c0e, cnt);
      MGEMM(true,false,0,false, SCAT,nullptr,WCi,DE0, cnt,128,352);
      MGEMM(true,true, 0,false, Zc,nullptr,WaSi,DE0, cnt,128,32);
      MGEMM(true,false,0,false, Zc,nullptr,WaDi,DZD, cnt,128,32);
      MEINS(64,64,3,true,false,false, SV1,nullptr,Wv1i,SV1, cnt);
      MEINS(32,32,5,true,false,false, SV2,nullptr,Wv2i,SV2, cnt);
      MGEMM(true,false,0,false, Zc,nullptr,WaEi,H2, cnt,64,32);
      MG(16,true,true,0,false, false,false,true,false, DGc,nullptr,rW3i,H2, cnt,64,224, nullptr,nullptr,PRE2,nullptr);
      MG(16,true,false,0,false, false,false,true,false, H2,nullptr,rW2i,H1, cnt,64,64, nullptr,nullptr,PRE1,nullptr);
      MGEMM(true,false,0,false, H1,nullptr,rW1i,RBFc, cnt,128,64);
      k_dr<<<GW4(cnt)>>>(RBFc,Rr,rbfc,rbfw,DRr, c0e,cnt);
      k_scat<<<dim3(NG),dim3(640),0,stream>>>(DI0,DI1,DI2, DE0,DZD,SV1,SV2, ESRC2,EDST2, c0e,c0e+cnt);
    }
  }

  // ---------------- initial embedding backward [fused] ----------------
  for (int cc=0;cc<NCHUNK;cc++){
    int c0e=cc*CH, cnt=CH;
    MG(16,false,false,1,false, false,true,false,true, Rr+c0e,nullptr,degW1,H1, cnt,64,128, rbfc,rbfw,nullptr,PRE1);
    MG(16,false,false,1,false, false,false,false,true, H1,nullptr,degW2,H2, cnt,64,64, nullptr,nullptr,nullptr,PRE2);
    MGEMM(false,false,0,false, H2,nullptr,degW3,Gc, cnt,224,64);
    k_initback<<<GW4(cnt)>>>(DI0,DI1,DI2,EDST2,Gc,U,SH2b,DGc,DSH1,DSH2, c0e,cnt);
    MG(16,true,false,0,false, false,false,true,false, DGc,nullptr,degW3,H2, cnt,64,224, nullptr,nullptr,PRE2,nullptr);
    MG(16,true,false,0,false, false,false,true,false, H2,nullptr,degW2,H1, cnt,64,64, nullptr,nullptr,PRE1,nullptr);
    MGEMM(true,false,0,false, H1,nullptr,degW1,RBFc, cnt,128,64);
    k_dr<<<GW4(cnt)>>>(RBFc,Rr,rbfc,rbfw,DRr, c0e,cnt);
  }

  // ---------------- geometry backward + outputs ----------------
  k_geoback<<<G256(NE)>>>(DRr,DSH1,DSH2,U,Rr,ESRC2,EDST2,DPOS);
  k_forces<<<G256(NN*3)>>>(DPOS,outF);
  (void)in_sizes; (void)n_in; (void)out_size;
}

// Round 19
// 41745.480 us; speedup vs baseline: 1.7204x; 1.1661x over previous
//
#include <hip/hip_runtime.h>
#include <string.h>
#include <math.h>

#define NE 100000
#define NN 8192
#define NG 512
#define CH 16700
#define NCHUNK 6
#define NNC 2048

#define SQ3F  1.7320508075688772f
#define SQ5F  2.23606797749979f
#define SQ15F 3.872983346207417f

__constant__ int c_amap[10] = {-1,0,-1,-1,-1,-1,1,2,3,4};

typedef __attribute__((ext_vector_type(4))) float f32x4;
typedef __attribute__((ext_vector_type(8))) short bf16x8;

__device__ __forceinline__ float sigf(float x){ return 1.0f/(1.0f+expf(-x)); }
__device__ __forceinline__ float siluf(float x){ return x*sigf(x); }
__device__ __forceinline__ float dsiluf(float x){ float s=sigf(x); return s*(1.0f + x*(1.0f-s)); }

__device__ __forceinline__ float wred64(float v){
  #pragma unroll
  for (int o=32;o>0;o>>=1) v += __shfl_down(v,o,64);
  return v;
}
__device__ __forceinline__ int lbound(const int* a, int n, int v){
  int lo=0, hi=n;
  while (lo<hi){ int m=(lo+hi)>>1; if (a[m]<v) lo=m+1; else hi=m; }
  return lo;
}
__device__ __forceinline__ unsigned short f2b(float x){
  unsigned u=__float_as_uint(x);
  unsigned r=(u + 0x7fffu + ((u>>16)&1u))>>16;
  return (unsigned short)r;
}
__device__ __forceinline__ float b2f(unsigned short b){
  return __uint_as_float(((unsigned)b)<<16);
}

// ---------------- edge sort by dst (counting sort) ----------------
__global__ void k_hist(const int* keys, int* hist, int n){
  int i = blockIdx.x*256 + threadIdx.x;
  if (i < n) atomicAdd(&hist[keys[i]], 1);
}
__global__ void k_scan0(const int* hist, int* rows){
  if (threadIdx.x == 0 && blockIdx.x == 0){
    int acc = 0;
    for (int i = 0; i < NN; i++){ rows[i] = acc; acc += hist[i]; }
    rows[NN] = acc;
  }
}
__global__ void k_fillperm(const int* keys, int* cursor, int* perm, int n){
  int i = blockIdx.x*256 + threadIdx.x;
  if (i < n){
    int slot = atomicAdd(&cursor[keys[i]], 1);
    perm[slot] = i;
  }
}
__global__ void k_mkedge(const int* perm, const int* src, const int* dst, int* src2, int* dst2){
  int k = blockIdx.x*256 + threadIdx.x;
  if (k < NE){ int e = perm[k]; src2[k] = src[e]; dst2[k] = dst[e]; }
}

// weight concat: WCATF[i][k][0:352] = [Wv0 | Ws0 | Ws1 | Ws2]
__global__ void k_wcat(const float* Wv0,const float* Ws0,const float* Ws1,const float* Ws2, float* W){
  int t = blockIdx.x*256 + threadIdx.x;
  if (t >= 8*128*352) return;
  int i = t/45056, r = t - i*45056;
  int k = r/352, n = r - k*352;
  float v;
  if (n < 128) v = Wv0[(size_t)i*16384 + k*128 + n];
  else if (n < 256) v = Ws0[(size_t)i*16384 + k*128 + (n-128)];
  else if (n < 320) v = Ws1[(size_t)i*8192 + k*64 + (n-256)];
  else v = Ws2[(size_t)i*4096 + k*32 + (n-320)];
  W[t] = v;
}

// --- bf16 MFMA GEMM; MT = M-tile (64 or 16); SPLIT=3-term split-bf16; ARBF=A computed as RBF(Rr row);
//     DMUL=epilogue *dsilu(dm); PREOUT=write pre-activation to pre[] ---
template<int MT, bool TB, bool ACC, int ACT, bool GATHER, bool SPLIT, bool ARBF, bool DMUL, bool PREOUT>
__global__ __launch_bounds__(256) void k_mgemm(
    const float* __restrict__ A, const int* __restrict__ idx,
    const float* __restrict__ B, float* __restrict__ C,
    int M, int Nd, int K,
    const float* __restrict__ cen, const float* __restrict__ wid,
    const float* __restrict__ dm, float* __restrict__ pre)
{
  constexpr int TPR = 256/MT;     // threads per A-row
  constexpr int EPT = 32/TPR;     // elems per thread (A staging)
  constexpr int RT  = MT/16;      // MFMA row-tiles
  __shared__ unsigned short Asb[(SPLIT?2:1)*MT*40];
  __shared__ unsigned short Btb[(SPLIT?2:1)*2560];
  const int bm = blockIdx.x*MT, bn = blockIdx.y*64;
  const int tid = threadIdx.x;
  const int wave = tid>>6, lane = tid&63;
  const int arow_s = tid / TPR, aoff = (tid % TPR) * EPT;
  const int bsrow = tid>>2, bsoff = (tid&3)*8;
  f32x4 acc[RT];
  #pragma unroll
  for (int r=0;r<RT;r++) acc[r] = (f32x4){0.f,0.f,0.f,0.f};
  int arow = -1;
  {
    int gr = bm + arow_s;
    if (gr < M) arow = GATHER ? idx[gr] : gr;
  }
  int bcol = bn + bsrow;
  for (int k0=0;k0<K;k0+=32){
    #pragma unroll
    for (int i=0;i<EPT;i++){
      float v = 0.0f;
      if (arow>=0){
        if (ARBF){
          float r = A[arow];
          int kk = k0 + aoff + i;
          float t = (r - cen[kk]) / wid[kk];
          v = expf(-0.5f*t*t);
        } else {
          v = A[(size_t)arow*K + k0 + aoff + i];
        }
      }
      unsigned short h = f2b(v);
      Asb[arow_s*40 + aoff + i] = h;
      if (SPLIT) Asb[MT*40 + arow_s*40 + aoff + i] = f2b(v - b2f(h));
    }
    #pragma unroll
    for (int i=0;i<8;i++){
      float v = 0.0f;
      if (bcol < Nd) v = TB ? B[(size_t)bcol*K + k0 + bsoff + i] : B[(size_t)(k0+bsoff+i)*Nd + bcol];
      unsigned short h = f2b(v);
      Btb[bsrow*40 + bsoff + i] = h;
      if (SPLIT) Btb[2560 + bsrow*40 + bsoff + i] = f2b(v - b2f(h));
    }
    __syncthreads();
    int boff = (wave*16 + (lane&15))*40 + (lane>>4)*8;
    bf16x8 bh = *(const bf16x8*)&Btb[boff];
    #pragma unroll
    for (int r=0;r<RT;r++){
      int aoff2 = (r*16 + (lane&15))*40 + (lane>>4)*8;
      bf16x8 ah = *(const bf16x8*)&Asb[aoff2];
      acc[r] = __builtin_amdgcn_mfma_f32_16x16x32_bf16(ah, bh, acc[r], 0,0,0);
      if (SPLIT){
        bf16x8 bl = *(const bf16x8*)&Btb[2560 + boff];
        bf16x8 al = *(const bf16x8*)&Asb[MT*40 + aoff2];
        acc[r] = __builtin_amdgcn_mfma_f32_16x16x32_bf16(ah, bl, acc[r], 0,0,0);
        acc[r] = __builtin_amdgcn_mfma_f32_16x16x32_bf16(al, bh, acc[r], 0,0,0);
      }
    }
    __syncthreads();
  }
  int col = bn + wave*16 + (lane&15);
  if (col < Nd){
    #pragma unroll
    for (int r=0;r<RT;r++){
      #pragma unroll
      for (int v=0;v<4;v++){
        int row = bm + r*16 + (lane>>4)*4 + v;
        if (row >= M) continue;
        size_t o = (size_t)row*Nd + col;
        float x = acc[r][v];
        if (ACC) x += C[o];
        if (DMUL) x *= dsiluf(dm[o]);
        if (PREOUT) pre[o] = x;
        if (ACT == 1) x = siluf(x);
        else if (ACT == 2) x = tanhf(x);
        else if (ACT == 3) x = sigf(x);
        C[o] = x;
      }
    }
  }
}

// ---------- bf16 MFMA einsum (X-strided rows); SPLIT => split-bf16 ----------
template<int CI, int CO, int X, bool TB, bool ACC, bool GATHER, bool SPLIT>
__global__ __launch_bounds__(256) void k_meinsum(
    const float* __restrict__ A, const int* __restrict__ idx,
    const float* __restrict__ W, float* __restrict__ C, int M)
{
  __shared__ unsigned short Asb[(SPLIT?2:1)*2560];
  __shared__ unsigned short Btb[(SPLIT?2:1)*2560];
  const int bm = blockIdx.x*64;
  const int tid = threadIdx.x, wave = tid>>6, lane = tid&63;
  const int srow = tid>>2, soff = (tid&3)*8;
  f32x4 acc[4];
  #pragma unroll
  for (int r=0;r<4;r++) acc[r] = (f32x4){0.f,0.f,0.f,0.f};
  long abase = -1;
  {
    int grow = bm + srow;
    if (grow < M*X){
      int ge = grow / X, gx = grow - ge*X;
      int ar = GATHER ? idx[ge] : ge;
      abase = (long)ar*CI*X + gx;
    }
  }
  for (int k0=0;k0<CI;k0+=32){
    #pragma unroll
    for (int i=0;i<8;i++){
      float v = (abase>=0) ? A[abase + (size_t)(k0+soff+i)*X] : 0.0f;
      unsigned short h = f2b(v);
      Asb[srow*40 + soff + i] = h;
      if (SPLIT) Asb[2560 + srow*40 + soff + i] = f2b(v - b2f(h));
    }
    #pragma unroll
    for (int i=0;i<8;i++){
      int kk = k0 + soff + i;
      float v = 0.0f;
      if (srow < CO) v = TB ? W[srow*CI + kk] : W[kk*CO + srow];
      unsigned short h = f2b(v);
      Btb[srow*40 + soff + i] = h;
      if (SPLIT) Btb[2560 + srow*40 + soff + i] = f2b(v - b2f(h));
    }
    __syncthreads();
    int boff = (wave*16 + (lane&15))*40 + (lane>>4)*8;
    bf16x8 bh = *(const bf16x8*)&Btb[boff];
    #pragma unroll
    for (int r=0;r<4;r++){
      int aoff = (r*16 + (lane&15))*40 + (lane>>4)*8;
      bf16x8 ah = *(const bf16x8*)&Asb[aoff];
      acc[r] = __builtin_amdgcn_mfma_f32_16x16x32_bf16(ah, bh, acc[r], 0,0,0);
      if (SPLIT){
        bf16x8 bl = *(const bf16x8*)&Btb[2560 + boff];
        bf16x8 al = *(const bf16x8*)&Asb[2560 + aoff];
        acc[r] = __builtin_amdgcn_mfma_f32_16x16x32_bf16(ah, bl, acc[r], 0,0,0);
        acc[r] = __builtin_amdgcn_mfma_f32_16x16x32_bf16(al, bh, acc[r], 0,0,0);
      }
    }
    __syncthreads();
  }
  int col = wave*16 + (lane&15);
  if (col < CO){
    #pragma unroll
    for (int r=0;r<4;r++){
      #pragma unroll
      for (int v=0;v<4;v++){
        int row = bm + r*16 + (lane>>4)*4 + v;
        if (row >= M*X) continue;
        int ge = row / X, gx = row - ge*X;
        size_t o = (size_t)ge*CO*X + (size_t)col*X + gx;
        float xx = acc[r][v];
        if (ACC) xx += C[o];
        C[o] = xx;
      }
    }
  }
}

// ------------------------- small kernels -------------------------
__global__ void k_sentinel(float* o, int n, float v){
  int i = blockIdx.x*256 + threadIdx.x;
  if (i < n) o[i] = v;
}

__global__ void k_geom(const float* __restrict__ pos, const int* __restrict__ src, const int* __restrict__ dst,
                       float* __restrict__ U, float* __restrict__ Rr, float* __restrict__ SH2b){
  int e = blockIdx.x*256 + threadIdx.x;
  if (e >= NE) return;
  int s = src[e], d = dst[e];
  float vx = pos[s*3+0]-pos[d*3+0];
  float vy = pos[s*3+1]-pos[d*3+1];
  float vz = pos[s*3+2]-pos[d*3+2];
  float r = sqrtf(vx*vx+vy*vy+vz*vz + 1e-12f);
  float ux=vx/r, uy=vy/r, uz=vz/r;
  U[e*3+0]=ux; U[e*3+1]=uy; U[e*3+2]=uz;
  Rr[e]=r;
  SH2b[e*5+0]=SQ15F*ux*uy;
  SH2b[e*5+1]=SQ15F*uy*uz;
  SH2b[e*5+2]=0.5f*SQ5F*(3.0f*uz*uz-1.0f);
  SH2b[e*5+3]=SQ15F*ux*uz;
  SH2b[e*5+4]=0.5f*SQ15F*(ux*ux-uy*uy);
}

__global__ void k_f0init(const int* __restrict__ na, const float* __restrict__ at, float* __restrict__ f0){
  int t = blockIdx.x*256 + threadIdx.x;
  if (t >= NN*128) return;
  int n = t>>7, j = t&127;
  int m = c_amap[na[n]];
  f0[t] = at[m*128+j];
}

// lambda -> p = exp(lambda)
__global__ void k_lambda(const float* __restrict__ Z, const float* __restrict__ wa, float* __restrict__ P_c, int cnt){
  int e = blockIdx.x*256 + threadIdx.x;
  if (e >= cnt) return;
  float s = 0.0f;
  #pragma unroll
  for (int k=0;k<32;k++) s += Z[e*32+k]*wa[k];
  P_c[e] = expf(s);
}

__global__ void k_norm(const float* __restrict__ P, const float* __restrict__ S,
                       const int* __restrict__ dst, float* __restrict__ AB){
  int e = blockIdx.x*256 + threadIdx.x;
  if (e < NE) AB[e] = P[e]/(S[dst[e]]+1e-9f);
}

__global__ void k_finy(const float* __restrict__ x0,const float* __restrict__ x1,const float* __restrict__ x2,
                       float* __restrict__ y0,float* __restrict__ y1,float* __restrict__ y2,
                       const float* __restrict__ S){
  int t = blockIdx.x*256 + threadIdx.x;
  if (t >= NN*480) return;
  if (t < NN*128){ int n=t>>7; y0[t]=x0[t]+y0[t]/(S[n]+1e-9f); }
  else if (t < NN*320){ int q=t-NN*128; int n=q/192; y1[q]=x1[q]+y1[q]/(S[n]+1e-9f); }
  else { int q=t-NN*320; int n=q/160; y2[q]=x2[q]+y2[q]/(S[n]+1e-9f); }
}

// bf16 checkpoint quant/dequant
__global__ void k_q3(const float* __restrict__ f0,const float* __restrict__ f1,const float* __restrict__ f2,
                     unsigned short* __restrict__ ck){
  int t = blockIdx.x*256 + threadIdx.x;
  if (t >= NN*480) return;
  float v;
  if (t < NN*128) v = f0[t];
  else if (t < NN*320) v = f1[t-NN*128];
  else v = f2[t-NN*320];
  ck[t] = f2b(v);
}
__global__ void k_dq3(const unsigned short* __restrict__ ck,
                      float* __restrict__ f0,float* __restrict__ f1,float* __restrict__ f2){
  int t = blockIdx.x*256 + threadIdx.x;
  if (t >= NN*480) return;
  float v = b2f(ck[t]);
  if (t < NN*128) f0[t]=v;
  else if (t < NN*320) f1[t-NN*128]=v;
  else f2[t-NN*320]=v;
}

// per-graph aggregation; SC strided 352 [sv0|sw0|sw1|sw2]; accumulates S in lanes 480..495
template<bool INIT>
__global__ __launch_bounds__(512) void k_agg(
  float* __restrict__ f0o,float* __restrict__ f1o,float* __restrict__ f2o,
  const float* __restrict__ SC,const float* __restrict__ sv1,const float* __restrict__ sv2,
  const float* __restrict__ g,const float* __restrict__ U,const float* __restrict__ SH2b,
  const float* __restrict__ aArr,const int* __restrict__ keys,const int* __restrict__ dst,
  float* __restrict__ SACC, int c0, int c1)
{
  __shared__ float acc[7680];
  int b = blockIdx.x, lo = b<<4;
  int e0 = lbound(keys, NE, lo), e1 = lbound(keys, NE, lo+16);
  if (e0 < c0) e0 = c0;
  if (e1 > c1) e1 = c1;
  if (e0 >= e1) return;
  for (int i=threadIdx.x;i<7680;i+=512) acc[i]=0.0f;
  __syncthreads();
  const int j = threadIdx.x;
  const float inv = 1.0f/sqrtf(15.57f);
  int cat=3, cc_=0, xx_=0;
  if (j<128){ cat=0; }
  else if (j<320){ cat=1; int t=j-128; cc_=t/3; xx_=t-3*cc_; }
  else if (j<480){ cat=2; int t=j-320; cc_=t/5; xx_=t-5*cc_; }
  float sacc=0.0f;
  for (int e=e0; e<e1; ++e){
    int el = e - c0;
    float a = INIT ? inv : aArr[e];
    int nl = dst[e]&15;
    if (cat==0){
      float m = INIT ? g[el*224+j] : (SC[(size_t)el*352+j]*g[el*224+j] + SC[(size_t)el*352+128+j]);
      acc[nl*480+j] += a*m;
    } else if (cat==1){
      int t=j-128;
      float sh = SQ3F*U[e*3+xx_];
      float m = INIT ? g[el*224+128+cc_]*sh : (sv1[el*192+t]*g[el*224+128+cc_] + SC[(size_t)el*352+256+cc_]*sh);
      acc[nl*480+j] += a*m;
    } else if (cat==2){
      int t=j-320;
      float sh = SH2b[e*5+xx_];
      float m = INIT ? g[el*224+192+cc_]*sh : (sv2[el*160+t]*g[el*224+192+cc_] + SC[(size_t)el*352+320+cc_]*sh);
      acc[nl*480+j] += a*m;
    } else if (!INIT && j<496){
      if (nl==(j-480)) sacc += a;
    }
  }
  __syncthreads();
  for (int i=threadIdx.x;i<7680;i+=512){
    int nl=i/480, jj=i-480*nl, n=lo+nl;
    float v=acc[i];
    if (jj<128) f0o[n*128+jj]+=v;
    else if (jj<320) f1o[n*192+jj-128]+=v;
    else f2o[n*160+jj-320]+=v;
  }
  if (!INIT && j>=480 && j<496) SACC[lo+(j-480)] += sacc;
}

// per-graph scatter of edge grads
__global__ __launch_bounds__(640) void k_scat(
  float* __restrict__ df0, float* __restrict__ df1, float* __restrict__ df2,
  const float* __restrict__ DE0, const float* __restrict__ DZD,
  const float* __restrict__ DE1, const float* __restrict__ DE2,
  const int* __restrict__ src, const int* __restrict__ dst, int c0, int c1)
{
  __shared__ float acc[7680];
  int b=blockIdx.x, lo=b<<4;
  int e0=lbound(dst,NE,lo), e1=lbound(dst,NE,lo+16);
  if (e0 < c0) e0 = c0;
  if (e1 > c1) e1 = c1;
  for (int i=threadIdx.x;i<7680;i+=640) acc[i]=0.0f;
  __syncthreads();
  const int j=threadIdx.x;
  for (int e=e0;e<e1;++e){
    int el=e-c0;
    int sl=(src[e]&15)*480, dl=(dst[e]&15)*480;
    if (j<128) acc[sl+j] += DE0[el*128+j];
    else if (j<256){ int q=j-128; acc[dl+q] += DZD[el*128+q]; }
    else if (j<448){ int q=j-256; acc[sl+128+q] += DE1[el*192+q]; }
    else if (j<608){ int q=j-448; acc[sl+320+q] += DE2[el*160+q]; }
    __syncthreads();
  }
  for (int i=threadIdx.x;i<7680;i+=640){
    int nl=i/480, jj=i-480*nl, n=lo+nl;
    float v=acc[i];
    if (jj<128) df0[n*128+jj]+=v;
    else if (jj<320) df1[n*192+jj-128]+=v;
    else df2[n*160+jj-320]+=v;
  }
}

// SSUM[n] = (FB[n]-FA[n]) . DY[n]
__global__ __launch_bounds__(256) void k_ssum(
  const float* __restrict__ FA0,const float* __restrict__ FA1,const float* __restrict__ FA2,
  const float* __restrict__ FB0,const float* __restrict__ FB1,const float* __restrict__ FB2,
  const float* __restrict__ DY0,const float* __restrict__ DY1,const float* __restrict__ DY2,
  float* __restrict__ SSUM)
{
  int n=blockIdx.x*4+(threadIdx.x>>6), lane=threadIdx.x&63;
  if (n>=NN) return;
  float s=0.0f;
  for (int j=lane;j<480;j+=64){
    float d,g;
    if (j<128){ d=FB0[n*128+j]-FA0[n*128+j]; g=DY0[n*128+j]; }
    else if (j<320){ int q=j-128; d=FB1[n*192+q]-FA1[n*192+q]; g=DY1[n*192+q]; }
    else { int q=j-320; d=FB2[n*160+q]-FA2[n*160+q]; g=DY2[n*160+q]; }
    s += d*g;
  }
  s = wred64(s);
  if (lane==0) SSUM[n]=s;
}

// fused backward edge chain: da -> dlam -> dz -> split0/1/2 ; one wave per edge
__global__ __launch_bounds__(256) void k_bedge(
  float* __restrict__ SC, float* __restrict__ SV1, float* __restrict__ SV2,
  const float* __restrict__ g, const float* __restrict__ U, const float* __restrict__ SH2b,
  const float* __restrict__ df0,const float* __restrict__ df1,const float* __restrict__ df2,
  const int* __restrict__ dst, const float* __restrict__ SSUM, const float* __restrict__ wa,
  float* __restrict__ Z, const float* __restrict__ aArr,
  float* __restrict__ DG, float* __restrict__ DSH1, float* __restrict__ DSH2,
  int c0, int cnt)
{
  int w=threadIdx.x>>6, lane=threadIdx.x&63;
  int el=blockIdx.x*4+w;
  if (el>=cnt) return;
  int e=c0+el;
  int d=dst[e];
  float s=0.0f;
  for (int j=lane;j<480;j+=64){
    float m, dfv;
    if (j<128){
      m = SC[(size_t)el*352+j]*g[el*224+j] + SC[(size_t)el*352+128+j];
      dfv = df0[(size_t)d*128+j];
    } else if (j<320){
      int t=j-128, c=t/3, x=t-3*c;
      m = SV1[el*192+t]*g[el*224+128+c] + SC[(size_t)el*352+256+c]*(SQ3F*U[e*3+x]);
      dfv = df1[(size_t)d*192+t];
    } else {
      int t=j-320, c=t/5, x=t-5*c;
      m = SV2[el*160+t]*g[el*224+192+c] + SC[(size_t)el*352+320+c]*SH2b[e*5+x];
      dfv = df2[(size_t)d*160+t];
    }
    s += m*dfv;
  }
  s = wred64(s);
  s = __shfl(s,0,64);
  float a = aArr[e];
  float dlam = a*(s - SSUM[d]);
  if (lane<32){
    float z = Z[(size_t)el*32+lane];
    Z[(size_t)el*32+lane] = dlam*wa[lane]*(1.0f-z*z);
  }
  {
    float* row = SC + (size_t)el*352;
    for (int j=lane;j<128;j+=64){
      float dm = a*df0[(size_t)d*128+j];
      float sv = row[j];
      row[128+j] = dm;
      row[j] = dm*g[el*224+j];
      DG[el*224+j] = dm*sv;
    }
  }
  {
    float dm0=a*df1[(size_t)d*192+lane*3+0];
    float dm1=a*df1[(size_t)d*192+lane*3+1];
    float dm2=a*df1[(size_t)d*192+lane*3+2];
    float sw1o=SC[(size_t)el*352+256+lane];
    float g1=g[el*224+128+lane];
    float c0v=dm0*sw1o, c1v=dm1*sw1o, c2v=dm2*sw1o;
    c0v=wred64(c0v); c1v=wred64(c1v); c2v=wred64(c2v);
    if (lane==0){ DSH1[e*3+0]+=c0v; DSH1[e*3+1]+=c1v; DSH1[e*3+2]+=c2v; }
    float sh0=SQ3F*U[e*3+0], sh1=SQ3F*U[e*3+1], sh2=SQ3F*U[e*3+2];
    SC[(size_t)el*352+256+lane]=dm0*sh0+dm1*sh1+dm2*sh2;
    float sv0o=SV1[el*192+lane*3+0], sv1o=SV1[el*192+lane*3+1], sv2o=SV1[el*192+lane*3+2];
    DG[el*224+128+lane]=dm0*sv0o+dm1*sv1o+dm2*sv2o;
    SV1[el*192+lane*3+0]=dm0*g1; SV1[el*192+lane*3+1]=dm1*g1; SV1[el*192+lane*3+2]=dm2*g1;
  }
  {
    float dm[5]={0,0,0,0,0}, svo[5]={0,0,0,0,0};
    float sw2o=0.0f, g2=0.0f;
    if (lane<32){
      #pragma unroll
      for (int x=0;x<5;x++){ dm[x]=a*df2[(size_t)d*160+lane*5+x]; svo[x]=SV2[el*160+lane*5+x]; }
      sw2o=SC[(size_t)el*352+320+lane]; g2=g[el*224+192+lane];
    }
    float c[5];
    #pragma unroll
    for (int x=0;x<5;x++){ c[x]=dm[x]*sw2o; c[x]=wred64(c[x]); }
    if (lane==0){
      #pragma unroll
      for (int x=0;x<5;x++) DSH2[e*5+x]+=c[x];
    }
    if (lane<32){
      float dsw=0.0f, dg2=0.0f;
      #pragma unroll
      for (int x=0;x<5;x++){ dsw+=dm[x]*SH2b[e*5+x]; dg2+=dm[x]*svo[x]; }
      SC[(size_t)el*352+320+lane]=dsw;
      DG[el*224+192+lane]=dg2;
      #pragma unroll
      for (int x=0;x<5;x++) SV2[el*160+lane*5+x]=dm[x]*g2;
    }
  }
}

template<int CD,int X>
__global__ void k_gatefwd(float* __restrict__ f, const float* __restrict__ V, const float* __restrict__ P){
  int t=blockIdx.x*256+threadIdx.x;
  const int ox=CD*X;
  if (t>=NN*ox) return;
  int n=t/ox, rem=t-n*ox, d=rem/X;
  f[t] += V[t]*P[n*CD+d];
}

template<int CD,int X>
__global__ void k_gateback(const float* __restrict__ dfB, float* __restrict__ V,
                           const float* __restrict__ P, float* __restrict__ DPa){
  int t=blockIdx.x*256+threadIdx.x;
  if (t>=NN*CD) return;
  float p=P[t];
  float dp=0.0f;
  #pragma unroll
  for (int x=0;x<X;x++){ dp += dfB[t*X+x]*V[t*X+x]; }
  #pragma unroll
  for (int x=0;x<X;x++){ V[t*X+x] = dfB[t*X+x]*p; }
  DPa[t] = dp*p*(1.0f-p);
}

__global__ __launch_bounds__(256) void k_dr(const float* __restrict__ DRBF, const float* __restrict__ Rr,
    const float* __restrict__ cen, const float* __restrict__ wid, float* __restrict__ DRa, int c0, int cnt){
  int w=threadIdx.x>>6, lane=threadIdx.x&63;
  int el=blockIdx.x*4+w;
  if (el>=cnt) return;
  int e=c0+el;
  float r=Rr[e], s=0.0f;
  for (int k=lane;k<128;k+=64){
    float c=cen[k], wd=wid[k];
    float t=(r-c)/wd;
    float rb=expf(-0.5f*t*t);
    s += DRBF[el*128+k]*rb*((c-r)/(wd*wd));
  }
  s=wred64(s);
  if (lane==0) DRa[e]+=s;
}

__global__ __launch_bounds__(256) void k_initback(
  const float* __restrict__ df0,const float* __restrict__ df1,const float* __restrict__ df2,
  const int* __restrict__ dst,
  const float* __restrict__ g,const float* __restrict__ U,const float* __restrict__ SH2b,
  float* __restrict__ DG,float* __restrict__ DSH1,float* __restrict__ DSH2, int c0, int cnt)
{
  int w=threadIdx.x>>6, lane=threadIdx.x&63;
  int el=blockIdx.x*4+w;
  if (el>=cnt) return;
  int e=c0+el;
  int d=dst[e];
  const float inv=1.0f/sqrtf(15.57f);
  for (int j=lane;j<128;j+=64) DG[el*224+j]=inv*df0[d*128+j];
  float sh0=SQ3F*U[e*3+0], sh1=SQ3F*U[e*3+1], sh2=SQ3F*U[e*3+2];
  float df10=df1[d*192+lane*3+0], df11=df1[d*192+lane*3+1], df12=df1[d*192+lane*3+2];
  float g1=g[el*224+128+lane];
  DG[el*224+128+lane]=inv*(df10*sh0+df11*sh1+df12*sh2);
  float c0v=g1*df10, c1v=g1*df11, c2v=g1*df12;
  c0v=wred64(c0v); c1v=wred64(c1v); c2v=wred64(c2v);
  if (lane==0){ DSH1[e*3+0]+=inv*c0v; DSH1[e*3+1]+=inv*c1v; DSH1[e*3+2]+=inv*c2v; }
  float cc[5]={0,0,0,0,0};
  if (lane<32){
    float g2=g[el*224+192+lane];
    float dgv=0.0f;
    #pragma unroll
    for (int x=0;x<5;x++){ float dfv=df2[d*160+lane*5+x]; dgv+=dfv*SH2b[e*5+x]; cc[x]=g2*dfv; }
    DG[el*224+192+lane]=inv*dgv;
  }
  #pragma unroll
  for (int x=0;x<5;x++) cc[x]=wred64(cc[x]);
  if (lane==0){
    #pragma unroll
    for (int x=0;x<5;x++) DSH2[e*5+x]+=inv*cc[x];
  }
}

__global__ void k_geoback(const float* __restrict__ DRa, const float* __restrict__ DSH1, const float* __restrict__ DSH2,
                          const float* __restrict__ U, const float* __restrict__ Rr,
                          const int* __restrict__ src, const int* __restrict__ dst,
                          float* __restrict__ DPOS){
  int e=blockIdx.x*256+threadIdx.x;
  if (e>=NE) return;
  float ux=U[e*3+0], uy=U[e*3+1], uz=U[e*3+2];
  float r=Rr[e];
  float dux=SQ3F*DSH1[e*3+0], duy=SQ3F*DSH1[e*3+1], duz=SQ3F*DSH1[e*3+2];
  float d0=DSH2[e*5+0],d1=DSH2[e*5+1],d2=DSH2[e*5+2],d3=DSH2[e*5+3],d4=DSH2[e*5+4];
  dux += SQ15F*(uy*d0+uz*d3+ux*d4);
  duy += SQ15F*(ux*d0+uz*d1-uy*d4);
  duz += SQ15F*(uy*d1+ux*d3)+3.0f*SQ5F*uz*d2;
  float dr=DRa[e];
  float dot=dux*ux+duy*uy+duz*uz;
  float dvx=(dux-dot*ux)/r+dr*ux;
  float dvy=(duy-dot*uy)/r+dr*uy;
  float dvz=(duz-dot*uz)/r+dr*uz;
  int s=src[e], d=dst[e];
  atomicAdd(&DPOS[s*3+0],dvx); atomicAdd(&DPOS[s*3+1],dvy); atomicAdd(&DPOS[s*3+2],dvz);
  atomicAdd(&DPOS[d*3+0],-dvx); atomicAdd(&DPOS[d*3+1],-dvy); atomicAdd(&DPOS[d*3+2],-dvz);
}

__global__ void k_forces(const float* __restrict__ DPOS, float* __restrict__ o){
  int i=blockIdx.x*256+threadIdx.x;
  if (i<NN*3) o[i]=-DPOS[i];
}

// per-node LN + head forward + backward seeds; single wave per node
__global__ __launch_bounds__(64) void k_lnhead(
  const float* __restrict__ f0,const float* __restrict__ f1,const float* __restrict__ f2,
  const float* __restrict__ lng,const float* __restrict__ lnb,
  const float* __restrict__ W0,const float* __restrict__ hout,
  float* __restrict__ EN, float* __restrict__ df0,float* __restrict__ df1,float* __restrict__ df2)
{
  __shared__ float xh[480];
  __shared__ float fl[128];
  __shared__ float dyv[128];
  __shared__ float dxh[128];
  int n=blockIdx.x, lane=threadIdx.x;
  const float c0=1.0f/sqrtf(18.03f);
  for (int i=lane;i<480;i+=64){
    float v=(i<128)? f0[n*128+i] : (i<320)? f1[n*192+(i-128)] : f2[n*160+(i-320)];
    xh[i]=v;
  }
  __syncthreads();
  float s1=0.0f,s2=0.0f;
  for (int i=lane;i<480;i+=64){ float v=xh[i]; s1+=v; s2+=v*v; }
  s1=wred64(s1); s2=wred64(s2);
  float mu=__shfl(s1,0,64)*(1.0f/480.0f);
  float var=__shfl(s2,0,64)*(1.0f/480.0f)-mu*mu;
  float rstd=rsqrtf(var+1e-5f);
  for (int i=lane;i<480;i+=64) xh[i]=(xh[i]-mu)*rstd;
  __syncthreads();
  for (int k=lane;k<128;k+=64) fl[k]=xh[k]*lng[k]+lnb[k];
  __syncthreads();
  float y0=0.0f,y1=0.0f;
  for (int k=0;k<128;k++){ float f=fl[k]; y0+=f*W0[k*128+lane]; y1+=f*W0[k*128+lane+64]; }
  float e = siluf(y0)*hout[lane] + siluf(y1)*hout[lane+64];
  e=wred64(e);
  if (lane==0) EN[n]=e*c0;
  dyv[lane]=c0*hout[lane]*dsiluf(y0);
  dyv[lane+64]=c0*hout[lane+64]*dsiluf(y1);
  __syncthreads();
  float d0=0.0f,d1=0.0f;
  for (int j=0;j<128;j++){ float dv=dyv[j]; d0+=dv*W0[lane*128+j]; d1+=dv*W0[(lane+64)*128+j]; }
  dxh[lane]=d0*lng[lane];
  dxh[lane+64]=d1*lng[lane+64];
  __syncthreads();
  float s3=dxh[lane]+dxh[lane+64];
  float s4=dxh[lane]*xh[lane]+dxh[lane+64]*xh[lane+64];
  s3=wred64(s3); s4=wred64(s4);
  float m1=__shfl(s3,0,64)*(1.0f/480.0f);
  float m2=__shfl(s4,0,64)*(1.0f/480.0f);
  for (int i=lane;i<480;i+=64){
    float dv=rstd*(((i<128)?dxh[i]:0.0f)-m1-xh[i]*m2);
    if (i<128) df0[n*128+i]=dv;
    else if (i<320) df1[n*192+(i-128)]=dv;
    else df2[n*160+(i-320)]=dv;
  }
}

__global__ void k_esum(const float* __restrict__ EN, float* __restrict__ out){
  int b=blockIdx.x*64+threadIdx.x;
  if (b<NG){
    float s=0.0f;
    for (int k=0;k<16;k++) s+=EN[b*16+k];
    out[b]=s;
  }
}

#define MG(MT,TB,ACC,ACT,GA,SP,AR,DM,PO, A,IDX,B,C,M,Nd,K, CEN,WID,DMp,POp) \
  k_mgemm<MT,TB,ACC,ACT,GA,SP,AR,DM,PO><<<dim3((unsigned)(((M)+(MT)-1)/(MT)),(unsigned)(((Nd)+63)/64)),dim3(256),0,stream>>>((A),(IDX),(B),(C),(M),(Nd),(K),(CEN),(WID),(DMp),(POp))
#define MGEMM(TB,ACC,ACT,GA, A,IDX,B,C,M,Nd,K) MG(16,TB,ACC,ACT,GA,false,false,false,false, A,IDX,B,C,M,Nd,K, nullptr,nullptr,nullptr,nullptr)
#define MGEMM3(TB,ACC,ACT,GA, A,IDX,B,C,M,Nd,K) MG(16,TB,ACC,ACT,GA,true,false,false,false, A,IDX,B,C,M,Nd,K, nullptr,nullptr,nullptr,nullptr)
#define MEINS(CI,CO,X,TB,ACC,GA, A,IDX,Wt,C,M) \
  k_meinsum<CI,CO,X,TB,ACC,GA,false><<<dim3((unsigned)(((M)*(X)+63)/64)),dim3(256),0,stream>>>((A),(IDX),(Wt),(C),(M))
#define MEINS3(CI,CO,X,TB,ACC,GA, A,IDX,Wt,C,M) \
  k_meinsum<CI,CO,X,TB,ACC,GA,true><<<dim3((unsigned)(((M)*(X)+63)/64)),dim3(256),0,stream>>>((A),(IDX),(Wt),(C),(M))
#define G256(n) dim3((unsigned)(((n)+255)/256)),dim3(256),0,stream
#define GW4(n) dim3((unsigned)(((n)+3)/4)),dim3(256),0,stream

extern "C" void kernel_launch(void* const* d_in, const int* in_sizes, int n_in,
                              void* d_out, int out_size, void* d_ws, size_t ws_size,
                              hipStream_t stream)
{
  const float* pos =(const float*)d_in[0];
  const float* atab=(const float*)d_in[1];
  const float* rbfc=(const float*)d_in[2];
  const float* rbfw=(const float*)d_in[3];
  const float* degW1=(const float*)d_in[4];
  const float* degW2=(const float*)d_in[5];
  const float* degW3=(const float*)d_in[6];
  const float* Wv0=(const float*)d_in[7];
  const float* Wv1=(const float*)d_in[8];
  const float* Wv2=(const float*)d_in[9];
  const float* Ws0=(const float*)d_in[10];
  const float* Ws1=(const float*)d_in[11];
  const float* Ws2=(const float*)d_in[12];
  const float* rW1=(const float*)d_in[13];
  const float* rW2=(const float*)d_in[14];
  const float* rW3=(const float*)d_in[15];
  const float* WaS=(const float*)d_in[16];
  const float* WaD=(const float*)d_in[17];
  const float* WaE=(const float*)d_in[18];
  const float* wab=(const float*)d_in[19];
  const float* ff1=(const float*)d_in[20];
  const float* ff2=(const float*)d_in[21];
  const float* fg1=(const float*)d_in[22];
  const float* fg2=(const float*)d_in[23];
  const float* fW1=(const float*)d_in[24];
  const float* fW2=(const float*)d_in[25];
  const float* lng=(const float*)d_in[26];
  const float* lnb=(const float*)d_in[27];
  const float* W0h=(const float*)d_in[28];
  const float* hout=(const float*)d_in[29];
  const int* natom=(const int*)d_in[30];
  const int* esrc=(const int*)d_in[31];
  const int* edst=(const int*)d_in[32];

  float* Wp=(float*)d_ws;
  size_t off=0;
  auto al=[&](size_t n)->float*{ float* q=Wp+off; off+=n; return q; };

  const size_t SLOT = (size_t)NN*480;
  unsigned short* CKB = (unsigned short*)al((9*SLOT+1)/2);
  float* FA0=al((size_t)NN*128); float* FA1=al((size_t)NN*192); float* FA2=al((size_t)NN*160);
  float* FB0=al((size_t)NN*128); float* FB1=al((size_t)NN*192); float* FB2=al((size_t)NN*160);
  float* DI0=al((size_t)NN*128); float* DI1=al((size_t)NN*192); float* DI2=al((size_t)NN*160);
  float* DY0=al((size_t)NN*128); float* DY1=al((size_t)NN*192); float* DY2=al((size_t)NN*160);
  float* U=al((size_t)NE*3); float* Rr=al(NE); float* SH2b=al((size_t)NE*5);
  float* ABLK=al(8ULL*NE); float* LAM=al(NE);
  float* SSUM=al(NN); float* ENODE=al(NN); float* SACC=al(NN);
  float* DRr=al(NE); float* DSH1=al((size_t)NE*3); float* DSH2=al((size_t)NE*5);
  float* DPOS=al((size_t)NN*3);
  float* WCATF=al(8ULL*128*352);
  int* ROWS =(int*)al(NN+1);
  int* CNT  =(int*)al(NN);
  int* POSB =(int*)al(NN);
  int* PERMB=(int*)al(NE);
  int* ESRC2=(int*)al(NE);
  int* EDST2=(int*)al(NE);

  // ---- UNION region: chunk-local edge buffers overlap node-phase buffers (time-disjoint) ----
  const size_t CHU = (size_t)CH*1568;
  float* UN = al(CHU);
  // chunk-local (edge-loop phase only)
  float* PRE1=UN;
  float* PRE2=PRE1+(size_t)CH*64;
  float* H1  =PRE2+(size_t)CH*64;
  float* H2  =H1  +(size_t)CH*64;
  float* Gc  =H2  +(size_t)CH*64;
  float* DGc =Gc  +(size_t)CH*224;
  float* SCAT=DGc +(size_t)CH*224;
  float* SV1 =SCAT+(size_t)CH*352;
  float* SV2 =SV1 +(size_t)CH*192;
  float* Zc  =SV2 +(size_t)CH*160;
  float* DE0 =Zc  +(size_t)CH*32;
  // aliases: RBFc written only after SCAT's last read; DZD written only after Gc's last read
  float* RBFc=SCAT;
  float* DZD =Gc;
  // node-phase buffers (between edge loops only); all write-before-read each phase
  float* TBc=UN;
  float* DTc=TBc+(size_t)NNC*512;
  float* P1 =DTc+(size_t)NNC*512;
  float* P2 =P1 +(size_t)NN*64;
  float* V1 =P2 +(size_t)NN*32;
  float* V2 =V1 +(size_t)NN*192;
  float* DPb=V2 +(size_t)NN*160;
  float* F0N=DPb+(size_t)NN*64;

  float* outE=(float*)d_out;
  float* outF=outE+NG;

  if (off*sizeof(float) > ws_size){
    k_sentinel<<<G256(out_size)>>>(outE, out_size, (float)ws_size);
    return;
  }

  // ---------------- sort edges by dst ----------------
  (void)hipMemsetAsync(CNT,0,NN*sizeof(int),stream);
  k_hist<<<G256(NE)>>>(edst,CNT,NE);
  k_scan0<<<dim3(1),dim3(64),0,stream>>>(CNT,ROWS);
  (void)hipMemcpyAsync(POSB,ROWS,NN*sizeof(int),hipMemcpyDeviceToDevice,stream);
  k_fillperm<<<G256(NE)>>>(edst,POSB,PERMB,NE);
  k_mkedge<<<G256(NE)>>>(PERMB,esrc,edst,ESRC2,EDST2);
  k_wcat<<<G256(8*128*352)>>>(Wv0,Ws0,Ws1,Ws2,WCATF);

  // ---------------- setup ----------------
  k_geom<<<G256(NE)>>>(pos,ESRC2,EDST2,U,Rr,SH2b);
  k_f0init<<<G256(NN*128)>>>(natom,atab,FA0);
  (void)hipMemsetAsync(FA1,0,(size_t)NN*192*4,stream);
  (void)hipMemsetAsync(FA2,0,(size_t)NN*160*4,stream);
  (void)hipMemsetAsync(DRr,0,(size_t)NE*4,stream);
  (void)hipMemsetAsync(DSH1,0,(size_t)NE*3*4,stream);
  (void)hipMemsetAsync(DSH2,0,(size_t)NE*5*4,stream);
  (void)hipMemsetAsync(DPOS,0,(size_t)NN*3*4,stream);

  // degree embedding (chunked) -> FA  [split-bf16 + fused RBF]
  for (int cc=0;cc<NCHUNK;cc++){
    int c0e=cc*CH, cnt=(c0e+CH<=NE)?CH:(NE-c0e);
    MG(16,false,false,1,false, true,true,false,false, Rr+c0e,nullptr,degW1,H1, cnt,64,128, rbfc,rbfw,nullptr,nullptr);
    MGEMM3(false,false,1,false, H1,nullptr,degW2,H2, cnt,64,64);
    MGEMM3(false,false,0,false, H2,nullptr,degW3,Gc, cnt,224,64);
    k_agg<true><<<dim3(NG),dim3(512),0,stream>>>(FA0,FA1,FA2,
      nullptr,nullptr,nullptr, Gc,U,SH2b, nullptr, EDST2,EDST2, nullptr, c0e,c0e+cnt);
  }
  k_q3<<<G256(NN*480)>>>(FA0,FA1,FA2, CKB);

  float *c0_=FA0,*c1_=FA1,*c2_=FA2, *n0_=FB0,*n1_=FB1,*n2_=FB2;

  // ---------------- forward blocks [split-bf16] ----------------
  for (int i=0;i<8;i++){
    const float* Wv1i=Wv1+(size_t)i*4096; const float* Wv2i=Wv2+(size_t)i*1024;
    const float* rW1i=rW1+(size_t)i*8192; const float* rW2i=rW2+(size_t)i*4096; const float* rW3i=rW3+(size_t)i*14336;
    const float* WaSi=WaS+(size_t)i*4096; const float* WaDi=WaD+(size_t)i*4096; const float* WaEi=WaE+(size_t)i*2048;
    const float* ff1i=ff1+(size_t)i*65536; const float* ff2i=ff2+(size_t)i*65536;
    const float* fg1i=fg1+(size_t)i*8192; const float* fg2i=fg2+(size_t)i*4096;
    const float* fW1i=fW1+(size_t)i*4096; const float* fW2i=fW2+(size_t)i*1024;
    const float* WCi=WCATF+(size_t)i*45056;
    float* AB=ABLK+(size_t)i*NE;

    (void)hipMemsetAsync(SACC,0,(size_t)NN*4,stream);
    (void)hipMemsetAsync(n0_,0,(size_t)NN*128*4,stream);
    (void)hipMemsetAsync(n1_,0,(size_t)NN*192*4,stream);
    (void)hipMemsetAsync(n2_,0,(size_t)NN*160*4,stream);
    for (int cc=0;cc<NCHUNK;cc++){
      int c0e=cc*CH, cnt=(c0e+CH<=NE)?CH:(NE-c0e);
      MG(16,false,false,1,false, true,true,false,false, Rr+c0e,nullptr,rW1i,H1, cnt,64,128, rbfc,rbfw,nullptr,nullptr);
      MGEMM3(false,false,1,false, H1,nullptr,rW2i,H2, cnt,64,64);
      MGEMM3(false,false,0,false, H2,nullptr,rW3i,Gc, cnt,224,64);
      MGEMM3(false,false,0,true,  c0_,ESRC2+c0e,WaSi,Zc, cnt,32,128);
      MGEMM3(false,true, 0,true,  c0_,EDST2+c0e,WaDi,Zc, cnt,32,128);
      MGEMM3(false,true, 2,false, H2,nullptr,WaEi,Zc, cnt,32,64);
      k_lambda<<<G256(cnt)>>>(Zc, wab+(size_t)i*32, LAM+c0e, cnt);
      MGEMM3(false,false,0,true, c0_,ESRC2+c0e,WCi,SCAT, cnt,352,128);
      MEINS3(64,64,3,false,false,true, c1_,ESRC2+c0e,Wv1i,SV1, cnt);
      MEINS3(32,32,5,false,false,true, c2_,ESRC2+c0e,Wv2i,SV2, cnt);
      k_agg<false><<<dim3(NG),dim3(512),0,stream>>>(n0_,n1_,n2_,
        SCAT,SV1,SV2, Gc,U,SH2b, LAM, EDST2,EDST2, SACC, c0e,c0e+cnt);
    }
    k_norm<<<G256(NE)>>>(LAM,SACC,EDST2,AB);
    k_finy<<<G256(NN*480)>>>(c0_,c1_,c2_, n0_,n1_,n2_, SACC);
    k_q3<<<G256(NN*480)>>>(n0_,n1_,n2_, CKB+(size_t)(i+1)*SLOT);
    for (int nc=0;nc<NN/NNC;nc++){
      MGEMM3(false,false,1,false, n0_+(size_t)nc*NNC*128,nullptr,ff1i,TBc, NNC,512,128);
      MGEMM3(false,true, 0,false, TBc,nullptr,ff2i, n0_+(size_t)nc*NNC*128, NNC,128,512);
    }
    MGEMM3(false,false,3,false, n0_,nullptr,fg1i,P1, NN,64,128);
    MGEMM3(false,false,3,false, n0_,nullptr,fg2i,P2, NN,32,128);
    MEINS3(64,64,3,false,false,false, n1_,nullptr,fW1i,V1, NN);
    MEINS3(32,32,5,false,false,false, n2_,nullptr,fW2i,V2, NN);
    k_gatefwd<64,3><<<G256(NN*192)>>>(n1_,V1,P1);
    k_gatefwd<32,5><<<G256(NN*160)>>>(n2_,V2,P2);
    float* t;
    t=c0_;c0_=n0_;n0_=t; t=c1_;c1_=n1_;n1_=t; t=c2_;c2_=n2_;n2_=t;
  }

  // ---------------- head ----------------
  k_lnhead<<<dim3(NN),dim3(64),0,stream>>>(c0_,c1_,c2_, lng,lnb,W0h,hout, ENODE, DI0,DI1,DI2);
  k_esum<<<dim3(8),dim3(64),0,stream>>>(ENODE,outE);

  // ---------------- backward blocks [plain bf16 MFMA, fused epilogues] ----------------
  for (int i=7;i>=0;--i){
    const float* Wv1i=Wv1+(size_t)i*4096; const float* Wv2i=Wv2+(size_t)i*1024;
    const float* rW1i=rW1+(size_t)i*8192; const float* rW2i=rW2+(size_t)i*4096; const float* rW3i=rW3+(size_t)i*14336;
    const float* WaSi=WaS+(size_t)i*4096; const float* WaDi=WaD+(size_t)i*4096; const float* WaEi=WaE+(size_t)i*2048;
    const float* ff1i=ff1+(size_t)i*65536; const float* ff2i=ff2+(size_t)i*65536;
    const float* fg1i=fg1+(size_t)i*8192; const float* fg2i=fg2+(size_t)i*4096;
    const float* fW1i=fW1+(size_t)i*4096; const float* fW2i=fW2+(size_t)i*1024;
    const float* WCi=WCATF+(size_t)i*45056;
    const float* AB=ABLK+(size_t)i*NE;

    k_dq3<<<G256(NN*480)>>>(CKB+(size_t)i*SLOT, FA0,FA1,FA2);
    if (i>0){
      const float* pf1=ff1+(size_t)(i-1)*65536; const float* pf2=ff2+(size_t)(i-1)*65536;
      const float* pg1=fg1+(size_t)(i-1)*8192; const float* pg2=fg2+(size_t)(i-1)*4096;
      const float* pW1=fW1+(size_t)(i-1)*4096; const float* pW2=fW2+(size_t)(i-1)*1024;
      for (int nc=0;nc<NN/NNC;nc++){
        MGEMM(false,false,1,false, FA0+(size_t)nc*NNC*128,nullptr,pf1,TBc, NNC,512,128);
        MGEMM(false,true, 0,false, TBc,nullptr,pf2, FA0+(size_t)nc*NNC*128, NNC,128,512);
      }
      MGEMM(false,false,3,false, FA0,nullptr,pg1,P1, NN,64,128);
      MGEMM(false,false,3,false, FA0,nullptr,pg2,P2, NN,32,128);
      MEINS(64,64,3,false,false,false, FA1,nullptr,pW1,V1, NN);
      MEINS(32,32,5,false,false,false, FA2,nullptr,pW2,V2, NN);
      k_gatefwd<64,3><<<G256(NN*192)>>>(FA1,V1,P1);
      k_gatefwd<32,5><<<G256(NN*160)>>>(FA2,V2,P2);
    }
    k_dq3<<<G256(NN*480)>>>(CKB+(size_t)(i+1)*SLOT, FB0,FB1,FB2);
    (void)hipMemcpyAsync(F0N,FB0,(size_t)NN*128*4,hipMemcpyDeviceToDevice,stream);
    for (int nc=0;nc<NN/NNC;nc++){
      MGEMM(false,false,1,false, FB0+(size_t)nc*NNC*128,nullptr,ff1i,TBc, NNC,512,128);
      MGEMM(false,true, 0,false, TBc,nullptr,ff2i, F0N+(size_t)nc*NNC*128, NNC,128,512);
    }
    MGEMM(false,false,3,false, F0N,nullptr,fg1i,P1, NN,64,128);
    MGEMM(false,false,3,false, F0N,nullptr,fg2i,P2, NN,32,128);
    MEINS(64,64,3,false,false,false, FB1,nullptr,fW1i,V1, NN);
    MEINS(32,32,5,false,false,false, FB2,nullptr,fW2i,V2, NN);
    k_gateback<64,3><<<G256(NN*64)>>>(DI1,V1,P1,DPb);
    MGEMM(true,true,0,false, DPb,nullptr,fg1i,DI0, NN,128,64);
    (void)hipMemcpyAsync(DY1,DI1,(size_t)NN*192*4,hipMemcpyDeviceToDevice,stream);
    MEINS(64,64,3,true,true,false, V1,nullptr,fW1i,DY1, NN);
    k_gateback<32,5><<<G256(NN*32)>>>(DI2,V2,P2,DPb);
    MGEMM(true,true,0,false, DPb,nullptr,fg2i,DI0, NN,128,32);
    (void)hipMemcpyAsync(DY2,DI2,(size_t)NN*160*4,hipMemcpyDeviceToDevice,stream);
    MEINS(32,32,5,true,true,false, V2,nullptr,fW2i,DY2, NN);
    (void)hipMemcpyAsync(DY0,DI0,(size_t)NN*128*4,hipMemcpyDeviceToDevice,stream);
    for (int nc=0;nc<NN/NNC;nc++){
      MGEMM(false,false,0,false, FB0+(size_t)nc*NNC*128,nullptr,ff1i,TBc, NNC,512,128);
      MG(16,true,false,0,false, false,false,true,false, DI0+(size_t)nc*NNC*128,nullptr,ff2i,DTc, NNC,512,128, nullptr,nullptr,TBc,nullptr);
      MGEMM(true,true,0,false, DTc,nullptr,ff1i, DY0+(size_t)nc*NNC*128, NNC,128,512);
    }
    k_ssum<<<dim3(NN/4),dim3(256),0,stream>>>(FA0,FA1,FA2,FB0,FB1,FB2,DY0,DY1,DY2,SSUM);
    (void)hipMemcpyAsync(DI0,DY0,(size_t)NN*128*4,hipMemcpyDeviceToDevice,stream);
    (void)hipMemcpyAsync(DI1,DY1,(size_t)NN*192*4,hipMemcpyDeviceToDevice,stream);
    (void)hipMemcpyAsync(DI2,DY2,(size_t)NN*160*4,hipMemcpyDeviceToDevice,stream);
    for (int cc=0;cc<NCHUNK;cc++){
      int c0e=cc*CH, cnt=(c0e+CH<=NE)?CH:(NE-c0e);
      MG(16,false,false,1,false, false,true,false,true, Rr+c0e,nullptr,rW1i,H1, cnt,64,128, rbfc,rbfw,nullptr,PRE1);
      MG(16,false,false,1,false, false,false,false,true, H1,nullptr,rW2i,H2, cnt,64,64, nullptr,nullptr,nullptr,PRE2);
      MGEMM(false,false,0,false, H2,nullptr,rW3i,Gc, cnt,224,64);
      MGEMM(false,false,0,true,  FA0,ESRC2+c0e,WaSi,Zc, cnt,32,128);
      MGEMM(false,true, 0,true,  FA0,EDST2+c0e,WaDi,Zc, cnt,32,128);
      MGEMM(false,true, 2,false, H2,nullptr,WaEi,Zc, cnt,32,64);
      MGEMM(false,false,0,true, FA0,ESRC2+c0e,WCi,SCAT, cnt,352,128);
      MEINS(64,64,3,false,false,true, FA1,ESRC2+c0e,Wv1i,SV1, cnt);
      MEINS(32,32,5,false,false,true, FA2,ESRC2+c0e,Wv2i,SV2, cnt);
      k_bedge<<<GW4(cnt)>>>(SCAT,SV1,SV2, Gc,U,SH2b, DY0,DY1,DY2, EDST2, SSUM,
                            wab+(size_t)i*32, Zc, AB, DGc, DSH1, DSH2, c0e, cnt);
      MGEMM(true,false,0,false, SCAT,nullptr,WCi,DE0, cnt,128,352);
      MGEMM(true,true, 0,false, Zc,nullptr,WaSi,DE0, cnt,128,32);
      MGEMM(true,false,0,false, Zc,nullptr,WaDi,DZD, cnt,128,32);
      MEINS(64,64,3,true,false,false, SV1,nullptr,Wv1i,SV1, cnt);
      MEINS(32,32,5,true,false,false, SV2,nullptr,Wv2i,SV2, cnt);
      MGEMM(true,false,0,false, Zc,nullptr,WaEi,H2, cnt,64,32);
      MG(16,true,true,0,false, false,false,true,false, DGc,nullptr,rW3i,H2, cnt,64,224, nullptr,nullptr,PRE2,nullptr);
      MG(16,true,false,0,false, false,false,true,false, H2,nullptr,rW2i,H1, cnt,64,64, nullptr,nullptr,PRE1,nullptr);
      MGEMM(true,false,0,false, H1,nullptr,rW1i,RBFc, cnt,128,64);
      k_dr<<<GW4(cnt)>>>(RBFc,Rr,rbfc,rbfw,DRr, c0e,cnt);
      k_scat<<<dim3(NG),dim3(640),0,stream>>>(DI0,DI1,DI2, DE0,DZD,SV1,SV2, ESRC2,EDST2, c0e,c0e+cnt);
    }
  }

  // ---------------- initial embedding backward [fused] ----------------
  for (int cc=0;cc<NCHUNK;cc++){
    int c0e=cc*CH, cnt=(c0e+CH<=NE)?CH:(NE-c0e);
    MG(16,false,false,1,false, false,true,false,true, Rr+c0e,nullptr,degW1,H1, cnt,64,128, rbfc,rbfw,nullptr,PRE1);
    MG(16,false,false,1,false, false,false,false,true, H1,nullptr,degW2,H2, cnt,64,64, nullptr,nullptr,nullptr,PRE2);
    MGEMM(false,false,0,false, H2,nullptr,degW3,Gc, cnt,224,64);
    k_initback<<<GW4(cnt)>>>(DI0,DI1,DI2,EDST2,Gc,U,SH2b,DGc,DSH1,DSH2, c0e,cnt);
    MG(16,true,false,0,false, false,false,true,false, DGc,nullptr,degW3,H2, cnt,64,224, nullptr,nullptr,PRE2,nullptr);
    MG(16,true,false,0,false, false,false,true,false, H2,nullptr,degW2,H1, cnt,64,64, nullptr,nullptr,PRE1,nullptr);
    MGEMM(true,false,0,false, H1,nullptr,degW1,RBFc, cnt,128,64);
    k_dr<<<GW4(cnt)>>>(RBFc,Rr,rbfc,rbfw,DRr, c0e,cnt);
  }

  // ---------------- geometry backward + outputs ----------------
  k_geoback<<<G256(NE)>>>(DRr,DSH1,DSH2,U,Rr,ESRC2,EDST2,DPOS);
  k_forces<<<G256(NN*3)>>>(DPOS,outF);
  (void)in_sizes; (void)n_in; (void)out_size;
}

// Round 20
// 38018.387 us; speedup vs baseline: 1.8890x; 1.0980x over previous
//
#include <hip/hip_runtime.h>
#include <string.h>
#include <math.h>

#define NE 100000
#define NN 8192
#define NG 512
#define CHF 25000
#define NF 4
#define CHB 16700
#define NB 6
#define CHIF 50000
#define NIF 2
#define CHIB 34000
#define NIB 3
#define NNC 2048

#define SQ3F  1.7320508075688772f
#define SQ5F  2.23606797749979f
#define SQ15F 3.872983346207417f

__constant__ int c_amap[10] = {-1,0,-1,-1,-1,-1,1,2,3,4};

typedef __attribute__((ext_vector_type(4))) float f32x4;
typedef __attribute__((ext_vector_type(8))) short bf16x8;

__device__ __forceinline__ float sigf(float x){ return 1.0f/(1.0f+expf(-x)); }
__device__ __forceinline__ float siluf(float x){ return x*sigf(x); }
__device__ __forceinline__ float dsiluf(float x){ float s=sigf(x); return s*(1.0f + x*(1.0f-s)); }

__device__ __forceinline__ float wred64(float v){
  #pragma unroll
  for (int o=32;o>0;o>>=1) v += __shfl_down(v,o,64);
  return v;
}
__device__ __forceinline__ int lbound(const int* a, int n, int v){
  int lo=0, hi=n;
  while (lo<hi){ int m=(lo+hi)>>1; if (a[m]<v) lo=m+1; else hi=m; }
  return lo;
}
__device__ __forceinline__ unsigned short f2b(float x){
  unsigned u=__float_as_uint(x);
  unsigned r=(u + 0x7fffu + ((u>>16)&1u))>>16;
  return (unsigned short)r;
}
__device__ __forceinline__ float b2f(unsigned short b){
  return __uint_as_float(((unsigned)b)<<16);
}

// ---------------- edge sort by dst (counting sort) ----------------
__global__ void k_hist(const int* keys, int* hist, int n){
  int i = blockIdx.x*256 + threadIdx.x;
  if (i < n) atomicAdd(&hist[keys[i]], 1);
}
__global__ void k_scan0(const int* hist, int* rows){
  if (threadIdx.x == 0 && blockIdx.x == 0){
    int acc = 0;
    for (int i = 0; i < NN; i++){ rows[i] = acc; acc += hist[i]; }
    rows[NN] = acc;
  }
}
__global__ void k_fillperm(const int* keys, int* cursor, int* perm, int n){
  int i = blockIdx.x*256 + threadIdx.x;
  if (i < n){
    int slot = atomicAdd(&cursor[keys[i]], 1);
    perm[slot] = i;
  }
}
__global__ void k_mkedge(const int* perm, const int* src, const int* dst, int* src2, int* dst2){
  int k = blockIdx.x*256 + threadIdx.x;
  if (k < NE){ int e = perm[k]; src2[k] = src[e]; dst2[k] = dst[e]; }
}

// weight concat: WCATF[i][k][0:352] = [Wv0 | Ws0 | Ws1 | Ws2]
__global__ void k_wcat(const float* Wv0,const float* Ws0,const float* Ws1,const float* Ws2, float* W){
  int t = blockIdx.x*256 + threadIdx.x;
  if (t >= 8*128*352) return;
  int i = t/45056, r = t - i*45056;
  int k = r/352, n = r - k*352;
  float v;
  if (n < 128) v = Wv0[(size_t)i*16384 + k*128 + n];
  else if (n < 256) v = Ws0[(size_t)i*16384 + k*128 + (n-128)];
  else if (n < 320) v = Ws1[(size_t)i*8192 + k*64 + (n-256)];
  else v = Ws2[(size_t)i*4096 + k*32 + (n-320)];
  W[t] = v;
}

// --- bf16 MFMA GEMM; MT = M-tile (64 or 16); SPLIT=3-term split-bf16; ARBF=A computed as RBF(Rr row);
//     DMUL=epilogue *dsilu(dm); PREOUT=write pre-activation to pre[] ---
template<int MT, bool TB, bool ACC, int ACT, bool GATHER, bool SPLIT, bool ARBF, bool DMUL, bool PREOUT>
__global__ __launch_bounds__(256) void k_mgemm(
    const float* __restrict__ A, const int* __restrict__ idx,
    const float* __restrict__ B, float* __restrict__ C,
    int M, int Nd, int K,
    const float* __restrict__ cen, const float* __restrict__ wid,
    const float* __restrict__ dm, float* __restrict__ pre)
{
  constexpr int TPR = 256/MT;     // threads per A-row
  constexpr int EPT = 32/TPR;     // elems per thread (A staging)
  constexpr int RT  = MT/16;      // MFMA row-tiles
  __shared__ unsigned short Asb[(SPLIT?2:1)*MT*40];
  __shared__ unsigned short Btb[(SPLIT?2:1)*2560];
  const int bm = blockIdx.x*MT, bn = blockIdx.y*64;
  const int tid = threadIdx.x;
  const int wave = tid>>6, lane = tid&63;
  const int arow_s = tid / TPR, aoff = (tid % TPR) * EPT;
  const int bsrow = tid>>2, bsoff = (tid&3)*8;
  f32x4 acc[RT];
  #pragma unroll
  for (int r=0;r<RT;r++) acc[r] = (f32x4){0.f,0.f,0.f,0.f};
  int arow = -1;
  {
    int gr = bm + arow_s;
    if (gr < M) arow = GATHER ? idx[gr] : gr;
  }
  int bcol = bn + bsrow;
  for (int k0=0;k0<K;k0+=32){
    #pragma unroll
    for (int i=0;i<EPT;i++){
      float v = 0.0f;
      if (arow>=0){
        if (ARBF){
          float r = A[arow];
          int kk = k0 + aoff + i;
          float t = (r - cen[kk]) / wid[kk];
          v = expf(-0.5f*t*t);
        } else {
          v = A[(size_t)arow*K + k0 + aoff + i];
        }
      }
      unsigned short h = f2b(v);
      Asb[arow_s*40 + aoff + i] = h;
      if (SPLIT) Asb[MT*40 + arow_s*40 + aoff + i] = f2b(v - b2f(h));
    }
    #pragma unroll
    for (int i=0;i<8;i++){
      float v = 0.0f;
      if (bcol < Nd) v = TB ? B[(size_t)bcol*K + k0 + bsoff + i] : B[(size_t)(k0+bsoff+i)*Nd + bcol];
      unsigned short h = f2b(v);
      Btb[bsrow*40 + bsoff + i] = h;
      if (SPLIT) Btb[2560 + bsrow*40 + bsoff + i] = f2b(v - b2f(h));
    }
    __syncthreads();
    int boff = (wave*16 + (lane&15))*40 + (lane>>4)*8;
    bf16x8 bh = *(const bf16x8*)&Btb[boff];
    #pragma unroll
    for (int r=0;r<RT;r++){
      int aoff2 = (r*16 + (lane&15))*40 + (lane>>4)*8;
      bf16x8 ah = *(const bf16x8*)&Asb[aoff2];
      acc[r] = __builtin_amdgcn_mfma_f32_16x16x32_bf16(ah, bh, acc[r], 0,0,0);
      if (SPLIT){
        bf16x8 bl = *(const bf16x8*)&Btb[2560 + boff];
        bf16x8 al = *(const bf16x8*)&Asb[MT*40 + aoff2];
        acc[r] = __builtin_amdgcn_mfma_f32_16x16x32_bf16(ah, bl, acc[r], 0,0,0);
        acc[r] = __builtin_amdgcn_mfma_f32_16x16x32_bf16(al, bh, acc[r], 0,0,0);
      }
    }
    __syncthreads();
  }
  int col = bn + wave*16 + (lane&15);
  if (col < Nd){
    #pragma unroll
    for (int r=0;r<RT;r++){
      #pragma unroll
      for (int v=0;v<4;v++){
        int row = bm + r*16 + (lane>>4)*4 + v;
        if (row >= M) continue;
        size_t o = (size_t)row*Nd + col;
        float x = acc[r][v];
        if (ACC) x += C[o];
        if (DMUL) x *= dsiluf(dm[o]);
        if (PREOUT) pre[o] = x;
        if (ACT == 1) x = siluf(x);
        else if (ACT == 2) x = tanhf(x);
        else if (ACT == 3) x = sigf(x);
        C[o] = x;
      }
    }
  }
}

// ---------- bf16 MFMA einsum (X-strided rows); SPLIT => split-bf16 ----------
template<int CI, int CO, int X, bool TB, bool ACC, bool GATHER, bool SPLIT>
__global__ __launch_bounds__(256) void k_meinsum(
    const float* __restrict__ A, const int* __restrict__ idx,
    const float* __restrict__ W, float* __restrict__ C, int M)
{
  __shared__ unsigned short Asb[(SPLIT?2:1)*2560];
  __shared__ unsigned short Btb[(SPLIT?2:1)*2560];
  const int bm = blockIdx.x*64;
  const int tid = threadIdx.x, wave = tid>>6, lane = tid&63;
  const int srow = tid>>2, soff = (tid&3)*8;
  f32x4 acc[4];
  #pragma unroll
  for (int r=0;r<4;r++) acc[r] = (f32x4){0.f,0.f,0.f,0.f};
  long abase = -1;
  {
    int grow = bm + srow;
    if (grow < M*X){
      int ge = grow / X, gx = grow - ge*X;
      int ar = GATHER ? idx[ge] : ge;
      abase = (long)ar*CI*X + gx;
    }
  }
  for (int k0=0;k0<CI;k0+=32){
    #pragma unroll
    for (int i=0;i<8;i++){
      float v = (abase>=0) ? A[abase + (size_t)(k0+soff+i)*X] : 0.0f;
      unsigned short h = f2b(v);
      Asb[srow*40 + soff + i] = h;
      if (SPLIT) Asb[2560 + srow*40 + soff + i] = f2b(v - b2f(h));
    }
    #pragma unroll
    for (int i=0;i<8;i++){
      int kk = k0 + soff + i;
      float v = 0.0f;
      if (srow < CO) v = TB ? W[srow*CI + kk] : W[kk*CO + srow];
      unsigned short h = f2b(v);
      Btb[srow*40 + soff + i] = h;
      if (SPLIT) Btb[2560 + srow*40 + soff + i] = f2b(v - b2f(h));
    }
    __syncthreads();
    int boff = (wave*16 + (lane&15))*40 + (lane>>4)*8;
    bf16x8 bh = *(const bf16x8*)&Btb[boff];
    #pragma unroll
    for (int r=0;r<4;r++){
      int aoff = (r*16 + (lane&15))*40 + (lane>>4)*8;
      bf16x8 ah = *(const bf16x8*)&Asb[aoff];
      acc[r] = __builtin_amdgcn_mfma_f32_16x16x32_bf16(ah, bh, acc[r], 0,0,0);
      if (SPLIT){
        bf16x8 bl = *(const bf16x8*)&Btb[2560 + boff];
        bf16x8 al = *(const bf16x8*)&Asb[2560 + aoff];
        acc[r] = __builtin_amdgcn_mfma_f32_16x16x32_bf16(ah, bl, acc[r], 0,0,0);
        acc[r] = __builtin_amdgcn_mfma_f32_16x16x32_bf16(al, bh, acc[r], 0,0,0);
      }
    }
    __syncthreads();
  }
  int col = wave*16 + (lane&15);
  if (col < CO){
    #pragma unroll
    for (int r=0;r<4;r++){
      #pragma unroll
      for (int v=0;v<4;v++){
        int row = bm + r*16 + (lane>>4)*4 + v;
        if (row >= M*X) continue;
        int ge = row / X, gx = row - ge*X;
        size_t o = (size_t)ge*CO*X + (size_t)col*X + gx;
        float xx = acc[r][v];
        if (ACC) xx += C[o];
        C[o] = xx;
      }
    }
  }
}

// ------------------------- small kernels -------------------------
__global__ void k_sentinel(float* o, int n, float v){
  int i = blockIdx.x*256 + threadIdx.x;
  if (i < n) o[i] = v;
}

__global__ void k_geom(const float* __restrict__ pos, const int* __restrict__ src, const int* __restrict__ dst,
                       float* __restrict__ U, float* __restrict__ Rr, float* __restrict__ SH2b){
  int e = blockIdx.x*256 + threadIdx.x;
  if (e >= NE) return;
  int s = src[e], d = dst[e];
  float vx = pos[s*3+0]-pos[d*3+0];
  float vy = pos[s*3+1]-pos[d*3+1];
  float vz = pos[s*3+2]-pos[d*3+2];
  float r = sqrtf(vx*vx+vy*vy+vz*vz + 1e-12f);
  float ux=vx/r, uy=vy/r, uz=vz/r;
  U[e*3+0]=ux; U[e*3+1]=uy; U[e*3+2]=uz;
  Rr[e]=r;
  SH2b[e*5+0]=SQ15F*ux*uy;
  SH2b[e*5+1]=SQ15F*uy*uz;
  SH2b[e*5+2]=0.5f*SQ5F*(3.0f*uz*uz-1.0f);
  SH2b[e*5+3]=SQ15F*ux*uz;
  SH2b[e*5+4]=0.5f*SQ15F*(ux*ux-uy*uy);
}

__global__ void k_f0init(const int* __restrict__ na, const float* __restrict__ at, float* __restrict__ f0){
  int t = blockIdx.x*256 + threadIdx.x;
  if (t >= NN*128) return;
  int n = t>>7, j = t&127;
  int m = c_amap[na[n]];
  f0[t] = at[m*128+j];
}

// lambda -> p = exp(lambda)
__global__ void k_lambda(const float* __restrict__ Z, const float* __restrict__ wa, float* __restrict__ P_c, int cnt){
  int e = blockIdx.x*256 + threadIdx.x;
  if (e >= cnt) return;
  float s = 0.0f;
  #pragma unroll
  for (int k=0;k<32;k++) s += Z[e*32+k]*wa[k];
  P_c[e] = expf(s);
}

__global__ void k_norm(const float* __restrict__ P, const float* __restrict__ S,
                       const int* __restrict__ dst, float* __restrict__ AB){
  int e = blockIdx.x*256 + threadIdx.x;
  if (e < NE) AB[e] = P[e]/(S[dst[e]]+1e-9f);
}

__global__ void k_finy(const float* __restrict__ x0,const float* __restrict__ x1,const float* __restrict__ x2,
                       float* __restrict__ y0,float* __restrict__ y1,float* __restrict__ y2,
                       const float* __restrict__ S){
  int t = blockIdx.x*256 + threadIdx.x;
  if (t >= NN*480) return;
  if (t < NN*128){ int n=t>>7; y0[t]=x0[t]+y0[t]/(S[n]+1e-9f); }
  else if (t < NN*320){ int q=t-NN*128; int n=q/192; y1[q]=x1[q]+y1[q]/(S[n]+1e-9f); }
  else { int q=t-NN*320; int n=q/160; y2[q]=x2[q]+y2[q]/(S[n]+1e-9f); }
}

// bf16 checkpoint quant/dequant
__global__ void k_q3(const float* __restrict__ f0,const float* __restrict__ f1,const float* __restrict__ f2,
                     unsigned short* __restrict__ ck){
  int t = blockIdx.x*256 + threadIdx.x;
  if (t >= NN*480) return;
  float v;
  if (t < NN*128) v = f0[t];
  else if (t < NN*320) v = f1[t-NN*128];
  else v = f2[t-NN*320];
  ck[t] = f2b(v);
}
__global__ void k_dq3(const unsigned short* __restrict__ ck,
                      float* __restrict__ f0,float* __restrict__ f1,float* __restrict__ f2){
  int t = blockIdx.x*256 + threadIdx.x;
  if (t >= NN*480) return;
  float v = b2f(ck[t]);
  if (t < NN*128) f0[t]=v;
  else if (t < NN*320) f1[t-NN*128]=v;
  else f2[t-NN*320]=v;
}

// per-graph aggregation; SC strided 352 [sv0|sw0|sw1|sw2]; accumulates S in lanes 480..495
template<bool INIT>
__global__ __launch_bounds__(512) void k_agg(
  float* __restrict__ f0o,float* __restrict__ f1o,float* __restrict__ f2o,
  const float* __restrict__ SC,const float* __restrict__ sv1,const float* __restrict__ sv2,
  const float* __restrict__ g,const float* __restrict__ U,const float* __restrict__ SH2b,
  const float* __restrict__ aArr,const int* __restrict__ keys,const int* __restrict__ dst,
  float* __restrict__ SACC, int c0, int c1)
{
  __shared__ float acc[7680];
  int b = blockIdx.x, lo = b<<4;
  int e0 = lbound(keys, NE, lo), e1 = lbound(keys, NE, lo+16);
  if (e0 < c0) e0 = c0;
  if (e1 > c1) e1 = c1;
  if (e0 >= e1) return;
  for (int i=threadIdx.x;i<7680;i+=512) acc[i]=0.0f;
  __syncthreads();
  const int j = threadIdx.x;
  const float inv = 1.0f/sqrtf(15.57f);
  int cat=3, cc_=0, xx_=0;
  if (j<128){ cat=0; }
  else if (j<320){ cat=1; int t=j-128; cc_=t/3; xx_=t-3*cc_; }
  else if (j<480){ cat=2; int t=j-320; cc_=t/5; xx_=t-5*cc_; }
  float sacc=0.0f;
  for (int e=e0; e<e1; ++e){
    int el = e - c0;
    float a = INIT ? inv : aArr[e];
    int nl = dst[e]&15;
    if (cat==0){
      float m = INIT ? g[el*224+j] : (SC[(size_t)el*352+j]*g[el*224+j] + SC[(size_t)el*352+128+j]);
      acc[nl*480+j] += a*m;
    } else if (cat==1){
      int t=j-128;
      float sh = SQ3F*U[e*3+xx_];
      float m = INIT ? g[el*224+128+cc_]*sh : (sv1[el*192+t]*g[el*224+128+cc_] + SC[(size_t)el*352+256+cc_]*sh);
      acc[nl*480+j] += a*m;
    } else if (cat==2){
      int t=j-320;
      float sh = SH2b[e*5+xx_];
      float m = INIT ? g[el*224+192+cc_]*sh : (sv2[el*160+t]*g[el*224+192+cc_] + SC[(size_t)el*352+320+cc_]*sh);
      acc[nl*480+j] += a*m;
    } else if (!INIT && j<496){
      if (nl==(j-480)) sacc += a;
    }
  }
  __syncthreads();
  for (int i=threadIdx.x;i<7680;i+=512){
    int nl=i/480, jj=i-480*nl, n=lo+nl;
    float v=acc[i];
    if (jj<128) f0o[n*128+jj]+=v;
    else if (jj<320) f1o[n*192+jj-128]+=v;
    else f2o[n*160+jj-320]+=v;
  }
  if (!INIT && j>=480 && j<496) SACC[lo+(j-480)] += sacc;
}

// per-graph scatter of edge grads
__global__ __launch_bounds__(640) void k_scat(
  float* __restrict__ df0, float* __restrict__ df1, float* __restrict__ df2,
  const float* __restrict__ DE0, const float* __restrict__ DZD,
  const float* __restrict__ DE1, const float* __restrict__ DE2,
  const int* __restrict__ src, const int* __restrict__ dst, int c0, int c1)
{
  __shared__ float acc[7680];
  int b=blockIdx.x, lo=b<<4;
  int e0=lbound(dst,NE,lo), e1=lbound(dst,NE,lo+16);
  if (e0 < c0) e0 = c0;
  if (e1 > c1) e1 = c1;
  for (int i=threadIdx.x;i<7680;i+=640) acc[i]=0.0f;
  __syncthreads();
  const int j=threadIdx.x;
  for (int e=e0;e<e1;++e){
    int el=e-c0;
    int sl=(src[e]&15)*480, dl=(dst[e]&15)*480;
    if (j<128) acc[sl+j] += DE0[el*128+j];
    else if (j<256){ int q=j-128; acc[dl+q] += DZD[el*128+q]; }
    else if (j<448){ int q=j-256; acc[sl+128+q] += DE1[el*192+q]; }
    else if (j<608){ int q=j-448; acc[sl+320+q] += DE2[el*160+q]; }
    __syncthreads();
  }
  for (int i=threadIdx.x;i<7680;i+=640){
    int nl=i/480, jj=i-480*nl, n=lo+nl;
    float v=acc[i];
    if (jj<128) df0[n*128+jj]+=v;
    else if (jj<320) df1[n*192+jj-128]+=v;
    else df2[n*160+jj-320]+=v;
  }
}

// SSUM[n] = (FB[n]-FA[n]) . DY[n]
__global__ __launch_bounds__(256) void k_ssum(
  const float* __restrict__ FA0,const float* __restrict__ FA1,const float* __restrict__ FA2,
  const float* __restrict__ FB0,const float* __restrict__ FB1,const float* __restrict__ FB2,
  const float* __restrict__ DY0,const float* __restrict__ DY1,const float* __restrict__ DY2,
  float* __restrict__ SSUM)
{
  int n=blockIdx.x*4+(threadIdx.x>>6), lane=threadIdx.x&63;
  if (n>=NN) return;
  float s=0.0f;
  for (int j=lane;j<480;j+=64){
    float d,g;
    if (j<128){ d=FB0[n*128+j]-FA0[n*128+j]; g=DY0[n*128+j]; }
    else if (j<320){ int q=j-128; d=FB1[n*192+q]-FA1[n*192+q]; g=DY1[n*192+q]; }
    else { int q=j-320; d=FB2[n*160+q]-FA2[n*160+q]; g=DY2[n*160+q]; }
    s += d*g;
  }
  s = wred64(s);
  if (lane==0) SSUM[n]=s;
}

// fused backward edge chain: da -> dlam -> dz -> split0/1/2 ; one wave per edge
__global__ __launch_bounds__(256) void k_bedge(
  float* __restrict__ SC, float* __restrict__ SV1, float* __restrict__ SV2,
  const float* __restrict__ g, const float* __restrict__ U, const float* __restrict__ SH2b,
  const float* __restrict__ df0,const float* __restrict__ df1,const float* __restrict__ df2,
  const int* __restrict__ dst, const float* __restrict__ SSUM, const float* __restrict__ wa,
  float* __restrict__ Z, const float* __restrict__ aArr,
  float* __restrict__ DG, float* __restrict__ DSH1, float* __restrict__ DSH2,
  int c0, int cnt)
{
  int w=threadIdx.x>>6, lane=threadIdx.x&63;
  int el=blockIdx.x*4+w;
  if (el>=cnt) return;
  int e=c0+el;
  int d=dst[e];
  float s=0.0f;
  for (int j=lane;j<480;j+=64){
    float m, dfv;
    if (j<128){
      m = SC[(size_t)el*352+j]*g[el*224+j] + SC[(size_t)el*352+128+j];
      dfv = df0[(size_t)d*128+j];
    } else if (j<320){
      int t=j-128, c=t/3, x=t-3*c;
      m = SV1[el*192+t]*g[el*224+128+c] + SC[(size_t)el*352+256+c]*(SQ3F*U[e*3+x]);
      dfv = df1[(size_t)d*192+t];
    } else {
      int t=j-320, c=t/5, x=t-5*c;
      m = SV2[el*160+t]*g[el*224+192+c] + SC[(size_t)el*352+320+c]*SH2b[e*5+x];
      dfv = df2[(size_t)d*160+t];
    }
    s += m*dfv;
  }
  s = wred64(s);
  s = __shfl(s,0,64);
  float a = aArr[e];
  float dlam = a*(s - SSUM[d]);
  if (lane<32){
    float z = Z[(size_t)el*32+lane];
    Z[(size_t)el*32+lane] = dlam*wa[lane]*(1.0f-z*z);
  }
  {
    float* row = SC + (size_t)el*352;
    for (int j=lane;j<128;j+=64){
      float dm = a*df0[(size_t)d*128+j];
      float sv = row[j];
      row[128+j] = dm;
      row[j] = dm*g[el*224+j];
      DG[el*224+j] = dm*sv;
    }
  }
  {
    float dm0=a*df1[(size_t)d*192+lane*3+0];
    float dm1=a*df1[(size_t)d*192+lane*3+1];
    float dm2=a*df1[(size_t)d*192+lane*3+2];
    float sw1o=SC[(size_t)el*352+256+lane];
    float g1=g[el*224+128+lane];
    float c0v=dm0*sw1o, c1v=dm1*sw1o, c2v=dm2*sw1o;
    c0v=wred64(c0v); c1v=wred64(c1v); c2v=wred64(c2v);
    if (lane==0){ DSH1[e*3+0]+=c0v; DSH1[e*3+1]+=c1v; DSH1[e*3+2]+=c2v; }
    float sh0=SQ3F*U[e*3+0], sh1=SQ3F*U[e*3+1], sh2=SQ3F*U[e*3+2];
    SC[(size_t)el*352+256+lane]=dm0*sh0+dm1*sh1+dm2*sh2;
    float sv0o=SV1[el*192+lane*3+0], sv1o=SV1[el*192+lane*3+1], sv2o=SV1[el*192+lane*3+2];
    DG[el*224+128+lane]=dm0*sv0o+dm1*sv1o+dm2*sv2o;
    SV1[el*192+lane*3+0]=dm0*g1; SV1[el*192+lane*3+1]=dm1*g1; SV1[el*192+lane*3+2]=dm2*g1;
  }
  {
    float dm[5]={0,0,0,0,0}, svo[5]={0,0,0,0,0};
    float sw2o=0.0f, g2=0.0f;
    if (lane<32){
      #pragma unroll
      for (int x=0;x<5;x++){ dm[x]=a*df2[(size_t)d*160+lane*5+x]; svo[x]=SV2[el*160+lane*5+x]; }
      sw2o=SC[(size_t)el*352+320+lane]; g2=g[el*224+192+lane];
    }
    float c[5];
    #pragma unroll
    for (int x=0;x<5;x++){ c[x]=dm[x]*sw2o; c[x]=wred64(c[x]); }
    if (lane==0){
      #pragma unroll
      for (int x=0;x<5;x++) DSH2[e*5+x]+=c[x];
    }
    if (lane<32){
      float dsw=0.0f, dg2=0.0f;
      #pragma unroll
      for (int x=0;x<5;x++){ dsw+=dm[x]*SH2b[e*5+x]; dg2+=dm[x]*svo[x]; }
      SC[(size_t)el*352+320+lane]=dsw;
      DG[el*224+192+lane]=dg2;
      #pragma unroll
      for (int x=0;x<5;x++) SV2[el*160+lane*5+x]=dm[x]*g2;
    }
  }
}

template<int CD,int X>
__global__ void k_gatefwd(float* __restrict__ f, const float* __restrict__ V, const float* __restrict__ P){
  int t=blockIdx.x*256+threadIdx.x;
  const int ox=CD*X;
  if (t>=NN*ox) return;
  int n=t/ox, rem=t-n*ox, d=rem/X;
  f[t] += V[t]*P[n*CD+d];
}

template<int CD,int X>
__global__ void k_gateback(const float* __restrict__ dfB, float* __restrict__ V,
                           const float* __restrict__ P, float* __restrict__ DPa){
  int t=blockIdx.x*256+threadIdx.x;
  if (t>=NN*CD) return;
  float p=P[t];
  float dp=0.0f;
  #pragma unroll
  for (int x=0;x<X;x++){ dp += dfB[t*X+x]*V[t*X+x]; }
  #pragma unroll
  for (int x=0;x<X;x++){ V[t*X+x] = dfB[t*X+x]*p; }
  DPa[t] = dp*p*(1.0f-p);
}

__global__ __launch_bounds__(256) void k_dr(const float* __restrict__ DRBF, const float* __restrict__ Rr,
    const float* __restrict__ cen, const float* __restrict__ wid, float* __restrict__ DRa, int c0, int cnt){
  int w=threadIdx.x>>6, lane=threadIdx.x&63;
  int el=blockIdx.x*4+w;
  if (el>=cnt) return;
  int e=c0+el;
  float r=Rr[e], s=0.0f;
  for (int k=lane;k<128;k+=64){
    float c=cen[k], wd=wid[k];
    float t=(r-c)/wd;
    float rb=expf(-0.5f*t*t);
    s += DRBF[el*128+k]*rb*((c-r)/(wd*wd));
  }
  s=wred64(s);
  if (lane==0) DRa[e]+=s;
}

__global__ __launch_bounds__(256) void k_initback(
  const float* __restrict__ df0,const float* __restrict__ df1,const float* __restrict__ df2,
  const int* __restrict__ dst,
  const float* __restrict__ g,const float* __restrict__ U,const float* __restrict__ SH2b,
  float* __restrict__ DG,float* __restrict__ DSH1,float* __restrict__ DSH2, int c0, int cnt)
{
  int w=threadIdx.x>>6, lane=threadIdx.x&63;
  int el=blockIdx.x*4+w;
  if (el>=cnt) return;
  int e=c0+el;
  int d=dst[e];
  const float inv=1.0f/sqrtf(15.57f);
  for (int j=lane;j<128;j+=64) DG[el*224+j]=inv*df0[d*128+j];
  float sh0=SQ3F*U[e*3+0], sh1=SQ3F*U[e*3+1], sh2=SQ3F*U[e*3+2];
  float df10=df1[d*192+lane*3+0], df11=df1[d*192+lane*3+1], df12=df1[d*192+lane*3+2];
  float g1=g[el*224+128+lane];
  DG[el*224+128+lane]=inv*(df10*sh0+df11*sh1+df12*sh2);
  float c0v=g1*df10, c1v=g1*df11, c2v=g1*df12;
  c0v=wred64(c0v); c1v=wred64(c1v); c2v=wred64(c2v);
  if (lane==0){ DSH1[e*3+0]+=inv*c0v; DSH1[e*3+1]+=inv*c1v; DSH1[e*3+2]+=inv*c2v; }
  float cc[5]={0,0,0,0,0};
  if (lane<32){
    float g2=g[el*224+192+lane];
    float dgv=0.0f;
    #pragma unroll
    for (int x=0;x<5;x++){ float dfv=df2[d*160+lane*5+x]; dgv+=dfv*SH2b[e*5+x]; cc[x]=g2*dfv; }
    DG[el*224+192+lane]=inv*dgv;
  }
  #pragma unroll
  for (int x=0;x<5;x++) cc[x]=wred64(cc[x]);
  if (lane==0){
    #pragma unroll
    for (int x=0;x<5;x++) DSH2[e*5+x]+=inv*cc[x];
  }
}

__global__ void k_geoback(const float* __restrict__ DRa, const float* __restrict__ DSH1, const float* __restrict__ DSH2,
                          const float* __restrict__ U, const float* __restrict__ Rr,
                          const int* __restrict__ src, const int* __restrict__ dst,
                          float* __restrict__ DPOS){
  int e=blockIdx.x*256+threadIdx.x;
  if (e>=NE) return;
  float ux=U[e*3+0], uy=U[e*3+1], uz=U[e*3+2];
  float r=Rr[e];
  float dux=SQ3F*DSH1[e*3+0], duy=SQ3F*DSH1[e*3+1], duz=SQ3F*DSH1[e*3+2];
  float d0=DSH2[e*5+0],d1=DSH2[e*5+1],d2=DSH2[e*5+2],d3=DSH2[e*5+3],d4=DSH2[e*5+4];
  dux += SQ15F*(uy*d0+uz*d3+ux*d4);
  duy += SQ15F*(ux*d0+uz*d1-uy*d4);
  duz += SQ15F*(uy*d1+ux*d3)+3.0f*SQ5F*uz*d2;
  float dr=DRa[e];
  float dot=dux*ux+duy*uy+duz*uz;
  float dvx=(dux-dot*ux)/r+dr*ux;
  float dvy=(duy-dot*uy)/r+dr*uy;
  float dvz=(duz-dot*uz)/r+dr*uz;
  int s=src[e], d=dst[e];
  atomicAdd(&DPOS[s*3+0],dvx); atomicAdd(&DPOS[s*3+1],dvy); atomicAdd(&DPOS[s*3+2],dvz);
  atomicAdd(&DPOS[d*3+0],-dvx); atomicAdd(&DPOS[d*3+1],-dvy); atomicAdd(&DPOS[d*3+2],-dvz);
}

__global__ void k_forces(const float* __restrict__ DPOS, float* __restrict__ o){
  int i=blockIdx.x*256+threadIdx.x;
  if (i<NN*3) o[i]=-DPOS[i];
}

// per-node LN + head forward + backward seeds; single wave per node
__global__ __launch_bounds__(64) void k_lnhead(
  const float* __restrict__ f0,const float* __restrict__ f1,const float* __restrict__ f2,
  const float* __restrict__ lng,const float* __restrict__ lnb,
  const float* __restrict__ W0,const float* __restrict__ hout,
  float* __restrict__ EN, float* __restrict__ df0,float* __restrict__ df1,float* __restrict__ df2)
{
  __shared__ float xh[480];
  __shared__ float fl[128];
  __shared__ float dyv[128];
  __shared__ float dxh[128];
  int n=blockIdx.x, lane=threadIdx.x;
  const float c0=1.0f/sqrtf(18.03f);
  for (int i=lane;i<480;i+=64){
    float v=(i<128)? f0[n*128+i] : (i<320)? f1[n*192+(i-128)] : f2[n*160+(i-320)];
    xh[i]=v;
  }
  __syncthreads();
  float s1=0.0f,s2=0.0f;
  for (int i=lane;i<480;i+=64){ float v=xh[i]; s1+=v; s2+=v*v; }
  s1=wred64(s1); s2=wred64(s2);
  float mu=__shfl(s1,0,64)*(1.0f/480.0f);
  float var=__shfl(s2,0,64)*(1.0f/480.0f)-mu*mu;
  float rstd=rsqrtf(var+1e-5f);
  for (int i=lane;i<480;i+=64) xh[i]=(xh[i]-mu)*rstd;
  __syncthreads();
  for (int k=lane;k<128;k+=64) fl[k]=xh[k]*lng[k]+lnb[k];
  __syncthreads();
  float y0=0.0f,y1=0.0f;
  for (int k=0;k<128;k++){ float f=fl[k]; y0+=f*W0[k*128+lane]; y1+=f*W0[k*128+lane+64]; }
  float e = siluf(y0)*hout[lane] + siluf(y1)*hout[lane+64];
  e=wred64(e);
  if (lane==0) EN[n]=e*c0;
  dyv[lane]=c0*hout[lane]*dsiluf(y0);
  dyv[lane+64]=c0*hout[lane+64]*dsiluf(y1);
  __syncthreads();
  float d0=0.0f,d1=0.0f;
  for (int j=0;j<128;j++){ float dv=dyv[j]; d0+=dv*W0[lane*128+j]; d1+=dv*W0[(lane+64)*128+j]; }
  dxh[lane]=d0*lng[lane];
  dxh[lane+64]=d1*lng[lane+64];
  __syncthreads();
  float s3=dxh[lane]+dxh[lane+64];
  float s4=dxh[lane]*xh[lane]+dxh[lane+64]*xh[lane+64];
  s3=wred64(s3); s4=wred64(s4);
  float m1=__shfl(s3,0,64)*(1.0f/480.0f);
  float m2=__shfl(s4,0,64)*(1.0f/480.0f);
  for (int i=lane;i<480;i+=64){
    float dv=rstd*(((i<128)?dxh[i]:0.0f)-m1-xh[i]*m2);
    if (i<128) df0[n*128+i]=dv;
    else if (i<320) df1[n*192+(i-128)]=dv;
    else df2[n*160+(i-320)]=dv;
  }
}

__global__ void k_esum(const float* __restrict__ EN, float* __restrict__ out){
  int b=blockIdx.x*64+threadIdx.x;
  if (b<NG){
    float s=0.0f;
    for (int k=0;k<16;k++) s+=EN[b*16+k];
    out[b]=s;
  }
}

#define MG(MT,TB,ACC,ACT,GA,SP,AR,DM,PO, A,IDX,B,C,M,Nd,K, CEN,WID,DMp,POp) \
  k_mgemm<MT,TB,ACC,ACT,GA,SP,AR,DM,PO><<<dim3((unsigned)(((M)+(MT)-1)/(MT)),(unsigned)(((Nd)+63)/64)),dim3(256),0,stream>>>((A),(IDX),(B),(C),(M),(Nd),(K),(CEN),(WID),(DMp),(POp))
#define MGEMM(TB,ACC,ACT,GA, A,IDX,B,C,M,Nd,K) MG(16,TB,ACC,ACT,GA,false,false,false,false, A,IDX,B,C,M,Nd,K, nullptr,nullptr,nullptr,nullptr)
#define MGEMM3(TB,ACC,ACT,GA, A,IDX,B,C,M,Nd,K) MG(16,TB,ACC,ACT,GA,true,false,false,false, A,IDX,B,C,M,Nd,K, nullptr,nullptr,nullptr,nullptr)
#define MEINS(CI,CO,X,TB,ACC,GA, A,IDX,Wt,C,M) \
  k_meinsum<CI,CO,X,TB,ACC,GA,false><<<dim3((unsigned)(((M)*(X)+63)/64)),dim3(256),0,stream>>>((A),(IDX),(Wt),(C),(M))
#define MEINS3(CI,CO,X,TB,ACC,GA, A,IDX,Wt,C,M) \
  k_meinsum<CI,CO,X,TB,ACC,GA,true><<<dim3((unsigned)(((M)*(X)+63)/64)),dim3(256),0,stream>>>((A),(IDX),(Wt),(C),(M))
#define G256(n) dim3((unsigned)(((n)+255)/256)),dim3(256),0,stream
#define GW4(n) dim3((unsigned)(((n)+3)/4)),dim3(256),0,stream

extern "C" void kernel_launch(void* const* d_in, const int* in_sizes, int n_in,
                              void* d_out, int out_size, void* d_ws, size_t ws_size,
                              hipStream_t stream)
{
  const float* pos =(const float*)d_in[0];
  const float* atab=(const float*)d_in[1];
  const float* rbfc=(const float*)d_in[2];
  const float* rbfw=(const float*)d_in[3];
  const float* degW1=(const float*)d_in[4];
  const float* degW2=(const float*)d_in[5];
  const float* degW3=(const float*)d_in[6];
  const float* Wv0=(const float*)d_in[7];
  const float* Wv1=(const float*)d_in[8];
  const float* Wv2=(const float*)d_in[9];
  const float* Ws0=(const float*)d_in[10];
  const float* Ws1=(const float*)d_in[11];
  const float* Ws2=(const float*)d_in[12];
  const float* rW1=(const float*)d_in[13];
  const float* rW2=(const float*)d_in[14];
  const float* rW3=(const float*)d_in[15];
  const float* WaS=(const float*)d_in[16];
  const float* WaD=(const float*)d_in[17];
  const float* WaE=(const float*)d_in[18];
  const float* wab=(const float*)d_in[19];
  const float* ff1=(const float*)d_in[20];
  const float* ff2=(const float*)d_in[21];
  const float* fg1=(const float*)d_in[22];
  const float* fg2=(const float*)d_in[23];
  const float* fW1=(const float*)d_in[24];
  const float* fW2=(const float*)d_in[25];
  const float* lng=(const float*)d_in[26];
  const float* lnb=(const float*)d_in[27];
  const float* W0h=(const float*)d_in[28];
  const float* hout=(const float*)d_in[29];
  const int* natom=(const int*)d_in[30];
  const int* esrc=(const int*)d_in[31];
  const int* edst=(const int*)d_in[32];

  float* Wp=(float*)d_ws;
  size_t off=0;
  auto al=[&](size_t n)->float*{ float* q=Wp+off; off+=n; return q; };

  const size_t SLOT = (size_t)NN*480;
  unsigned short* CKB = (unsigned short*)al((9*SLOT+1)/2);
  float* FA0=al((size_t)NN*128); float* FA1=al((size_t)NN*192); float* FA2=al((size_t)NN*160);
  float* FB0=al((size_t)NN*128); float* FB1=al((size_t)NN*192); float* FB2=al((size_t)NN*160);
  float* DI0=al((size_t)NN*128); float* DI1=al((size_t)NN*192); float* DI2=al((size_t)NN*160);
  float* DY0=al((size_t)NN*128); float* DY1=al((size_t)NN*192); float* DY2=al((size_t)NN*160);
  float* U=al((size_t)NE*3); float* Rr=al(NE); float* SH2b=al((size_t)NE*5);
  float* ABLK=al(8ULL*NE); float* LAM=al(NE);
  float* SSUM=al(NN); float* ENODE=al(NN); float* SACC=al(NN);
  float* DRr=al(NE); float* DSH1=al((size_t)NE*3); float* DSH2=al((size_t)NE*5);
  float* DPOS=al((size_t)NN*3);
  float* WCATF=al(8ULL*128*352);
  int* ROWS =(int*)al(NN+1);
  int* CNT  =(int*)al(NN);
  int* POSB =(int*)al(NN);
  int* PERMB=(int*)al(NE);
  int* ESRC2=(int*)al(NE);
  int* EDST2=(int*)al(NE);

  // ---- UNION region: per-phase chunk layouts + node-phase buffers (all time-disjoint) ----
  const size_t UNI = 28288000;
  float* UN = al(UNI);
  float* TBc=UN;
  float* DTc=TBc+(size_t)NNC*512;
  float* P1 =DTc+(size_t)NNC*512;
  float* P2 =P1 +(size_t)NN*64;
  float* V1 =P2 +(size_t)NN*32;
  float* V2 =V1 +(size_t)NN*192;
  float* DPb=V2 +(size_t)NN*160;
  float* F0N=DPb+(size_t)NN*64;

  float* outE=(float*)d_out;
  float* outF=outE+NG;

  if (off*sizeof(float) > ws_size){
    k_sentinel<<<G256(out_size)>>>(outE, out_size, (float)ws_size);
    return;
  }

  // ---------------- sort edges by dst ----------------
  (void)hipMemsetAsync(CNT,0,NN*sizeof(int),stream);
  k_hist<<<G256(NE)>>>(edst,CNT,NE);
  k_scan0<<<dim3(1),dim3(64),0,stream>>>(CNT,ROWS);
  (void)hipMemcpyAsync(POSB,ROWS,NN*sizeof(int),hipMemcpyDeviceToDevice,stream);
  k_fillperm<<<G256(NE)>>>(edst,POSB,PERMB,NE);
  k_mkedge<<<G256(NE)>>>(PERMB,esrc,edst,ESRC2,EDST2);
  k_wcat<<<G256(8*128*352)>>>(Wv0,Ws0,Ws1,Ws2,WCATF);

  // ---------------- setup ----------------
  k_geom<<<G256(NE)>>>(pos,ESRC2,EDST2,U,Rr,SH2b);
  k_f0init<<<G256(NN*128)>>>(natom,atab,FA0);
  (void)hipMemsetAsync(FA1,0,(size_t)NN*192*4,stream);
  (void)hipMemsetAsync(FA2,0,(size_t)NN*160*4,stream);
  (void)hipMemsetAsync(DRr,0,(size_t)NE*4,stream);
  (void)hipMemsetAsync(DSH1,0,(size_t)NE*3*4,stream);
  (void)hipMemsetAsync(DSH2,0,(size_t)NE*5*4,stream);
  (void)hipMemsetAsync(DPOS,0,(size_t)NN*3*4,stream);

  // degree embedding (CHIF chunks) -> FA  [split-bf16 + fused RBF]
  {
    float* H1=UN; float* H2=H1+(size_t)CHIF*64; float* Gc=H2+(size_t)CHIF*64;
    for (int cc=0;cc<NIF;cc++){
      int c0e=cc*CHIF, cnt=(c0e+CHIF<=NE)?CHIF:(NE-c0e);
      MG(16,false,false,1,false, true,true,false,false, Rr+c0e,nullptr,degW1,H1, cnt,64,128, rbfc,rbfw,nullptr,nullptr);
      MGEMM3(false,false,1,false, H1,nullptr,degW2,H2, cnt,64,64);
      MGEMM3(false,false,0,false, H2,nullptr,degW3,Gc, cnt,224,64);
      k_agg<true><<<dim3(NG),dim3(512),0,stream>>>(FA0,FA1,FA2,
        nullptr,nullptr,nullptr, Gc,U,SH2b, nullptr, EDST2,EDST2, nullptr, c0e,c0e+cnt);
    }
  }
  k_q3<<<G256(NN*480)>>>(FA0,FA1,FA2, CKB);

  float *c0_=FA0,*c1_=FA1,*c2_=FA2, *n0_=FB0,*n1_=FB1,*n2_=FB2;

  // ---------------- forward blocks [split-bf16], CHF chunks ----------------
  {
    float* H1  =UN;
    float* H2  =H1  +(size_t)CHF*64;
    float* Gc  =H2  +(size_t)CHF*64;
    float* SCAT=Gc  +(size_t)CHF*224;
    float* SV1 =SCAT+(size_t)CHF*352;
    float* SV2 =SV1 +(size_t)CHF*192;
    float* Zc  =SV2 +(size_t)CHF*160;
    for (int i=0;i<8;i++){
      const float* Wv1i=Wv1+(size_t)i*4096; const float* Wv2i=Wv2+(size_t)i*1024;
      const float* rW1i=rW1+(size_t)i*8192; const float* rW2i=rW2+(size_t)i*4096; const float* rW3i=rW3+(size_t)i*14336;
      const float* WaSi=WaS+(size_t)i*4096; const float* WaDi=WaD+(size_t)i*4096; const float* WaEi=WaE+(size_t)i*2048;
      const float* ff1i=ff1+(size_t)i*65536; const float* ff2i=ff2+(size_t)i*65536;
      const float* fg1i=fg1+(size_t)i*8192; const float* fg2i=fg2+(size_t)i*4096;
      const float* fW1i=fW1+(size_t)i*4096; const float* fW2i=fW2+(size_t)i*1024;
      const float* WCi=WCATF+(size_t)i*45056;
      float* AB=ABLK+(size_t)i*NE;

      (void)hipMemsetAsync(SACC,0,(size_t)NN*4,stream);
      (void)hipMemsetAsync(n0_,0,(size_t)NN*128*4,stream);
      (void)hipMemsetAsync(n1_,0,(size_t)NN*192*4,stream);
      (void)hipMemsetAsync(n2_,0,(size_t)NN*160*4,stream);
      for (int cc=0;cc<NF;cc++){
        int c0e=cc*CHF, cnt=(c0e+CHF<=NE)?CHF:(NE-c0e);
        MG(16,false,false,1,false, true,true,false,false, Rr+c0e,nullptr,rW1i,H1, cnt,64,128, rbfc,rbfw,nullptr,nullptr);
        MGEMM3(false,false,1,false, H1,nullptr,rW2i,H2, cnt,64,64);
        MGEMM3(false,false,0,false, H2,nullptr,rW3i,Gc, cnt,224,64);
        MGEMM3(false,false,0,true,  c0_,ESRC2+c0e,WaSi,Zc, cnt,32,128);
        MGEMM3(false,true, 0,true,  c0_,EDST2+c0e,WaDi,Zc, cnt,32,128);
        MGEMM3(false,true, 2,false, H2,nullptr,WaEi,Zc, cnt,32,64);
        k_lambda<<<G256(cnt)>>>(Zc, wab+(size_t)i*32, LAM+c0e, cnt);
        MGEMM3(false,false,0,true, c0_,ESRC2+c0e,WCi,SCAT, cnt,352,128);
        MEINS3(64,64,3,false,false,true, c1_,ESRC2+c0e,Wv1i,SV1, cnt);
        MEINS3(32,32,5,false,false,true, c2_,ESRC2+c0e,Wv2i,SV2, cnt);
        k_agg<false><<<dim3(NG),dim3(512),0,stream>>>(n0_,n1_,n2_,
          SCAT,SV1,SV2, Gc,U,SH2b, LAM, EDST2,EDST2, SACC, c0e,c0e+cnt);
      }
      k_norm<<<G256(NE)>>>(LAM,SACC,EDST2,AB);
      k_finy<<<G256(NN*480)>>>(c0_,c1_,c2_, n0_,n1_,n2_, SACC);
      k_q3<<<G256(NN*480)>>>(n0_,n1_,n2_, CKB+(size_t)(i+1)*SLOT);
      for (int nc=0;nc<NN/NNC;nc++){
        MGEMM3(false,false,1,false, n0_+(size_t)nc*NNC*128,nullptr,ff1i,TBc, NNC,512,128);
        MGEMM3(false,true, 0,false, TBc,nullptr,ff2i, n0_+(size_t)nc*NNC*128, NNC,128,512);
      }
      MGEMM3(false,false,3,false, n0_,nullptr,fg1i,P1, NN,64,128);
      MGEMM3(false,false,3,false, n0_,nullptr,fg2i,P2, NN,32,128);
      MEINS3(64,64,3,false,false,false, n1_,nullptr,fW1i,V1, NN);
      MEINS3(32,32,5,false,false,false, n2_,nullptr,fW2i,V2, NN);
      k_gatefwd<64,3><<<G256(NN*192)>>>(n1_,V1,P1);
      k_gatefwd<32,5><<<G256(NN*160)>>>(n2_,V2,P2);
      float* t;
      t=c0_;c0_=n0_;n0_=t; t=c1_;c1_=n1_;n1_=t; t=c2_;c2_=n2_;n2_=t;
    }
  }

  // ---------------- head ----------------
  k_lnhead<<<dim3(NN),dim3(64),0,stream>>>(c0_,c1_,c2_, lng,lnb,W0h,hout, ENODE, DI0,DI1,DI2);
  k_esum<<<dim3(8),dim3(64),0,stream>>>(ENODE,outE);

  // ---------------- backward blocks [plain bf16 MFMA, fused epilogues], CHB chunks ----------------
  {
    float* PRE1=UN;
    float* PRE2=PRE1+(size_t)CHB*64;
    float* H1  =PRE2+(size_t)CHB*64;
    float* H2  =H1  +(size_t)CHB*64;
    float* Gc  =H2  +(size_t)CHB*64;
    float* DGc =Gc  +(size_t)CHB*224;
    float* SCAT=DGc +(size_t)CHB*224;
    float* SV1 =SCAT+(size_t)CHB*352;
    float* SV2 =SV1 +(size_t)CHB*192;
    float* Zc  =SV2 +(size_t)CHB*160;
    float* DE0 =Zc  +(size_t)CHB*32;
    float* RBFc=SCAT;
    float* DZD =Gc;
    for (int i=7;i>=0;--i){
      const float* Wv1i=Wv1+(size_t)i*4096; const float* Wv2i=Wv2+(size_t)i*1024;
      const float* rW1i=rW1+(size_t)i*8192; const float* rW2i=rW2+(size_t)i*4096; const float* rW3i=rW3+(size_t)i*14336;
      const float* WaSi=WaS+(size_t)i*4096; const float* WaDi=WaD+(size_t)i*4096; const float* WaEi=WaE+(size_t)i*2048;
      const float* ff1i=ff1+(size_t)i*65536; const float* ff2i=ff2+(size_t)i*65536;
      const float* fg1i=fg1+(size_t)i*8192; const float* fg2i=fg2+(size_t)i*4096;
      const float* fW1i=fW1+(size_t)i*4096; const float* fW2i=fW2+(size_t)i*1024;
      const float* WCi=WCATF+(size_t)i*45056;
      const float* AB=ABLK+(size_t)i*NE;

      k_dq3<<<G256(NN*480)>>>(CKB+(size_t)i*SLOT, FA0,FA1,FA2);
      if (i>0){
        const float* pf1=ff1+(size_t)(i-1)*65536; const float* pf2=ff2+(size_t)(i-1)*65536;
        const float* pg1=fg1+(size_t)(i-1)*8192; const float* pg2=fg2+(size_t)(i-1)*4096;
        const float* pW1=fW1+(size_t)(i-1)*4096; const float* pW2=fW2+(size_t)(i-1)*1024;
        for (int nc=0;nc<NN/NNC;nc++){
          MGEMM(false,false,1,false, FA0+(size_t)nc*NNC*128,nullptr,pf1,TBc, NNC,512,128);
          MGEMM(false,true, 0,false, TBc,nullptr,pf2, FA0+(size_t)nc*NNC*128, NNC,128,512);
        }
        MGEMM(false,false,3,false, FA0,nullptr,pg1,P1, NN,64,128);
        MGEMM(false,false,3,false, FA0,nullptr,pg2,P2, NN,32,128);
        MEINS(64,64,3,false,false,false, FA1,nullptr,pW1,V1, NN);
        MEINS(32,32,5,false,false,false, FA2,nullptr,pW2,V2, NN);
        k_gatefwd<64,3><<<G256(NN*192)>>>(FA1,V1,P1);
        k_gatefwd<32,5><<<G256(NN*160)>>>(FA2,V2,P2);
      }
      k_dq3<<<G256(NN*480)>>>(CKB+(size_t)(i+1)*SLOT, FB0,FB1,FB2);
      (void)hipMemcpyAsync(F0N,FB0,(size_t)NN*128*4,hipMemcpyDeviceToDevice,stream);
      for (int nc=0;nc<NN/NNC;nc++){
        MGEMM(false,false,1,false, FB0+(size_t)nc*NNC*128,nullptr,ff1i,TBc, NNC,512,128);
        MGEMM(false,true, 0,false, TBc,nullptr,ff2i, F0N+(size_t)nc*NNC*128, NNC,128,512);
      }
      MGEMM(false,false,3,false, F0N,nullptr,fg1i,P1, NN,64,128);
      MGEMM(false,false,3,false, F0N,nullptr,fg2i,P2, NN,32,128);
      MEINS(64,64,3,false,false,false, FB1,nullptr,fW1i,V1, NN);
      MEINS(32,32,5,false,false,false, FB2,nullptr,fW2i,V2, NN);
      k_gateback<64,3><<<G256(NN*64)>>>(DI1,V1,P1,DPb);
      MGEMM(true,true,0,false, DPb,nullptr,fg1i,DI0, NN,128,64);
      (void)hipMemcpyAsync(DY1,DI1,(size_t)NN*192*4,hipMemcpyDeviceToDevice,stream);
      MEINS(64,64,3,true,true,false, V1,nullptr,fW1i,DY1, NN);
      k_gateback<32,5><<<G256(NN*32)>>>(DI2,V2,P2,DPb);
      MGEMM(true,true,0,false, DPb,nullptr,fg2i,DI0, NN,128,32);
      (void)hipMemcpyAsync(DY2,DI2,(size_t)NN*160*4,hipMemcpyDeviceToDevice,stream);
      MEINS(32,32,5,true,true,false, V2,nullptr,fW2i,DY2, NN);
      (void)hipMemcpyAsync(DY0,DI0,(size_t)NN*128*4,hipMemcpyDeviceToDevice,stream);
      for (int nc=0;nc<NN/NNC;nc++){
        MGEMM(false,false,0,false, FB0+(size_t)nc*NNC*128,nullptr,ff1i,TBc, NNC,512,128);
        MG(16,true,false,0,false, false,false,true,false, DI0+(size_t)nc*NNC*128,nullptr,ff2i,DTc, NNC,512,128, nullptr,nullptr,TBc,nullptr);
        MGEMM(true,true,0,false, DTc,nullptr,ff1i, DY0+(size_t)nc*NNC*128, NNC,128,512);
      }
      k_ssum<<<dim3(NN/4),dim3(256),0,stream>>>(FA0,FA1,FA2,FB0,FB1,FB2,DY0,DY1,DY2,SSUM);
      (void)hipMemcpyAsync(DI0,DY0,(size_t)NN*128*4,hipMemcpyDeviceToDevice,stream);
      (void)hipMemcpyAsync(DI1,DY1,(size_t)NN*192*4,hipMemcpyDeviceToDevice,stream);
      (void)hipMemcpyAsync(DI2,DY2,(size_t)NN*160*4,hipMemcpyDeviceToDevice,stream);
      for (int cc=0;cc<NB;cc++){
        int c0e=cc*CHB, cnt=(c0e+CHB<=NE)?CHB:(NE-c0e);
        MG(16,false,false,1,false, false,true,false,true, Rr+c0e,nullptr,rW1i,H1, cnt,64,128, rbfc,rbfw,nullptr,PRE1);
        MG(16,false,false,1,false, false,false,false,true, H1,nullptr,rW2i,H2, cnt,64,64, nullptr,nullptr,nullptr,PRE2);
        MGEMM(false,false,0,false, H2,nullptr,rW3i,Gc, cnt,224,64);
        MGEMM(false,false,0,true,  FA0,ESRC2+c0e,WaSi,Zc, cnt,32,128);
        MGEMM(false,true, 0,true,  FA0,EDST2+c0e,WaDi,Zc, cnt,32,128);
        MGEMM(false,true, 2,false, H2,nullptr,WaEi,Zc, cnt,32,64);
        MGEMM(false,false,0,true, FA0,ESRC2+c0e,WCi,SCAT, cnt,352,128);
        MEINS(64,64,3,false,false,true, FA1,ESRC2+c0e,Wv1i,SV1, cnt);
        MEINS(32,32,5,false,false,true, FA2,ESRC2+c0e,Wv2i,SV2, cnt);
        k_bedge<<<GW4(cnt)>>>(SCAT,SV1,SV2, Gc,U,SH2b, DY0,DY1,DY2, EDST2, SSUM,
                              wab+(size_t)i*32, Zc, AB, DGc, DSH1, DSH2, c0e, cnt);
        MGEMM(true,false,0,false, SCAT,nullptr,WCi,DE0, cnt,128,352);
        MGEMM(true,true, 0,false, Zc,nullptr,WaSi,DE0, cnt,128,32);
        MGEMM(true,false,0,false, Zc,nullptr,WaDi,DZD, cnt,128,32);
        MEINS(64,64,3,true,false,false, SV1,nullptr,Wv1i,SV1, cnt);
        MEINS(32,32,5,true,false,false, SV2,nullptr,Wv2i,SV2, cnt);
        MGEMM(true,false,0,false, Zc,nullptr,WaEi,H2, cnt,64,32);
        MG(16,true,true,0,false, false,false,true,false, DGc,nullptr,rW3i,H2, cnt,64,224, nullptr,nullptr,PRE2,nullptr);
        MG(16,true,false,0,false, false,false,true,false, H2,nullptr,rW2i,H1, cnt,64,64, nullptr,nullptr,PRE1,nullptr);
        MGEMM(true,false,0,false, H1,nullptr,rW1i,RBFc, cnt,128,64);
        k_dr<<<GW4(cnt)>>>(RBFc,Rr,rbfc,rbfw,DRr, c0e,cnt);
        k_scat<<<dim3(NG),dim3(640),0,stream>>>(DI0,DI1,DI2, DE0,DZD,SV1,SV2, ESRC2,EDST2, c0e,c0e+cnt);
      }
    }
  }

  // ---------------- initial embedding backward [fused], CHIB chunks ----------------
  {
    float* PRE1=UN;
    float* PRE2=PRE1+(size_t)CHIB*64;
    float* H1  =PRE2+(size_t)CHIB*64;
    float* H2  =H1  +(size_t)CHIB*64;
    float* Gc  =H2  +(size_t)CHIB*64;
    float* DGc =Gc  +(size_t)CHIB*224;
    float* RBFc=DGc +(size_t)CHIB*224;
    for (int cc=0;cc<NIB;cc++){
      int c0e=cc*CHIB, cnt=(c0e+CHIB<=NE)?CHIB:(NE-c0e);
      MG(16,false,false,1,false, false,true,false,true, Rr+c0e,nullptr,degW1,H1, cnt,64,128, rbfc,rbfw,nullptr,PRE1);
      MG(16,false,false,1,false, false,false,false,true, H1,nullptr,degW2,H2, cnt,64,64, nullptr,nullptr,nullptr,PRE2);
      MGEMM(false,false,0,false, H2,nullptr,degW3,Gc, cnt,224,64);
      k_initback<<<GW4(cnt)>>>(DI0,DI1,DI2,EDST2,Gc,U,SH2b,DGc,DSH1,DSH2, c0e,cnt);
      MG(16,true,false,0,false, false,false,true,false, DGc,nullptr,degW3,H2, cnt,64,224, nullptr,nullptr,PRE2,nullptr);
      MG(16,true,false,0,false, false,false,true,false, H2,nullptr,degW2,H1, cnt,64,64, nullptr,nullptr,PRE1,nullptr);
      MGEMM(true,false,0,false, H1,nullptr,degW1,RBFc, cnt,128,64);
      k_dr<<<GW4(cnt)>>>(RBFc,Rr,rbfc,rbfw,DRr, c0e,cnt);
    }
  }

  // ---------------- geometry backward + outputs ----------------
  k_geoback<<<G256(NE)>>>(DRr,DSH1,DSH2,U,Rr,ESRC2,EDST2,DPOS);
  k_forces<<<G256(NN*3)>>>(DPOS,outF);
  (void)in_sizes; (void)n_in; (void)out_size;
}

// Round 21
// 34067.758 us; speedup vs baseline: 2.1081x; 1.1160x over previous
//
#include <hip/hip_runtime.h>
#include <string.h>
#include <math.h>

#define NE 100000
#define NN 8192
#define NG 512
#define CHF 25000
#define NF 4
#define CHB 20000
#define NB 5
#define CHIF 50000
#define NIF 2
#define CHIB 34000
#define NIB 3
#define NNC 8192

#define SQ3F  1.7320508075688772f
#define SQ5F  2.23606797749979f
#define SQ15F 3.872983346207417f

__constant__ int c_amap[10] = {-1,0,-1,-1,-1,-1,1,2,3,4};

typedef __attribute__((ext_vector_type(4))) float f32x4;
typedef __attribute__((ext_vector_type(8))) short bf16x8;

__device__ __forceinline__ float sigf(float x){ return 1.0f/(1.0f+expf(-x)); }
__device__ __forceinline__ float siluf(float x){ return x*sigf(x); }
__device__ __forceinline__ float dsiluf(float x){ float s=sigf(x); return s*(1.0f + x*(1.0f-s)); }

__device__ __forceinline__ float wred64(float v){
  #pragma unroll
  for (int o=32;o>0;o>>=1) v += __shfl_down(v,o,64);
  return v;
}
__device__ __forceinline__ int lbound(const int* a, int n, int v){
  int lo=0, hi=n;
  while (lo<hi){ int m=(lo+hi)>>1; if (a[m]<v) lo=m+1; else hi=m; }
  return lo;
}
__device__ __forceinline__ unsigned short f2b(float x){
  unsigned u=__float_as_uint(x);
  unsigned r=(u + 0x7fffu + ((u>>16)&1u))>>16;
  return (unsigned short)r;
}
__device__ __forceinline__ float b2f(unsigned short b){
  return __uint_as_float(((unsigned)b)<<16);
}

// ---------------- edge sort by dst (counting sort) ----------------
__global__ void k_hist(const int* keys, int* hist, int n){
  int i = blockIdx.x*256 + threadIdx.x;
  if (i < n) atomicAdd(&hist[keys[i]], 1);
}
__global__ void k_scan0(const int* hist, int* rows){
  if (threadIdx.x == 0 && blockIdx.x == 0){
    int acc = 0;
    for (int i = 0; i < NN; i++){ rows[i] = acc; acc += hist[i]; }
    rows[NN] = acc;
  }
}
__global__ void k_fillperm(const int* keys, int* cursor, int* perm, int n){
  int i = blockIdx.x*256 + threadIdx.x;
  if (i < n){
    int slot = atomicAdd(&cursor[keys[i]], 1);
    perm[slot] = i;
  }
}
__global__ void k_mkedge(const int* perm, const int* src, const int* dst, int* src2, int* dst2){
  int k = blockIdx.x*256 + threadIdx.x;
  if (k < NE){ int e = perm[k]; src2[k] = src[e]; dst2[k] = dst[e]; }
}

// weight concat: WCATF[i][k][0:352] = [Wv0 | Ws0 | Ws1 | Ws2]
__global__ void k_wcat(const float* Wv0,const float* Ws0,const float* Ws1,const float* Ws2, float* W){
  int t = blockIdx.x*256 + threadIdx.x;
  if (t >= 8*128*352) return;
  int i = t/45056, r = t - i*45056;
  int k = r/352, n = r - k*352;
  float v;
  if (n < 128) v = Wv0[(size_t)i*16384 + k*128 + n];
  else if (n < 256) v = Ws0[(size_t)i*16384 + k*128 + (n-128)];
  else if (n < 320) v = Ws1[(size_t)i*8192 + k*64 + (n-256)];
  else v = Ws2[(size_t)i*4096 + k*32 + (n-320)];
  W[t] = v;
}

// --- bf16 MFMA GEMM; MT = M-tile (64 or 16); SPLIT=3-term split-bf16; ARBF=A computed as RBF(Rr row);
//     DMUL=epilogue *dsilu(dm); PREOUT=write pre-activation to pre[] ---
template<int MT, bool TB, bool ACC, int ACT, bool GATHER, bool SPLIT, bool ARBF, bool DMUL, bool PREOUT>
__global__ __launch_bounds__(256) void k_mgemm(
    const float* __restrict__ A, const int* __restrict__ idx,
    const float* __restrict__ B, float* __restrict__ C,
    int M, int Nd, int K,
    const float* __restrict__ cen, const float* __restrict__ wid,
    const float* __restrict__ dm, float* __restrict__ pre)
{
  constexpr int TPR = 256/MT;     // threads per A-row
  constexpr int EPT = 32/TPR;     // elems per thread (A staging)
  constexpr int RT  = MT/16;      // MFMA row-tiles
  __shared__ unsigned short Asb[(SPLIT?2:1)*MT*40];
  __shared__ unsigned short Btb[(SPLIT?2:1)*2560];
  const int bm = blockIdx.x*MT, bn = blockIdx.y*64;
  const int tid = threadIdx.x;
  const int wave = tid>>6, lane = tid&63;
  const int arow_s = tid / TPR, aoff = (tid % TPR) * EPT;
  const int bsrow = tid>>2, bsoff = (tid&3)*8;
  f32x4 acc[RT];
  #pragma unroll
  for (int r=0;r<RT;r++) acc[r] = (f32x4){0.f,0.f,0.f,0.f};
  int arow = -1;
  {
    int gr = bm + arow_s;
    if (gr < M) arow = GATHER ? idx[gr] : gr;
  }
  int bcol = bn + bsrow;
  for (int k0=0;k0<K;k0+=32){
    #pragma unroll
    for (int i=0;i<EPT;i++){
      float v = 0.0f;
      if (arow>=0){
        if (ARBF){
          float r = A[arow];
          int kk = k0 + aoff + i;
          float t = (r - cen[kk]) / wid[kk];
          v = expf(-0.5f*t*t);
        } else {
          v = A[(size_t)arow*K + k0 + aoff + i];
        }
      }
      unsigned short h = f2b(v);
      Asb[arow_s*40 + aoff + i] = h;
      if (SPLIT) Asb[MT*40 + arow_s*40 + aoff + i] = f2b(v - b2f(h));
    }
    #pragma unroll
    for (int i=0;i<8;i++){
      float v = 0.0f;
      if (bcol < Nd) v = TB ? B[(size_t)bcol*K + k0 + bsoff + i] : B[(size_t)(k0+bsoff+i)*Nd + bcol];
      unsigned short h = f2b(v);
      Btb[bsrow*40 + bsoff + i] = h;
      if (SPLIT) Btb[2560 + bsrow*40 + bsoff + i] = f2b(v - b2f(h));
    }
    __syncthreads();
    int boff = (wave*16 + (lane&15))*40 + (lane>>4)*8;
    bf16x8 bh = *(const bf16x8*)&Btb[boff];
    #pragma unroll
    for (int r=0;r<RT;r++){
      int aoff2 = (r*16 + (lane&15))*40 + (lane>>4)*8;
      bf16x8 ah = *(const bf16x8*)&Asb[aoff2];
      acc[r] = __builtin_amdgcn_mfma_f32_16x16x32_bf16(ah, bh, acc[r], 0,0,0);
      if (SPLIT){
        bf16x8 bl = *(const bf16x8*)&Btb[2560 + boff];
        bf16x8 al = *(const bf16x8*)&Asb[MT*40 + aoff2];
        acc[r] = __builtin_amdgcn_mfma_f32_16x16x32_bf16(ah, bl, acc[r], 0,0,0);
        acc[r] = __builtin_amdgcn_mfma_f32_16x16x32_bf16(al, bh, acc[r], 0,0,0);
      }
    }
    __syncthreads();
  }
  int col = bn + wave*16 + (lane&15);
  if (col < Nd){
    #pragma unroll
    for (int r=0;r<RT;r++){
      #pragma unroll
      for (int v=0;v<4;v++){
        int row = bm + r*16 + (lane>>4)*4 + v;
        if (row >= M) continue;
        size_t o = (size_t)row*Nd + col;
        float x = acc[r][v];
        if (ACC) x += C[o];
        if (DMUL) x *= dsiluf(dm[o]);
        if (PREOUT) pre[o] = x;
        if (ACT == 1) x = siluf(x);
        else if (ACT == 2) x = tanhf(x);
        else if (ACT == 3) x = sigf(x);
        C[o] = x;
      }
    }
  }
}

// ---------- bf16 MFMA einsum (X-strided rows); SPLIT => split-bf16 ----------
template<int CI, int CO, int X, bool TB, bool ACC, bool GATHER, bool SPLIT>
__global__ __launch_bounds__(256) void k_meinsum(
    const float* __restrict__ A, const int* __restrict__ idx,
    const float* __restrict__ W, float* __restrict__ C, int M)
{
  __shared__ unsigned short Asb[(SPLIT?2:1)*2560];
  __shared__ unsigned short Btb[(SPLIT?2:1)*2560];
  const int bm = blockIdx.x*64;
  const int tid = threadIdx.x, wave = tid>>6, lane = tid&63;
  const int srow = tid>>2, soff = (tid&3)*8;
  f32x4 acc[4];
  #pragma unroll
  for (int r=0;r<4;r++) acc[r] = (f32x4){0.f,0.f,0.f,0.f};
  long abase = -1;
  {
    int grow = bm + srow;
    if (grow < M*X){
      int ge = grow / X, gx = grow - ge*X;
      int ar = GATHER ? idx[ge] : ge;
      abase = (long)ar*CI*X + gx;
    }
  }
  for (int k0=0;k0<CI;k0+=32){
    #pragma unroll
    for (int i=0;i<8;i++){
      float v = (abase>=0) ? A[abase + (size_t)(k0+soff+i)*X] : 0.0f;
      unsigned short h = f2b(v);
      Asb[srow*40 + soff + i] = h;
      if (SPLIT) Asb[2560 + srow*40 + soff + i] = f2b(v - b2f(h));
    }
    #pragma unroll
    for (int i=0;i<8;i++){
      int kk = k0 + soff + i;
      float v = 0.0f;
      if (srow < CO) v = TB ? W[srow*CI + kk] : W[kk*CO + srow];
      unsigned short h = f2b(v);
      Btb[srow*40 + soff + i] = h;
      if (SPLIT) Btb[2560 + srow*40 + soff + i] = f2b(v - b2f(h));
    }
    __syncthreads();
    int boff = (wave*16 + (lane&15))*40 + (lane>>4)*8;
    bf16x8 bh = *(const bf16x8*)&Btb[boff];
    #pragma unroll
    for (int r=0;r<4;r++){
      int aoff = (r*16 + (lane&15))*40 + (lane>>4)*8;
      bf16x8 ah = *(const bf16x8*)&Asb[aoff];
      acc[r] = __builtin_amdgcn_mfma_f32_16x16x32_bf16(ah, bh, acc[r], 0,0,0);
      if (SPLIT){
        bf16x8 bl = *(const bf16x8*)&Btb[2560 + boff];
        bf16x8 al = *(const bf16x8*)&Asb[2560 + aoff];
        acc[r] = __builtin_amdgcn_mfma_f32_16x16x32_bf16(ah, bl, acc[r], 0,0,0);
        acc[r] = __builtin_amdgcn_mfma_f32_16x16x32_bf16(al, bh, acc[r], 0,0,0);
      }
    }
    __syncthreads();
  }
  int col = wave*16 + (lane&15);
  if (col < CO){
    #pragma unroll
    for (int r=0;r<4;r++){
      #pragma unroll
      for (int v=0;v<4;v++){
        int row = bm + r*16 + (lane>>4)*4 + v;
        if (row >= M*X) continue;
        int ge = row / X, gx = row - ge*X;
        size_t o = (size_t)ge*CO*X + (size_t)col*X + gx;
        float xx = acc[r][v];
        if (ACC) xx += C[o];
        C[o] = xx;
      }
    }
  }
}

// ------------------------- small kernels -------------------------
__global__ void k_sentinel(float* o, int n, float v){
  int i = blockIdx.x*256 + threadIdx.x;
  if (i < n) o[i] = v;
}

__global__ void k_geom(const float* __restrict__ pos, const int* __restrict__ src, const int* __restrict__ dst,
                       float* __restrict__ U, float* __restrict__ Rr, float* __restrict__ SH2b){
  int e = blockIdx.x*256 + threadIdx.x;
  if (e >= NE) return;
  int s = src[e], d = dst[e];
  float vx = pos[s*3+0]-pos[d*3+0];
  float vy = pos[s*3+1]-pos[d*3+1];
  float vz = pos[s*3+2]-pos[d*3+2];
  float r = sqrtf(vx*vx+vy*vy+vz*vz + 1e-12f);
  float ux=vx/r, uy=vy/r, uz=vz/r;
  U[e*3+0]=ux; U[e*3+1]=uy; U[e*3+2]=uz;
  Rr[e]=r;
  SH2b[e*5+0]=SQ15F*ux*uy;
  SH2b[e*5+1]=SQ15F*uy*uz;
  SH2b[e*5+2]=0.5f*SQ5F*(3.0f*uz*uz-1.0f);
  SH2b[e*5+3]=SQ15F*ux*uz;
  SH2b[e*5+4]=0.5f*SQ15F*(ux*ux-uy*uy);
}

__global__ void k_f0init(const int* __restrict__ na, const float* __restrict__ at, float* __restrict__ f0){
  int t = blockIdx.x*256 + threadIdx.x;
  if (t >= NN*128) return;
  int n = t>>7, j = t&127;
  int m = c_amap[na[n]];
  f0[t] = at[m*128+j];
}

// lambda -> p = exp(lambda)
__global__ void k_lambda(const float* __restrict__ Z, const float* __restrict__ wa, float* __restrict__ P_c, int cnt){
  int e = blockIdx.x*256 + threadIdx.x;
  if (e >= cnt) return;
  float s = 0.0f;
  #pragma unroll
  for (int k=0;k<32;k++) s += Z[e*32+k]*wa[k];
  P_c[e] = expf(s);
}

__global__ void k_norm(const float* __restrict__ P, const float* __restrict__ S,
                       const int* __restrict__ dst, float* __restrict__ AB){
  int e = blockIdx.x*256 + threadIdx.x;
  if (e < NE) AB[e] = P[e]/(S[dst[e]]+1e-9f);
}

__global__ void k_finy(const float* __restrict__ x0,const float* __restrict__ x1,const float* __restrict__ x2,
                       float* __restrict__ y0,float* __restrict__ y1,float* __restrict__ y2,
                       const float* __restrict__ S){
  int t = blockIdx.x*256 + threadIdx.x;
  if (t >= NN*480) return;
  if (t < NN*128){ int n=t>>7; y0[t]=x0[t]+y0[t]/(S[n]+1e-9f); }
  else if (t < NN*320){ int q=t-NN*128; int n=q/192; y1[q]=x1[q]+y1[q]/(S[n]+1e-9f); }
  else { int q=t-NN*320; int n=q/160; y2[q]=x2[q]+y2[q]/(S[n]+1e-9f); }
}

// bf16 checkpoint quant/dequant
__global__ void k_q3(const float* __restrict__ f0,const float* __restrict__ f1,const float* __restrict__ f2,
                     unsigned short* __restrict__ ck){
  int t = blockIdx.x*256 + threadIdx.x;
  if (t >= NN*480) return;
  float v;
  if (t < NN*128) v = f0[t];
  else if (t < NN*320) v = f1[t-NN*128];
  else v = f2[t-NN*320];
  ck[t] = f2b(v);
}
__global__ void k_dq3(const unsigned short* __restrict__ ck,
                      float* __restrict__ f0,float* __restrict__ f1,float* __restrict__ f2){
  int t = blockIdx.x*256 + threadIdx.x;
  if (t >= NN*480) return;
  float v = b2f(ck[t]);
  if (t < NN*128) f0[t]=v;
  else if (t < NN*320) f1[t-NN*128]=v;
  else f2[t-NN*320]=v;
}

// per-graph aggregation; SC strided 352 [sv0|sw0|sw1|sw2]; accumulates S in lanes 480..495
template<bool INIT>
__global__ __launch_bounds__(512) void k_agg(
  float* __restrict__ f0o,float* __restrict__ f1o,float* __restrict__ f2o,
  const float* __restrict__ SC,const float* __restrict__ sv1,const float* __restrict__ sv2,
  const float* __restrict__ g,const float* __restrict__ U,const float* __restrict__ SH2b,
  const float* __restrict__ aArr,const int* __restrict__ keys,const int* __restrict__ dst,
  float* __restrict__ SACC, int c0, int c1)
{
  __shared__ float acc[7680];
  int b = blockIdx.x, lo = b<<4;
  int e0 = lbound(keys, NE, lo), e1 = lbound(keys, NE, lo+16);
  if (e0 < c0) e0 = c0;
  if (e1 > c1) e1 = c1;
  if (e0 >= e1) return;
  for (int i=threadIdx.x;i<7680;i+=512) acc[i]=0.0f;
  __syncthreads();
  const int j = threadIdx.x;
  const float inv = 1.0f/sqrtf(15.57f);
  int cat=3, cc_=0, xx_=0;
  if (j<128){ cat=0; }
  else if (j<320){ cat=1; int t=j-128; cc_=t/3; xx_=t-3*cc_; }
  else if (j<480){ cat=2; int t=j-320; cc_=t/5; xx_=t-5*cc_; }
  float sacc=0.0f;
  for (int e=e0; e<e1; ++e){
    int el = e - c0;
    float a = INIT ? inv : aArr[e];
    int nl = dst[e]&15;
    if (cat==0){
      float m = INIT ? g[el*224+j] : (SC[(size_t)el*352+j]*g[el*224+j] + SC[(size_t)el*352+128+j]);
      acc[nl*480+j] += a*m;
    } else if (cat==1){
      int t=j-128;
      float sh = SQ3F*U[e*3+xx_];
      float m = INIT ? g[el*224+128+cc_]*sh : (sv1[el*192+t]*g[el*224+128+cc_] + SC[(size_t)el*352+256+cc_]*sh);
      acc[nl*480+j] += a*m;
    } else if (cat==2){
      int t=j-320;
      float sh = SH2b[e*5+xx_];
      float m = INIT ? g[el*224+192+cc_]*sh : (sv2[el*160+t]*g[el*224+192+cc_] + SC[(size_t)el*352+320+cc_]*sh);
      acc[nl*480+j] += a*m;
    } else if (!INIT && j<496){
      if (nl==(j-480)) sacc += a;
    }
  }
  __syncthreads();
  for (int i=threadIdx.x;i<7680;i+=512){
    int nl=i/480, jj=i-480*nl, n=lo+nl;
    float v=acc[i];
    if (jj<128) f0o[n*128+jj]+=v;
    else if (jj<320) f1o[n*192+jj-128]+=v;
    else f2o[n*160+jj-320]+=v;
  }
  if (!INIT && j>=480 && j<496) SACC[lo+(j-480)] += sacc;
}

// per-graph scatter of edge grads
__global__ __launch_bounds__(640) void k_scat(
  float* __restrict__ df0, float* __restrict__ df1, float* __restrict__ df2,
  const float* __restrict__ DE0, const float* __restrict__ DZD,
  const float* __restrict__ DE1, const float* __restrict__ DE2,
  const int* __restrict__ src, const int* __restrict__ dst, int c0, int c1)
{
  __shared__ float acc[7680];
  int b=blockIdx.x, lo=b<<4;
  int e0=lbound(dst,NE,lo), e1=lbound(dst,NE,lo+16);
  if (e0 < c0) e0 = c0;
  if (e1 > c1) e1 = c1;
  for (int i=threadIdx.x;i<7680;i+=640) acc[i]=0.0f;
  __syncthreads();
  const int j=threadIdx.x;
  for (int e=e0;e<e1;++e){
    int el=e-c0;
    int sl=(src[e]&15)*480, dl=(dst[e]&15)*480;
    if (j<128) acc[sl+j] += DE0[el*128+j];
    else if (j<256){ int q=j-128; acc[dl+q] += DZD[el*128+q]; }
    else if (j<448){ int q=j-256; acc[sl+128+q] += DE1[el*192+q]; }
    else if (j<608){ int q=j-448; acc[sl+320+q] += DE2[el*160+q]; }
    __syncthreads();
  }
  for (int i=threadIdx.x;i<7680;i+=640){
    int nl=i/480, jj=i-480*nl, n=lo+nl;
    float v=acc[i];
    if (jj<128) df0[n*128+jj]+=v;
    else if (jj<320) df1[n*192+jj-128]+=v;
    else df2[n*160+jj-320]+=v;
  }
}

// SSUM[n] = (FB[n]-FA[n]) . DY[n]
__global__ __launch_bounds__(256) void k_ssum(
  const float* __restrict__ FA0,const float* __restrict__ FA1,const float* __restrict__ FA2,
  const float* __restrict__ FB0,const float* __restrict__ FB1,const float* __restrict__ FB2,
  const float* __restrict__ DY0,const float* __restrict__ DY1,const float* __restrict__ DY2,
  float* __restrict__ SSUM)
{
  int n=blockIdx.x*4+(threadIdx.x>>6), lane=threadIdx.x&63;
  if (n>=NN) return;
  float s=0.0f;
  for (int j=lane;j<480;j+=64){
    float d,g;
    if (j<128){ d=FB0[n*128+j]-FA0[n*128+j]; g=DY0[n*128+j]; }
    else if (j<320){ int q=j-128; d=FB1[n*192+q]-FA1[n*192+q]; g=DY1[n*192+q]; }
    else { int q=j-320; d=FB2[n*160+q]-FA2[n*160+q]; g=DY2[n*160+q]; }
    s += d*g;
  }
  s = wred64(s);
  if (lane==0) SSUM[n]=s;
}

// fused backward edge chain: da -> dlam -> dz -> split0/1/2 ; one wave per edge
__global__ __launch_bounds__(256) void k_bedge(
  float* __restrict__ SC, float* __restrict__ SV1, float* __restrict__ SV2,
  const float* __restrict__ g, const float* __restrict__ U, const float* __restrict__ SH2b,
  const float* __restrict__ df0,const float* __restrict__ df1,const float* __restrict__ df2,
  const int* __restrict__ dst, const float* __restrict__ SSUM, const float* __restrict__ wa,
  float* __restrict__ Z, const float* __restrict__ aArr,
  float* __restrict__ DG, float* __restrict__ DSH1, float* __restrict__ DSH2,
  int c0, int cnt)
{
  int w=threadIdx.x>>6, lane=threadIdx.x&63;
  int el=blockIdx.x*4+w;
  if (el>=cnt) return;
  int e=c0+el;
  int d=dst[e];
  float s=0.0f;
  for (int j=lane;j<480;j+=64){
    float m, dfv;
    if (j<128){
      m = SC[(size_t)el*352+j]*g[el*224+j] + SC[(size_t)el*352+128+j];
      dfv = df0[(size_t)d*128+j];
    } else if (j<320){
      int t=j-128, c=t/3, x=t-3*c;
      m = SV1[el*192+t]*g[el*224+128+c] + SC[(size_t)el*352+256+c]*(SQ3F*U[e*3+x]);
      dfv = df1[(size_t)d*192+t];
    } else {
      int t=j-320, c=t/5, x=t-5*c;
      m = SV2[el*160+t]*g[el*224+192+c] + SC[(size_t)el*352+320+c]*SH2b[e*5+x];
      dfv = df2[(size_t)d*160+t];
    }
    s += m*dfv;
  }
  s = wred64(s);
  s = __shfl(s,0,64);
  float a = aArr[e];
  float dlam = a*(s - SSUM[d]);
  if (lane<32){
    float z = Z[(size_t)el*32+lane];
    Z[(size_t)el*32+lane] = dlam*wa[lane]*(1.0f-z*z);
  }
  {
    float* row = SC + (size_t)el*352;
    for (int j=lane;j<128;j+=64){
      float dm = a*df0[(size_t)d*128+j];
      float sv = row[j];
      row[128+j] = dm;
      row[j] = dm*g[el*224+j];
      DG[el*224+j] = dm*sv;
    }
  }
  {
    float dm0=a*df1[(size_t)d*192+lane*3+0];
    float dm1=a*df1[(size_t)d*192+lane*3+1];
    float dm2=a*df1[(size_t)d*192+lane*3+2];
    float sw1o=SC[(size_t)el*352+256+lane];
    float g1=g[el*224+128+lane];
    float c0v=dm0*sw1o, c1v=dm1*sw1o, c2v=dm2*sw1o;
    c0v=wred64(c0v); c1v=wred64(c1v); c2v=wred64(c2v);
    if (lane==0){ DSH1[e*3+0]+=c0v; DSH1[e*3+1]+=c1v; DSH1[e*3+2]+=c2v; }
    float sh0=SQ3F*U[e*3+0], sh1=SQ3F*U[e*3+1], sh2=SQ3F*U[e*3+2];
    SC[(size_t)el*352+256+lane]=dm0*sh0+dm1*sh1+dm2*sh2;
    float sv0o=SV1[el*192+lane*3+0], sv1o=SV1[el*192+lane*3+1], sv2o=SV1[el*192+lane*3+2];
    DG[el*224+128+lane]=dm0*sv0o+dm1*sv1o+dm2*sv2o;
    SV1[el*192+lane*3+0]=dm0*g1; SV1[el*192+lane*3+1]=dm1*g1; SV1[el*192+lane*3+2]=dm2*g1;
  }
  {
    float dm[5]={0,0,0,0,0}, svo[5]={0,0,0,0,0};
    float sw2o=0.0f, g2=0.0f;
    if (lane<32){
      #pragma unroll
      for (int x=0;x<5;x++){ dm[x]=a*df2[(size_t)d*160+lane*5+x]; svo[x]=SV2[el*160+lane*5+x]; }
      sw2o=SC[(size_t)el*352+320+lane]; g2=g[el*224+192+lane];
    }
    float c[5];
    #pragma unroll
    for (int x=0;x<5;x++){ c[x]=dm[x]*sw2o; c[x]=wred64(c[x]); }
    if (lane==0){
      #pragma unroll
      for (int x=0;x<5;x++) DSH2[e*5+x]+=c[x];
    }
    if (lane<32){
      float dsw=0.0f, dg2=0.0f;
      #pragma unroll
      for (int x=0;x<5;x++){ dsw+=dm[x]*SH2b[e*5+x]; dg2+=dm[x]*svo[x]; }
      SC[(size_t)el*352+320+lane]=dsw;
      DG[el*224+192+lane]=dg2;
      #pragma unroll
      for (int x=0;x<5;x++) SV2[el*160+lane*5+x]=dm[x]*g2;
    }
  }
}

template<int CD,int X>
__global__ void k_gatefwd(float* __restrict__ f, const float* __restrict__ V, const float* __restrict__ P){
  int t=blockIdx.x*256+threadIdx.x;
  const int ox=CD*X;
  if (t>=NN*ox) return;
  int n=t/ox, rem=t-n*ox, d=rem/X;
  f[t] += V[t]*P[n*CD+d];
}

template<int CD,int X>
__global__ void k_gateback(const float* __restrict__ dfB, float* __restrict__ V,
                           const float* __restrict__ P, float* __restrict__ DPa){
  int t=blockIdx.x*256+threadIdx.x;
  if (t>=NN*CD) return;
  float p=P[t];
  float dp=0.0f;
  #pragma unroll
  for (int x=0;x<X;x++){ dp += dfB[t*X+x]*V[t*X+x]; }
  #pragma unroll
  for (int x=0;x<X;x++){ V[t*X+x] = dfB[t*X+x]*p; }
  DPa[t] = dp*p*(1.0f-p);
}

__global__ __launch_bounds__(256) void k_dr(const float* __restrict__ DRBF, const float* __restrict__ Rr,
    const float* __restrict__ cen, const float* __restrict__ wid, float* __restrict__ DRa, int c0, int cnt){
  int w=threadIdx.x>>6, lane=threadIdx.x&63;
  int el=blockIdx.x*4+w;
  if (el>=cnt) return;
  int e=c0+el;
  float r=Rr[e], s=0.0f;
  for (int k=lane;k<128;k+=64){
    float c=cen[k], wd=wid[k];
    float t=(r-c)/wd;
    float rb=expf(-0.5f*t*t);
    s += DRBF[el*128+k]*rb*((c-r)/(wd*wd));
  }
  s=wred64(s);
  if (lane==0) DRa[e]+=s;
}

__global__ __launch_bounds__(256) void k_initback(
  const float* __restrict__ df0,const float* __restrict__ df1,const float* __restrict__ df2,
  const int* __restrict__ dst,
  const float* __restrict__ g,const float* __restrict__ U,const float* __restrict__ SH2b,
  float* __restrict__ DG,float* __restrict__ DSH1,float* __restrict__ DSH2, int c0, int cnt)
{
  int w=threadIdx.x>>6, lane=threadIdx.x&63;
  int el=blockIdx.x*4+w;
  if (el>=cnt) return;
  int e=c0+el;
  int d=dst[e];
  const float inv=1.0f/sqrtf(15.57f);
  for (int j=lane;j<128;j+=64) DG[el*224+j]=inv*df0[d*128+j];
  float sh0=SQ3F*U[e*3+0], sh1=SQ3F*U[e*3+1], sh2=SQ3F*U[e*3+2];
  float df10=df1[d*192+lane*3+0], df11=df1[d*192+lane*3+1], df12=df1[d*192+lane*3+2];
  float g1=g[el*224+128+lane];
  DG[el*224+128+lane]=inv*(df10*sh0+df11*sh1+df12*sh2);
  float c0v=g1*df10, c1v=g1*df11, c2v=g1*df12;
  c0v=wred64(c0v); c1v=wred64(c1v); c2v=wred64(c2v);
  if (lane==0){ DSH1[e*3+0]+=inv*c0v; DSH1[e*3+1]+=inv*c1v; DSH1[e*3+2]+=inv*c2v; }
  float cc[5]={0,0,0,0,0};
  if (lane<32){
    float g2=g[el*224+192+lane];
    float dgv=0.0f;
    #pragma unroll
    for (int x=0;x<5;x++){ float dfv=df2[d*160+lane*5+x]; dgv+=dfv*SH2b[e*5+x]; cc[x]=g2*dfv; }
    DG[el*224+192+lane]=inv*dgv;
  }
  #pragma unroll
  for (int x=0;x<5;x++) cc[x]=wred64(cc[x]);
  if (lane==0){
    #pragma unroll
    for (int x=0;x<5;x++) DSH2[e*5+x]+=inv*cc[x];
  }
}

__global__ void k_geoback(const float* __restrict__ DRa, const float* __restrict__ DSH1, const float* __restrict__ DSH2,
                          const float* __restrict__ U, const float* __restrict__ Rr,
                          const int* __restrict__ src, const int* __restrict__ dst,
                          float* __restrict__ DPOS){
  int e=blockIdx.x*256+threadIdx.x;
  if (e>=NE) return;
  float ux=U[e*3+0], uy=U[e*3+1], uz=U[e*3+2];
  float r=Rr[e];
  float dux=SQ3F*DSH1[e*3+0], duy=SQ3F*DSH1[e*3+1], duz=SQ3F*DSH1[e*3+2];
  float d0=DSH2[e*5+0],d1=DSH2[e*5+1],d2=DSH2[e*5+2],d3=DSH2[e*5+3],d4=DSH2[e*5+4];
  dux += SQ15F*(uy*d0+uz*d3+ux*d4);
  duy += SQ15F*(ux*d0+uz*d1-uy*d4);
  duz += SQ15F*(uy*d1+ux*d3)+3.0f*SQ5F*uz*d2;
  float dr=DRa[e];
  float dot=dux*ux+duy*uy+duz*uz;
  float dvx=(dux-dot*ux)/r+dr*ux;
  float dvy=(duy-dot*uy)/r+dr*uy;
  float dvz=(duz-dot*uz)/r+dr*uz;
  int s=src[e], d=dst[e];
  atomicAdd(&DPOS[s*3+0],dvx); atomicAdd(&DPOS[s*3+1],dvy); atomicAdd(&DPOS[s*3+2],dvz);
  atomicAdd(&DPOS[d*3+0],-dvx); atomicAdd(&DPOS[d*3+1],-dvy); atomicAdd(&DPOS[d*3+2],-dvz);
}

__global__ void k_forces(const float* __restrict__ DPOS, float* __restrict__ o){
  int i=blockIdx.x*256+threadIdx.x;
  if (i<NN*3) o[i]=-DPOS[i];
}

// per-node LN + head forward + backward seeds; single wave per node
__global__ __launch_bounds__(64) void k_lnhead(
  const float* __restrict__ f0,const float* __restrict__ f1,const float* __restrict__ f2,
  const float* __restrict__ lng,const float* __restrict__ lnb,
  const float* __restrict__ W0,const float* __restrict__ hout,
  float* __restrict__ EN, float* __restrict__ df0,float* __restrict__ df1,float* __restrict__ df2)
{
  __shared__ float xh[480];
  __shared__ float fl[128];
  __shared__ float dyv[128];
  __shared__ float dxh[128];
  int n=blockIdx.x, lane=threadIdx.x;
  const float c0=1.0f/sqrtf(18.03f);
  for (int i=lane;i<480;i+=64){
    float v=(i<128)? f0[n*128+i] : (i<320)? f1[n*192+(i-128)] : f2[n*160+(i-320)];
    xh[i]=v;
  }
  __syncthreads();
  float s1=0.0f,s2=0.0f;
  for (int i=lane;i<480;i+=64){ float v=xh[i]; s1+=v; s2+=v*v; }
  s1=wred64(s1); s2=wred64(s2);
  float mu=__shfl(s1,0,64)*(1.0f/480.0f);
  float var=__shfl(s2,0,64)*(1.0f/480.0f)-mu*mu;
  float rstd=rsqrtf(var+1e-5f);
  for (int i=lane;i<480;i+=64) xh[i]=(xh[i]-mu)*rstd;
  __syncthreads();
  for (int k=lane;k<128;k+=64) fl[k]=xh[k]*lng[k]+lnb[k];
  __syncthreads();
  float y0=0.0f,y1=0.0f;
  for (int k=0;k<128;k++){ float f=fl[k]; y0+=f*W0[k*128+lane]; y1+=f*W0[k*128+lane+64]; }
  float e = siluf(y0)*hout[lane] + siluf(y1)*hout[lane+64];
  e=wred64(e);
  if (lane==0) EN[n]=e*c0;
  dyv[lane]=c0*hout[lane]*dsiluf(y0);
  dyv[lane+64]=c0*hout[lane+64]*dsiluf(y1);
  __syncthreads();
  float d0=0.0f,d1=0.0f;
  for (int j=0;j<128;j++){ float dv=dyv[j]; d0+=dv*W0[lane*128+j]; d1+=dv*W0[(lane+64)*128+j]; }
  dxh[lane]=d0*lng[lane];
  dxh[lane+64]=d1*lng[lane+64];
  __syncthreads();
  float s3=dxh[lane]+dxh[lane+64];
  float s4=dxh[lane]*xh[lane]+dxh[lane+64]*xh[lane+64];
  s3=wred64(s3); s4=wred64(s4);
  float m1=__shfl(s3,0,64)*(1.0f/480.0f);
  float m2=__shfl(s4,0,64)*(1.0f/480.0f);
  for (int i=lane;i<480;i+=64){
    float dv=rstd*(((i<128)?dxh[i]:0.0f)-m1-xh[i]*m2);
    if (i<128) df0[n*128+i]=dv;
    else if (i<320) df1[n*192+(i-128)]=dv;
    else df2[n*160+(i-320)]=dv;
  }
}

__global__ void k_esum(const float* __restrict__ EN, float* __restrict__ out){
  int b=blockIdx.x*64+threadIdx.x;
  if (b<NG){
    float s=0.0f;
    for (int k=0;k<16;k++) s+=EN[b*16+k];
    out[b]=s;
  }
}

#define MG(MT,TB,ACC,ACT,GA,SP,AR,DM,PO, A,IDX,B,C,M,Nd,K, CEN,WID,DMp,POp) \
  k_mgemm<MT,TB,ACC,ACT,GA,SP,AR,DM,PO><<<dim3((unsigned)(((M)+(MT)-1)/(MT)),(unsigned)(((Nd)+63)/64)),dim3(256),0,stream>>>((A),(IDX),(B),(C),(M),(Nd),(K),(CEN),(WID),(DMp),(POp))
#define MGEMM(TB,ACC,ACT,GA, A,IDX,B,C,M,Nd,K) MG(16,TB,ACC,ACT,GA,false,false,false,false, A,IDX,B,C,M,Nd,K, nullptr,nullptr,nullptr,nullptr)
#define MGEMM3(TB,ACC,ACT,GA, A,IDX,B,C,M,Nd,K) MG(16,TB,ACC,ACT,GA,true,false,false,false, A,IDX,B,C,M,Nd,K, nullptr,nullptr,nullptr,nullptr)
#define MEINS(CI,CO,X,TB,ACC,GA, A,IDX,Wt,C,M) \
  k_meinsum<CI,CO,X,TB,ACC,GA,false><<<dim3((unsigned)(((M)*(X)+63)/64)),dim3(256),0,stream>>>((A),(IDX),(Wt),(C),(M))
#define MEINS3(CI,CO,X,TB,ACC,GA, A,IDX,Wt,C,M) \
  k_meinsum<CI,CO,X,TB,ACC,GA,true><<<dim3((unsigned)(((M)*(X)+63)/64)),dim3(256),0,stream>>>((A),(IDX),(Wt),(C),(M))
#define G256(n) dim3((unsigned)(((n)+255)/256)),dim3(256),0,stream
#define GW4(n) dim3((unsigned)(((n)+3)/4)),dim3(256),0,stream

extern "C" void kernel_launch(void* const* d_in, const int* in_sizes, int n_in,
                              void* d_out, int out_size, void* d_ws, size_t ws_size,
                              hipStream_t stream)
{
  const float* pos =(const float*)d_in[0];
  const float* atab=(const float*)d_in[1];
  const float* rbfc=(const float*)d_in[2];
  const float* rbfw=(const float*)d_in[3];
  const float* degW1=(const float*)d_in[4];
  const float* degW2=(const float*)d_in[5];
  const float* degW3=(const float*)d_in[6];
  const float* Wv0=(const float*)d_in[7];
  const float* Wv1=(const float*)d_in[8];
  const float* Wv2=(const float*)d_in[9];
  const float* Ws0=(const float*)d_in[10];
  const float* Ws1=(const float*)d_in[11];
  const float* Ws2=(const float*)d_in[12];
  const float* rW1=(const float*)d_in[13];
  const float* rW2=(const float*)d_in[14];
  const float* rW3=(const float*)d_in[15];
  const float* WaS=(const float*)d_in[16];
  const float* WaD=(const float*)d_in[17];
  const float* WaE=(const float*)d_in[18];
  const float* wab=(const float*)d_in[19];
  const float* ff1=(const float*)d_in[20];
  const float* ff2=(const float*)d_in[21];
  const float* fg1=(const float*)d_in[22];
  const float* fg2=(const float*)d_in[23];
  const float* fW1=(const float*)d_in[24];
  const float* fW2=(const float*)d_in[25];
  const float* lng=(const float*)d_in[26];
  const float* lnb=(const float*)d_in[27];
  const float* W0h=(const float*)d_in[28];
  const float* hout=(const float*)d_in[29];
  const int* natom=(const int*)d_in[30];
  const int* esrc=(const int*)d_in[31];
  const int* edst=(const int*)d_in[32];

  float* Wp=(float*)d_ws;
  size_t off=0;
  auto al=[&](size_t n)->float*{ float* q=Wp+off; off+=n; return q; };

  const size_t SLOT = (size_t)NN*480;
  unsigned short* CKB = (unsigned short*)al((9*SLOT+1)/2);
  float* FA0=al((size_t)NN*128); float* FA1=al((size_t)NN*192); float* FA2=al((size_t)NN*160);
  float* FB0=al((size_t)NN*128); float* FB1=al((size_t)NN*192); float* FB2=al((size_t)NN*160);
  float* DI0=al((size_t)NN*128); float* DI1=al((size_t)NN*192); float* DI2=al((size_t)NN*160);
  float* DY0=al((size_t)NN*128); float* DY1=al((size_t)NN*192); float* DY2=al((size_t)NN*160);
  float* U=al((size_t)NE*3); float* Rr=al(NE); float* SH2b=al((size_t)NE*5);
  float* ABLK=al(8ULL*NE); float* LAM=al(NE);
  float* SSUM=al(NN); float* ENODE=al(NN); float* SACC=al(NN);
  float* DRr=al(NE); float* DSH1=al((size_t)NE*3); float* DSH2=al((size_t)NE*5);
  float* DPOS=al((size_t)NN*3);
  float* WCATF=al(8ULL*128*352);
  int* ROWS =(int*)al(NN+1);
  int* CNT  =(int*)al(NN);
  int* POSB =(int*)al(NN);
  int* PERMB=(int*)al(NE);
  int* ESRC2=(int*)al(NE);
  int* EDST2=(int*)al(NE);

  // ---- UNION region: per-phase chunk layouts + node-phase buffers (all time-disjoint) ----
  const size_t UNI = 28800000;
  float* UN = al(UNI);
  float* TBc=UN;
  float* DTc=TBc+(size_t)NNC*512;
  float* P1 =DTc+(size_t)NNC*512;
  float* P2 =P1 +(size_t)NN*64;
  float* V1 =P2 +(size_t)NN*32;
  float* V2 =V1 +(size_t)NN*192;
  float* DPb=V2 +(size_t)NN*160;
  float* F0N=DPb+(size_t)NN*64;

  float* outE=(float*)d_out;
  float* outF=outE+NG;

  if (off*sizeof(float) > ws_size){
    k_sentinel<<<G256(out_size)>>>(outE, out_size, (float)ws_size);
    return;
  }

  // ---------------- sort edges by dst ----------------
  (void)hipMemsetAsync(CNT,0,NN*sizeof(int),stream);
  k_hist<<<G256(NE)>>>(edst,CNT,NE);
  k_scan0<<<dim3(1),dim3(64),0,stream>>>(CNT,ROWS);
  (void)hipMemcpyAsync(POSB,ROWS,NN*sizeof(int),hipMemcpyDeviceToDevice,stream);
  k_fillperm<<<G256(NE)>>>(edst,POSB,PERMB,NE);
  k_mkedge<<<G256(NE)>>>(PERMB,esrc,edst,ESRC2,EDST2);
  k_wcat<<<G256(8*128*352)>>>(Wv0,Ws0,Ws1,Ws2,WCATF);

  // ---------------- setup ----------------
  k_geom<<<G256(NE)>>>(pos,ESRC2,EDST2,U,Rr,SH2b);
  k_f0init<<<G256(NN*128)>>>(natom,atab,FA0);
  (void)hipMemsetAsync(FA1,0,(size_t)NN*192*4,stream);
  (void)hipMemsetAsync(FA2,0,(size_t)NN*160*4,stream);
  (void)hipMemsetAsync(DRr,0,(size_t)NE*4,stream);
  (void)hipMemsetAsync(DSH1,0,(size_t)NE*3*4,stream);
  (void)hipMemsetAsync(DSH2,0,(size_t)NE*5*4,stream);
  (void)hipMemsetAsync(DPOS,0,(size_t)NN*3*4,stream);

  // degree embedding (CHIF chunks) -> FA  [split-bf16 + fused RBF]
  {
    float* H1=UN; float* H2=H1+(size_t)CHIF*64; float* Gc=H2+(size_t)CHIF*64;
    for (int cc=0;cc<NIF;cc++){
      int c0e=cc*CHIF, cnt=(c0e+CHIF<=NE)?CHIF:(NE-c0e);
      MG(16,false,false,1,false, true,true,false,false, Rr+c0e,nullptr,degW1,H1, cnt,64,128, rbfc,rbfw,nullptr,nullptr);
      MGEMM3(false,false,1,false, H1,nullptr,degW2,H2, cnt,64,64);
      MGEMM3(false,false,0,false, H2,nullptr,degW3,Gc, cnt,224,64);
      k_agg<true><<<dim3(NG),dim3(512),0,stream>>>(FA0,FA1,FA2,
        nullptr,nullptr,nullptr, Gc,U,SH2b, nullptr, EDST2,EDST2, nullptr, c0e,c0e+cnt);
    }
  }
  k_q3<<<G256(NN*480)>>>(FA0,FA1,FA2, CKB);

  float *c0_=FA0,*c1_=FA1,*c2_=FA2, *n0_=FB0,*n1_=FB1,*n2_=FB2;

  // ---------------- forward blocks [split-bf16], CHF chunks ----------------
  {
    float* H1  =UN;
    float* H2  =H1  +(size_t)CHF*64;
    float* Gc  =H2  +(size_t)CHF*64;
    float* SCAT=Gc  +(size_t)CHF*224;
    float* SV1 =SCAT+(size_t)CHF*352;
    float* SV2 =SV1 +(size_t)CHF*192;
    float* Zc  =SV2 +(size_t)CHF*160;
    for (int i=0;i<8;i++){
      const float* Wv1i=Wv1+(size_t)i*4096; const float* Wv2i=Wv2+(size_t)i*1024;
      const float* rW1i=rW1+(size_t)i*8192; const float* rW2i=rW2+(size_t)i*4096; const float* rW3i=rW3+(size_t)i*14336;
      const float* WaSi=WaS+(size_t)i*4096; const float* WaDi=WaD+(size_t)i*4096; const float* WaEi=WaE+(size_t)i*2048;
      const float* ff1i=ff1+(size_t)i*65536; const float* ff2i=ff2+(size_t)i*65536;
      const float* fg1i=fg1+(size_t)i*8192; const float* fg2i=fg2+(size_t)i*4096;
      const float* fW1i=fW1+(size_t)i*4096; const float* fW2i=fW2+(size_t)i*1024;
      const float* WCi=WCATF+(size_t)i*45056;
      float* AB=ABLK+(size_t)i*NE;

      (void)hipMemsetAsync(SACC,0,(size_t)NN*4,stream);
      (void)hipMemsetAsync(n0_,0,(size_t)NN*128*4,stream);
      (void)hipMemsetAsync(n1_,0,(size_t)NN*192*4,stream);
      (void)hipMemsetAsync(n2_,0,(size_t)NN*160*4,stream);
      for (int cc=0;cc<NF;cc++){
        int c0e=cc*CHF, cnt=(c0e+CHF<=NE)?CHF:(NE-c0e);
        MG(16,false,false,1,false, true,true,false,false, Rr+c0e,nullptr,rW1i,H1, cnt,64,128, rbfc,rbfw,nullptr,nullptr);
        MGEMM3(false,false,1,false, H1,nullptr,rW2i,H2, cnt,64,64);
        MGEMM3(false,false,0,false, H2,nullptr,rW3i,Gc, cnt,224,64);
        MGEMM3(false,false,0,true,  c0_,ESRC2+c0e,WaSi,Zc, cnt,32,128);
        MGEMM3(false,true, 0,true,  c0_,EDST2+c0e,WaDi,Zc, cnt,32,128);
        MGEMM3(false,true, 2,false, H2,nullptr,WaEi,Zc, cnt,32,64);
        k_lambda<<<G256(cnt)>>>(Zc, wab+(size_t)i*32, LAM+c0e, cnt);
        MGEMM3(false,false,0,true, c0_,ESRC2+c0e,WCi,SCAT, cnt,352,128);
        MEINS3(64,64,3,false,false,true, c1_,ESRC2+c0e,Wv1i,SV1, cnt);
        MEINS3(32,32,5,false,false,true, c2_,ESRC2+c0e,Wv2i,SV2, cnt);
        k_agg<false><<<dim3(NG),dim3(512),0,stream>>>(n0_,n1_,n2_,
          SCAT,SV1,SV2, Gc,U,SH2b, LAM, EDST2,EDST2, SACC, c0e,c0e+cnt);
      }
      k_norm<<<G256(NE)>>>(LAM,SACC,EDST2,AB);
      k_finy<<<G256(NN*480)>>>(c0_,c1_,c2_, n0_,n1_,n2_, SACC);
      k_q3<<<G256(NN*480)>>>(n0_,n1_,n2_, CKB+(size_t)(i+1)*SLOT);
      for (int nc=0;nc<NN/NNC;nc++){
        MGEMM3(false,false,1,false, n0_+(size_t)nc*NNC*128,nullptr,ff1i,TBc, NNC,512,128);
        MGEMM3(false,true, 0,false, TBc,nullptr,ff2i, n0_+(size_t)nc*NNC*128, NNC,128,512);
      }
      MGEMM3(false,false,3,false, n0_,nullptr,fg1i,P1, NN,64,128);
      MGEMM3(false,false,3,false, n0_,nullptr,fg2i,P2, NN,32,128);
      MEINS3(64,64,3,false,false,false, n1_,nullptr,fW1i,V1, NN);
      MEINS3(32,32,5,false,false,false, n2_,nullptr,fW2i,V2, NN);
      k_gatefwd<64,3><<<G256(NN*192)>>>(n1_,V1,P1);
      k_gatefwd<32,5><<<G256(NN*160)>>>(n2_,V2,P2);
      float* t;
      t=c0_;c0_=n0_;n0_=t; t=c1_;c1_=n1_;n1_=t; t=c2_;c2_=n2_;n2_=t;
    }
  }

  // ---------------- head ----------------
  k_lnhead<<<dim3(NN),dim3(64),0,stream>>>(c0_,c1_,c2_, lng,lnb,W0h,hout, ENODE, DI0,DI1,DI2);
  k_esum<<<dim3(8),dim3(64),0,stream>>>(ENODE,outE);

  // ---------------- backward blocks [plain bf16 MFMA, fused epilogues], CHB chunks ----------------
  {
    float* PRE1=UN;
    float* PRE2=PRE1+(size_t)CHB*64;
    float* H1  =PRE2+(size_t)CHB*64;
    float* H2  =H1  +(size_t)CHB*64;
    float* Gc  =H2  +(size_t)CHB*64;
    float* DGc =Gc  +(size_t)CHB*224;
    float* SCAT=DGc +(size_t)CHB*224;
    float* SV1 =SCAT+(size_t)CHB*352;
    float* SV2 =SV1 +(size_t)CHB*192;
    float* Zc  =SV2 +(size_t)CHB*160;
    float* DE0 =PRE1;   // alias: PRE1+PRE2 (128/edge) dead after rW backward chain
    float* RBFc=DGc;    // alias: DGc dead after rW3^T read
    float* DZD =Gc;     // alias: Gc dead after k_bedge
    for (int i=7;i>=0;--i){
      const float* Wv1i=Wv1+(size_t)i*4096; const float* Wv2i=Wv2+(size_t)i*1024;
      const float* rW1i=rW1+(size_t)i*8192; const float* rW2i=rW2+(size_t)i*4096; const float* rW3i=rW3+(size_t)i*14336;
      const float* WaSi=WaS+(size_t)i*4096; const float* WaDi=WaD+(size_t)i*4096; const float* WaEi=WaE+(size_t)i*2048;
      const float* ff1i=ff1+(size_t)i*65536; const float* ff2i=ff2+(size_t)i*65536;
      const float* fg1i=fg1+(size_t)i*8192; const float* fg2i=fg2+(size_t)i*4096;
      const float* fW1i=fW1+(size_t)i*4096; const float* fW2i=fW2+(size_t)i*1024;
      const float* WCi=WCATF+(size_t)i*45056;
      const float* AB=ABLK+(size_t)i*NE;

      k_dq3<<<G256(NN*480)>>>(CKB+(size_t)i*SLOT, FA0,FA1,FA2);
      if (i>0){
        const float* pf1=ff1+(size_t)(i-1)*65536; const float* pf2=ff2+(size_t)(i-1)*65536;
        const float* pg1=fg1+(size_t)(i-1)*8192; const float* pg2=fg2+(size_t)(i-1)*4096;
        const float* pW1=fW1+(size_t)(i-1)*4096; const float* pW2=fW2+(size_t)(i-1)*1024;
        for (int nc=0;nc<NN/NNC;nc++){
          MGEMM(false,false,1,false, FA0+(size_t)nc*NNC*128,nullptr,pf1,TBc, NNC,512,128);
          MGEMM(false,true, 0,false, TBc,nullptr,pf2, FA0+(size_t)nc*NNC*128, NNC,128,512);
        }
        MGEMM(false,false,3,false, FA0,nullptr,pg1,P1, NN,64,128);
        MGEMM(false,false,3,false, FA0,nullptr,pg2,P2, NN,32,128);
        MEINS(64,64,3,false,false,false, FA1,nullptr,pW1,V1, NN);
        MEINS(32,32,5,false,false,false, FA2,nullptr,pW2,V2, NN);
        k_gatefwd<64,3><<<G256(NN*192)>>>(FA1,V1,P1);
        k_gatefwd<32,5><<<G256(NN*160)>>>(FA2,V2,P2);
      }
      k_dq3<<<G256(NN*480)>>>(CKB+(size_t)(i+1)*SLOT, FB0,FB1,FB2);
      (void)hipMemcpyAsync(F0N,FB0,(size_t)NN*128*4,hipMemcpyDeviceToDevice,stream);
      for (int nc=0;nc<NN/NNC;nc++){
        MGEMM(false,false,1,false, FB0+(size_t)nc*NNC*128,nullptr,ff1i,TBc, NNC,512,128);
        MGEMM(false,true, 0,false, TBc,nullptr,ff2i, F0N+(size_t)nc*NNC*128, NNC,128,512);
      }
      MGEMM(false,false,3,false, F0N,nullptr,fg1i,P1, NN,64,128);
      MGEMM(false,false,3,false, F0N,nullptr,fg2i,P2, NN,32,128);
      MEINS(64,64,3,false,false,false, FB1,nullptr,fW1i,V1, NN);
      MEINS(32,32,5,false,false,false, FB2,nullptr,fW2i,V2, NN);
      k_gateback<64,3><<<G256(NN*64)>>>(DI1,V1,P1,DPb);
      MGEMM(true,true,0,false, DPb,nullptr,fg1i,DI0, NN,128,64);
      (void)hipMemcpyAsync(DY1,DI1,(size_t)NN*192*4,hipMemcpyDeviceToDevice,stream);
      MEINS(64,64,3,true,true,false, V1,nullptr,fW1i,DY1, NN);
      k_gateback<32,5><<<G256(NN*32)>>>(DI2,V2,P2,DPb);
      MGEMM(true,true,0,false, DPb,nullptr,fg2i,DI0, NN,128,32);
      (void)hipMemcpyAsync(DY2,DI2,(size_t)NN*160*4,hipMemcpyDeviceToDevice,stream);
      MEINS(32,32,5,true,true,false, V2,nullptr,fW2i,DY2, NN);
      (void)hipMemcpyAsync(DY0,DI0,(size_t)NN*128*4,hipMemcpyDeviceToDevice,stream);
      for (int nc=0;nc<NN/NNC;nc++){
        MGEMM(false,false,0,false, FB0+(size_t)nc*NNC*128,nullptr,ff1i,TBc, NNC,512,128);
        MG(16,true,false,0,false, false,false,true,false, DI0+(size_t)nc*NNC*128,nullptr,ff2i,DTc, NNC,512,128, nullptr,nullptr,TBc,nullptr);
        MGEMM(true,true,0,false, DTc,nullptr,ff1i, DY0+(size_t)nc*NNC*128, NNC,128,512);
      }
      k_ssum<<<dim3(NN/4),dim3(256),0,stream>>>(FA0,FA1,FA2,FB0,FB1,FB2,DY0,DY1,DY2,SSUM);
      (void)hipMemcpyAsync(DI0,DY0,(size_t)NN*128*4,hipMemcpyDeviceToDevice,stream);
      (void)hipMemcpyAsync(DI1,DY1,(size_t)NN*192*4,hipMemcpyDeviceToDevice,stream);
      (void)hipMemcpyAsync(DI2,DY2,(size_t)NN*160*4,hipMemcpyDeviceToDevice,stream);
      for (int cc=0;cc<NB;cc++){
        int c0e=cc*CHB, cnt=(c0e+CHB<=NE)?CHB:(NE-c0e);
        MG(16,false,false,1,false, false,true,false,true, Rr+c0e,nullptr,rW1i,H1, cnt,64,128, rbfc,rbfw,nullptr,PRE1);
        MG(16,false,false,1,false, false,false,false,true, H1,nullptr,rW2i,H2, cnt,64,64, nullptr,nullptr,nullptr,PRE2);
        MGEMM(false,false,0,false, H2,nullptr,rW3i,Gc, cnt,224,64);
        MGEMM(false,false,0,true,  FA0,ESRC2+c0e,WaSi,Zc, cnt,32,128);
        MGEMM(false,true, 0,true,  FA0,EDST2+c0e,WaDi,Zc, cnt,32,128);
        MGEMM(false,true, 2,false, H2,nullptr,WaEi,Zc, cnt,32,64);
        MGEMM(false,false,0,true, FA0,ESRC2+c0e,WCi,SCAT, cnt,352,128);
        MEINS(64,64,3,false,false,true, FA1,ESRC2+c0e,Wv1i,SV1, cnt);
        MEINS(32,32,5,false,false,true, FA2,ESRC2+c0e,Wv2i,SV2, cnt);
        k_bedge<<<GW4(cnt)>>>(SCAT,SV1,SV2, Gc,U,SH2b, DY0,DY1,DY2, EDST2, SSUM,
                              wab+(size_t)i*32, Zc, AB, DGc, DSH1, DSH2, c0e, cnt);
        // rW backward chain first (consumes PRE1/PRE2, DGc) ...
        MGEMM(true,false,0,false, Zc,nullptr,WaEi,H2, cnt,64,32);
        MG(16,true,true,0,false, false,false,true,false, DGc,nullptr,rW3i,H2, cnt,64,224, nullptr,nullptr,PRE2,nullptr);
        MG(16,true,false,0,false, false,false,true,false, H2,nullptr,rW2i,H1, cnt,64,64, nullptr,nullptr,PRE1,nullptr);
        MGEMM(true,false,0,false, H1,nullptr,rW1i,RBFc, cnt,128,64);
        k_dr<<<GW4(cnt)>>>(RBFc,Rr,rbfc,rbfw,DRr, c0e,cnt);
        // ... then edge-grad group into freed regions
        MGEMM(true,false,0,false, SCAT,nullptr,WCi,DE0, cnt,128,352);
        MGEMM(true,true, 0,false, Zc,nullptr,WaSi,DE0, cnt,128,32);
        MGEMM(true,false,0,false, Zc,nullptr,WaDi,DZD, cnt,128,32);
        MEINS(64,64,3,true,false,false, SV1,nullptr,Wv1i,SV1, cnt);
        MEINS(32,32,5,true,false,false, SV2,nullptr,Wv2i,SV2, cnt);
        k_scat<<<dim3(NG),dim3(640),0,stream>>>(DI0,DI1,DI2, DE0,DZD,SV1,SV2, ESRC2,EDST2, c0e,c0e+cnt);
      }
    }
  }

  // ---------------- initial embedding backward [fused], CHIB chunks ----------------
  {
    float* PRE1=UN;
    float* PRE2=PRE1+(size_t)CHIB*64;
    float* H1  =PRE2+(size_t)CHIB*64;
    float* H2  =H1  +(size_t)CHIB*64;
    float* Gc  =H2  +(size_t)CHIB*64;
    float* DGc =Gc  +(size_t)CHIB*224;
    float* RBFc=DGc +(size_t)CHIB*224;
    for (int cc=0;cc<NIB;cc++){
      int c0e=cc*CHIB, cnt=(c0e+CHIB<=NE)?CHIB:(NE-c0e);
      MG(16,false,false,1,false, false,true,false,true, Rr+c0e,nullptr,degW1,H1, cnt,64,128, rbfc,rbfw,nullptr,PRE1);
      MG(16,false,false,1,false, false,false,false,true, H1,nullptr,degW2,H2, cnt,64,64, nullptr,nullptr,nullptr,PRE2);
      MGEMM(false,false,0,false, H2,nullptr,degW3,Gc, cnt,224,64);
      k_initback<<<GW4(cnt)>>>(DI0,DI1,DI2,EDST2,Gc,U,SH2b,DGc,DSH1,DSH2, c0e,cnt);
      MG(16,true,false,0,false, false,false,true,false, DGc,nullptr,degW3,H2, cnt,64,224, nullptr,nullptr,PRE2,nullptr);
      MG(16,true,false,0,false, false,false,true,false, H2,nullptr,degW2,H1, cnt,64,64, nullptr,nullptr,PRE1,nullptr);
      MGEMM(true,false,0,false, H1,nullptr,degW1,RBFc, cnt,128,64);
      k_dr<<<GW4(cnt)>>>(RBFc,Rr,rbfc,rbfw,DRr, c0e,cnt);
    }
  }

  // ---------------- geometry backward + outputs ----------------
  k_geoback<<<G256(NE)>>>(DRr,DSH1,DSH2,U,Rr,ESRC2,EDST2,DPOS);
  k_forces<<<G256(NN*3)>>>(DPOS,outF);
  (void)in_sizes; (void)n_in; (void)out_size;
}